// Round 6
// baseline (534.226 us; speedup 1.0000x reference)
//
#include <hip/hip_runtime.h>
#include <math.h>

// Problem dims (fixed by reference)
#define Bsz 64
#define Ssz 512
#define Hsz 400
#define Dsz 400
#define Vsz 32000
#define Lsz 16
#define H3  1200   // 3*H

// Workspace layout (float offsets)
#define WT_HH_OFF 0                 // 400*1200 transposed W_hh [k][j]  (fallback only)
#define WT_IH_OFF 480000            // 400*1200 transposed W_ih [k][j]  (fallback only)
#define HQ_OFF    960000            // 16 bg * 2(ping/pong) * 1600 floats  h buffers
#define GI_OFF    1011200           // 16*1200*64   gi[t][j][b]
#define HALL_OFF  2240000           // 64*16*400    h_all[b][t][d]
#define SCALL_OFF 2649600           // 16*64*512    scores[t][b][s]
#define CTR_OFF   3173888           // 16 barrier counters, stride 32 uints (512 uints)
// total 3,174,400 floats = 12.7 MB

#define NBG   16                    // batch groups (4 batches each)
#define DGRP  16                    // d-groups = blocks per batch-group barrier
#define NBLK_CHAIN 256              // NBG * DGRP; 1 block/CU -> co-resident
#define KS    18                    // k-splits in the chain GEMV
#define PROBS4 8192000              // B*L*V/4 float4
#define START4 8192256              // (B*L*V + B*L)/4 : tail after preds region

// part index: [ks][gate][dd][bq]
#define PIDX(ks, g, dd, bq) ((((ks) * 3 + (g)) * 25 + (dd)) * 4 + (bq))

// native vector type for nontemporal builtins (HIP float4 class is rejected)
typedef float nf4 __attribute__((ext_vector_type(4)));

// ---------------------------------------------------------------------------
// k_init: tf==1: h0 + barrier ctrs (+tail zero). tf==0: full zero + WT + h0.
// ---------------------------------------------------------------------------
__global__ __launch_bounds__(256) void k_init(const float* __restrict__ W_hh,
                                              const float* __restrict__ W_ih,
                                              const float* __restrict__ enc_hidden,
                                              const int* __restrict__ tf_p,
                                              float4* __restrict__ out4, int n4,
                                              float* __restrict__ ws) {
    const int tf = tf_p[0];
    const int z0 = tf ? START4 : 0;          // first out4 index to zero
    const int nz = (n4 > z0) ? (n4 - z0) : 0;
    const int nT = tf ? 0 : 480000;          // transpose regions only for fallback
    const int R1 = nz + nT;
    const int R2 = R1 + nT;
    const int R3 = R2 + 25600;
    const int R4 = R3 + 512;
    int stride = gridDim.x * 256;
    for (int i = blockIdx.x * 256 + threadIdx.x; i < R4; i += stride) {
        if (i < nz) {
            out4[z0 + i] = make_float4(0.f, 0.f, 0.f, 0.f);
        } else if (i < R1) {
            int r = i - nz;
            int k = r / 1200, j = r % 1200;
            ws[WT_HH_OFF + r] = W_hh[(size_t)j * Hsz + k];
        } else if (i < R2) {
            int r = i - R1;
            int k = r / 1200, j = r % 1200;
            ws[WT_IH_OFF + r] = W_ih[(size_t)j * Dsz + k];
        } else if (i < R3) {
            int r = i - R2;
            int k = r >> 6, B = r & 63;
            // per-bg ping buffer, layout float4[k4][b] within group
            ws[HQ_OFF + (B >> 2) * 3200 + (((k >> 2) << 2) + (B & 3)) * 4 + (k & 3)]
                = enc_hidden[B * Hsz + k];
        } else {
            ((unsigned*)(ws + CTR_OFF))[i - R3] = 0u;
        }
    }
}

// ---------------------------------------------------------------------------
// k_gi (tf==1 only): gi[t][j][b] = (x_t[b] @ W_ih^T)[j], tiled GEMM.
// ---------------------------------------------------------------------------
__global__ __launch_bounds__(256) void k_gi(const int* __restrict__ tgt,
                                            const int* __restrict__ slot_p,
                                            const int* __restrict__ tf_p,
                                            const float* __restrict__ embedding,
                                            const float* __restrict__ slot_emb,
                                            const float* __restrict__ W_ih,
                                            float* __restrict__ gi) {
    if (tf_p[0] == 0) return;
    __shared__ float4 xs[100 * 64];   // 102.4 KB, [k4][b]

    int t  = blockIdx.x >> 4;
    int jc = blockIdx.x & 15;
    int tid = threadIdx.x;
    int lane = tid & 63, wv = tid >> 6;

    {
        int bb = tid & 63, q = tid >> 6;
        const float* src = (t == 0)
            ? (slot_emb + (size_t)slot_p[0] * Dsz)
            : (embedding + (size_t)tgt[bb * Lsz + (t - 1)] * Dsz);
        const float4* src4 = (const float4*)src;
        for (int k4 = q * 25; k4 < q * 25 + 25; ++k4) xs[k4 * 64 + bb] = src4[k4];
    }
    __syncthreads();

    for (int g = wv; g < 19; g += 4) {
        int j0l = g * 4;
        int nj = (j0l + 4 <= 75) ? 4 : (75 - j0l);
        int j0 = jc * 75 + j0l;
        const float4* w0 = (const float4*)(W_ih + (size_t)(j0 + 0) * Dsz);
        const float4* w1 = (const float4*)(W_ih + (size_t)(j0 + ((nj > 1) ? 1 : 0)) * Dsz);
        const float4* w2 = (const float4*)(W_ih + (size_t)(j0 + ((nj > 2) ? 2 : 0)) * Dsz);
        const float4* w3 = (const float4*)(W_ih + (size_t)(j0 + ((nj > 3) ? 3 : 0)) * Dsz);
        float a0 = 0.f, a1 = 0.f, a2 = 0.f, a3 = 0.f;
        for (int k4 = 0; k4 < 100; ++k4) {
            float4 xv = xs[k4 * 64 + lane];
            float4 r0 = w0[k4], r1 = w1[k4], r2 = w2[k4], r3 = w3[k4];
            a0 = fmaf(r0.x, xv.x, a0); a0 = fmaf(r0.y, xv.y, a0);
            a0 = fmaf(r0.z, xv.z, a0); a0 = fmaf(r0.w, xv.w, a0);
            a1 = fmaf(r1.x, xv.x, a1); a1 = fmaf(r1.y, xv.y, a1);
            a1 = fmaf(r1.z, xv.z, a1); a1 = fmaf(r1.w, xv.w, a1);
            a2 = fmaf(r2.x, xv.x, a2); a2 = fmaf(r2.y, xv.y, a2);
            a2 = fmaf(r2.z, xv.z, a2); a2 = fmaf(r2.w, xv.w, a2);
            a3 = fmaf(r3.x, xv.x, a3); a3 = fmaf(r3.y, xv.y, a3);
            a3 = fmaf(r3.z, xv.z, a3); a3 = fmaf(r3.w, xv.w, a3);
        }
        float* go = gi + ((size_t)t * H3 + j0) * 64 + lane;
        go[0] = a0;
        if (nj > 1) go[64] = a1;
        if (nj > 2) go[128] = a2;
        if (nj > 3) go[192] = a3;
    }
}

// ---------------------------------------------------------------------------
// k_chain: tf==1: 256 blocks = 16 batch-groups (4 b each) x 16 d-groups.
// Per-bg 16-block barrier; NEW: all reload threads poll the counter and
// bypass-load their own h word directly (no tid0-spin + extra barriers).
// Race-free: ctr cannot reach target until our own finalize waves arrive,
// and those arrives are ordered after their h4 reads (lockstep + release).
// tf==0: blocks 0..63 run independent per-batch full decode (unchanged).
// ---------------------------------------------------------------------------
struct SmemChain {
    float4 W4[75 * 101];    // 121.2 KB  W_hh slice rows (padded to 101 float4)
    float4 h4[400];         //   6.4 KB  h staged [k4][b] for the 4 batches
    float  part[KS * 300];  //  21.6 KB  [ks][gate][dd][bq]
};
struct SmemFallback {
    float part_i[3 * H3];
    float part_h[3 * H3];
    float hx[Hsz];
    float xv[Dsz];
    float sL[Ssz];
    float redv[15];
    int   redi[15];
    float bc_max, bc_sum;
    int   bc_idx;
};
union SmemU { SmemChain c; SmemFallback f; };

__device__ __forceinline__ float sigmoidf_(float x) { return 1.f / (1.f + expf(-x)); }

__global__ __launch_bounds__(960) void k_chain(const float* __restrict__ ws_ro,
                                               const float* __restrict__ gi,
                                               const float* __restrict__ W_hh,
                                               const float* __restrict__ enc_hidden,
                                               const float* __restrict__ enc_out,
                                               const int* __restrict__ lens,
                                               const int* __restrict__ uttrs,
                                               const int* __restrict__ slot_p,
                                               const int* __restrict__ tf_p,
                                               const float* __restrict__ embedding,
                                               const float* __restrict__ slot_emb,
                                               const float* __restrict__ b_ih,
                                               const float* __restrict__ b_hh,
                                               float* __restrict__ ws_rw,
                                               float* __restrict__ h_all,
                                               float* __restrict__ out_probs,
                                               float* __restrict__ preds_out) {
    __shared__ SmemU sm;
    const int tid = threadIdx.x;
    const int tf  = tf_p[0];

    if (tf != 0) {
        // ================= grouped h-chain =================
        const int bg = blockIdx.x & 15;      // batch group (4 batches)
        const int dg = blockIdx.x >> 4;      // d group (25 dims)
        const int D0 = dg * 25;
        unsigned* ctr = (unsigned*)(ws_rw + CTR_OFF) + bg * 32;

        // preload W_hh slice: rows r = g*25+dd (g gate, dd local dim), padded LDS
        for (int i = tid; i < 7500; i += 960) {
            int r = i / 100, k4 = i % 100;
            int g = r / 25, dd = r % 25;
            sm.c.W4[r * 101 + k4] =
                ((const float4*)(W_hh + (size_t)(g * Hsz + D0 + dd) * Hsz))[k4];
        }

        // GEMV thread geometry (tid < 900): (ks, dd, bp)
        const int gks = tid / 50;
        const int gidx = tid % 50;
        const int gbp = gidx & 1;
        const int gdd = gidx >> 1;
        const int gk4b = (gks * 100) / KS;
        const int gk4e = ((gks + 1) * 100) / KS;
        const int gbq0 = gbp << 1;

        // finalize unit: one (dd,bq) per thread, tids 0..99 (waves 0 and 1)
        const bool is_fin = (tid < 100);
        const int  fbq = tid & 3, fdd = tid >> 2;
        const int  fd  = D0 + fdd;
        float g1r = 0.f, g1z = 0.f, g1n = 0.f;   // gi for current step
        float g2r = 0.f, g2z = 0.f, g2n = 0.f;   // gi prefetch for next step
        float bir = 0.f, biz = 0.f, bin = 0.f;
        float bhr = 0.f, bhz = 0.f, bhn = 0.f;
        if (is_fin) {
            bir = b_ih[fd]; biz = b_ih[fd + Hsz]; bin = b_ih[fd + 2 * Hsz];
            bhr = b_hh[fd]; bhz = b_hh[fd + Hsz]; bhn = b_hh[fd + 2 * Hsz];
            const float* gp = gi + (size_t)fd * 64 + (bg * 4 + fbq);
            g1r = gp[0];
            g1z = gp[(size_t)Hsz * 64];
            g1n = gp[(size_t)2 * Hsz * 64];
        }

        // initial stage: h0 from the bg ping buffer (bypass for uniformity)
        {
            const unsigned long long* hq8 = (const unsigned long long*)
                (ws_ro + HQ_OFF + (size_t)(bg * 2) * 1600);
            unsigned long long* h8 = (unsigned long long*)sm.c.h4;
            if (tid < 800)
                h8[tid] = __hip_atomic_load(hq8 + tid, __ATOMIC_RELAXED,
                                            __HIP_MEMORY_SCOPE_AGENT);
        }
        __syncthreads();

        for (int t = 0; t < Lsz; ++t) {
            float* hq_nxt = ws_rw + HQ_OFF + (size_t)(bg * 2 + ((t & 1) ^ 1)) * 1600;

            // gi(t+1) prefetch issued early: L2 latency hides under the GEMV
            if (is_fin && t + 1 < Lsz) {
                const float* gp = gi + ((size_t)(t + 1) * H3 + fd) * 64
                                + (bg * 4 + fbq);
                g2r = gp[0];
                g2z = gp[(size_t)Hsz * 64];
                g2n = gp[(size_t)2 * Hsz * 64];
            }

            // GEMV partials: 900 threads (14 waves), 3 gate-rows x 2 batches
            // per thread over a ~5.6-k4 slice. 5 LDS reads per 24 FMA.
            if (tid < 900) {
                const float4* Wr = sm.c.W4 + (0 * 25 + gdd) * 101;
                const float4* Wz = sm.c.W4 + (1 * 25 + gdd) * 101;
                const float4* Wn = sm.c.W4 + (2 * 25 + gdd) * 101;
                float4 ar0 = make_float4(0.f, 0.f, 0.f, 0.f), ar1 = ar0;
                float4 az0 = ar0, az1 = ar0, an0 = ar0, an1 = ar0;
                for (int k4 = gk4b; k4 < gk4e; ++k4) {
                    float4 h0 = sm.c.h4[(k4 << 2) | gbq0];
                    float4 h1 = sm.c.h4[(k4 << 2) | gbq0 | 1];
                    float4 wr = Wr[k4], wz = Wz[k4], wn = Wn[k4];
                    ar0.x = fmaf(wr.x, h0.x, ar0.x); ar0.y = fmaf(wr.y, h0.y, ar0.y);
                    ar0.z = fmaf(wr.z, h0.z, ar0.z); ar0.w = fmaf(wr.w, h0.w, ar0.w);
                    ar1.x = fmaf(wr.x, h1.x, ar1.x); ar1.y = fmaf(wr.y, h1.y, ar1.y);
                    ar1.z = fmaf(wr.z, h1.z, ar1.z); ar1.w = fmaf(wr.w, h1.w, ar1.w);
                    az0.x = fmaf(wz.x, h0.x, az0.x); az0.y = fmaf(wz.y, h0.y, az0.y);
                    az0.z = fmaf(wz.z, h0.z, az0.z); az0.w = fmaf(wz.w, h0.w, az0.w);
                    az1.x = fmaf(wz.x, h1.x, az1.x); az1.y = fmaf(wz.y, h1.y, az1.y);
                    az1.z = fmaf(wz.z, h1.z, az1.z); az1.w = fmaf(wz.w, h1.w, az1.w);
                    an0.x = fmaf(wn.x, h0.x, an0.x); an0.y = fmaf(wn.y, h0.y, an0.y);
                    an0.z = fmaf(wn.z, h0.z, an0.z); an0.w = fmaf(wn.w, h0.w, an0.w);
                    an1.x = fmaf(wn.x, h1.x, an1.x); an1.y = fmaf(wn.y, h1.y, an1.y);
                    an1.z = fmaf(wn.z, h1.z, an1.z); an1.w = fmaf(wn.w, h1.w, an1.w);
                }
                sm.c.part[PIDX(gks, 0, gdd, gbq0)]     = (ar0.x + ar0.y) + (ar0.z + ar0.w);
                sm.c.part[PIDX(gks, 0, gdd, gbq0 | 1)] = (ar1.x + ar1.y) + (ar1.z + ar1.w);
                sm.c.part[PIDX(gks, 1, gdd, gbq0)]     = (az0.x + az0.y) + (az0.z + az0.w);
                sm.c.part[PIDX(gks, 1, gdd, gbq0 | 1)] = (az1.x + az1.y) + (az1.z + az1.w);
                sm.c.part[PIDX(gks, 2, gdd, gbq0)]     = (an0.x + an0.y) + (an0.z + an0.w);
                sm.c.part[PIDX(gks, 2, gdd, gbq0 | 1)] = (an1.x + an1.y) + (an1.z + an1.w);
            }
            __syncthreads();

            // finalize: waves 0+1, one (dd,bq) unit per thread, sum 18 k-splits
            if (is_fin) {
                float ghr = bhr, ghz = bhz, ghn = bhn;
                #pragma unroll
                for (int ks = 0; ks < KS; ++ks) {
                    ghr += sm.c.part[PIDX(ks, 0, fdd, fbq)];
                    ghz += sm.c.part[PIDX(ks, 1, fdd, fbq)];
                    ghn += sm.c.part[PIDX(ks, 2, fdd, fbq)];
                }
                float rr = sigmoidf_(g1r + bir + ghr);
                float zz = sigmoidf_(g1z + biz + ghz);
                float nn = tanhf(g1n + bin + rr * ghn);
                int hidx = (((fd >> 2) << 2) | fbq) * 4 + (fd & 3);
                float hp = ((const float*)sm.c.h4)[hidx];
                float hv = (1.f - zz) * nn + zz * hp;
                // device-visible (IF) store: peers read via bypass loads
                __hip_atomic_store(&hq_nxt[hidx], hv, __ATOMIC_RELAXED,
                                   __HIP_MEMORY_SCOPE_AGENT);
                h_all[(size_t)(bg * 4 + fbq) * (Lsz * Hsz)
                      + (size_t)t * Hsz + fd] = hv;
                g1r = g2r; g1z = g2z; g1n = g2n;
            }

            if (t < Lsz - 1) {
                // arrive: one release-add per finalize wave (drains own h stores)
                if (tid == 0 || tid == 64) {
                    __hip_atomic_fetch_add(ctr, 1u, __ATOMIC_RELEASE,
                                           __HIP_MEMORY_SCOPE_AGENT);
                }
                // fused detect + reload: every reload thread polls, then pulls
                // its own 8B fresh from IF. Non-finalize waves reach this while
                // finalize is still running -> overlap.
                if (tid < 800) {
                    unsigned target = 2u * (unsigned)DGRP * (t + 1);
                    while (__hip_atomic_load(ctr, __ATOMIC_RELAXED,
                                             __HIP_MEMORY_SCOPE_AGENT) < target) {
                        __builtin_amdgcn_s_sleep(2);
                    }
                    const unsigned long long* hq8n = (const unsigned long long*)
                        (ws_ro + HQ_OFF + (size_t)(bg * 2 + ((t + 1) & 1)) * 1600);
                    ((unsigned long long*)sm.c.h4)[tid] =
                        __hip_atomic_load(hq8n + tid, __ATOMIC_RELAXED,
                                          __HIP_MEMORY_SCOPE_AGENT);
                }
                __syncthreads();
            }
        }
        return;
    }

    // ================= tf==0 fallback: per-batch independent decode =========
    if (blockIdx.x >= Bsz) return;
    const int b    = blockIdx.x;
    const int lane = tid & 63;
    const int w    = tid >> 6;          // 0..14
    const int jc   = tid % 300;
    const int ksf  = tid / 300;
    const int kbeg = ksf * 134;
    const int kend = (ksf == 2) ? Hsz : kbeg + 134;
    const int len  = lens[b];

    const float4* WTH4 = (const float4*)(ws_ro + WT_HH_OFF);
    const float4* WTI4 = (const float4*)(ws_ro + WT_IH_OFF);

    if (tid < Hsz) {
        sm.f.hx[tid] = enc_hidden[b * Hsz + tid];
        sm.f.xv[tid] = slot_emb[(size_t)slot_p[0] * Dsz + tid];
    }
    __syncthreads();

    for (int t = 0; t < Lsz; ++t) {
        if (tid < 900) {
            float4 ai = make_float4(0.f, 0.f, 0.f, 0.f);
            float4 ah = make_float4(0.f, 0.f, 0.f, 0.f);
            for (int k = kbeg; k < kend; ++k) {
                float4 wi = WTI4[(size_t)k * 300 + jc];
                float4 wh = WTH4[(size_t)k * 300 + jc];
                float x = sm.f.xv[k], h = sm.f.hx[k];
                ai.x = fmaf(wi.x, x, ai.x); ai.y = fmaf(wi.y, x, ai.y);
                ai.z = fmaf(wi.z, x, ai.z); ai.w = fmaf(wi.w, x, ai.w);
                ah.x = fmaf(wh.x, h, ah.x); ah.y = fmaf(wh.y, h, ah.y);
                ah.z = fmaf(wh.z, h, ah.z); ah.w = fmaf(wh.w, h, ah.w);
            }
            ((float4*)sm.f.part_i)[ksf * 300 + jc] = ai;
            ((float4*)sm.f.part_h)[ksf * 300 + jc] = ah;
        }
        __syncthreads();

        if (tid < Hsz) {
            int d = tid;
            float i_r = sm.f.part_i[d]           + sm.f.part_i[H3 + d]           + sm.f.part_i[2 * H3 + d]           + b_ih[d];
            float i_z = sm.f.part_i[d + Hsz]     + sm.f.part_i[H3 + d + Hsz]     + sm.f.part_i[2 * H3 + d + Hsz]     + b_ih[d + Hsz];
            float i_n = sm.f.part_i[d + 2 * Hsz] + sm.f.part_i[H3 + d + 2 * Hsz] + sm.f.part_i[2 * H3 + d + 2 * Hsz] + b_ih[d + 2 * Hsz];
            float h_r = sm.f.part_h[d]           + sm.f.part_h[H3 + d]           + sm.f.part_h[2 * H3 + d]           + b_hh[d];
            float h_z = sm.f.part_h[d + Hsz]     + sm.f.part_h[H3 + d + Hsz]     + sm.f.part_h[2 * H3 + d + Hsz]     + b_hh[d + Hsz];
            float h_n = sm.f.part_h[d + 2 * Hsz] + sm.f.part_h[H3 + d + 2 * Hsz] + sm.f.part_h[2 * H3 + d + 2 * Hsz] + b_hh[d + 2 * Hsz];
            float r = sigmoidf_(i_r + h_r);
            float z = sigmoidf_(i_z + h_z);
            float n = tanhf(i_n + r * h_n);
            sm.f.hx[d] = (1.f - z) * n + z * sm.f.hx[d];
        }
        __syncthreads();

        const float4* hx4 = (const float4*)sm.f.hx;
        for (int s = w; s < len; s += 15) {
            const float4* e4 = (const float4*)(enc_out + ((size_t)b * Ssz + s) * Hsz);
            float4 ev = e4[lane];
            float4 hv = hx4[lane];
            float acc = ev.x * hv.x + ev.y * hv.y + ev.z * hv.z + ev.w * hv.w;
            if (lane < 36) {
                float4 ev2 = e4[64 + lane];
                float4 hv2 = hx4[64 + lane];
                acc += ev2.x * hv2.x + ev2.y * hv2.y + ev2.z * hv2.z + ev2.w * hv2.w;
            }
            #pragma unroll
            for (int off = 32; off >= 1; off >>= 1) acc += __shfl_xor(acc, off, 64);
            if (lane == 0) sm.f.sL[s] = acc;
        }
        __syncthreads();

        float bv = -INFINITY; int bi = 0x7fffffff;
        for (int s = tid; s < len; s += 960) {
            float v = sm.f.sL[s];
            if (v > bv || (v == bv && s < bi)) { bv = v; bi = s; }
        }
        #pragma unroll
        for (int off = 32; off >= 1; off >>= 1) {
            float ov = __shfl_xor(bv, off, 64);
            int   oi = __shfl_xor(bi, off, 64);
            if (ov > bv || (ov == bv && oi < bi)) { bv = ov; bi = oi; }
        }
        if (lane == 0) { sm.f.redv[w] = bv; sm.f.redi[w] = bi; }
        __syncthreads();
        if (tid == 0) {
            float mv = sm.f.redv[0]; int mi = sm.f.redi[0];
            for (int i = 1; i < 15; ++i)
                if (sm.f.redv[i] > mv || (sm.f.redv[i] == mv && sm.f.redi[i] < mi)) {
                    mv = sm.f.redv[i]; mi = sm.f.redi[i];
                }
            sm.f.bc_max = mv; sm.f.bc_idx = mi;
        }
        __syncthreads();
        float maxv = sm.f.bc_max;
        int   amax = sm.f.bc_idx;

        float ls = 0.f;
        for (int s = tid; s < len; s += 960) {
            float e = expf(sm.f.sL[s] - maxv);
            sm.f.sL[s] = e;
            ls += e;
        }
        #pragma unroll
        for (int off = 32; off >= 1; off >>= 1) ls += __shfl_xor(ls, off, 64);
        if (lane == 0) sm.f.redv[w] = ls;
        __syncthreads();
        if (tid == 0) {
            float sms = 0.f;
            for (int i = 0; i < 15; ++i) sms += sm.f.redv[i];
            sm.f.bc_sum = sms;
        }
        __syncthreads();
        float sum = sm.f.bc_sum;

        float* orow = out_probs + (size_t)b * (Lsz * Vsz) + (size_t)t * Vsz;
        for (int s = tid; s < len; s += 960) {
            atomicAdd(&orow[uttrs[b * Ssz + s]], sm.f.sL[s] / sum);
        }

        int predtok = uttrs[b * Ssz + amax];
        if (tid == 0) preds_out[(size_t)t * Bsz + b] = (float)predtok;
        __syncthreads();
        if (tid < Dsz) sm.f.xv[tid] = embedding[(size_t)predtok * Dsz + tid];
        __syncthreads();
    }
}

// ---------------------------------------------------------------------------
// Batched scores (tf==1), shuffle-free: 256 blocks = (b, s-quarter of 128).
// 256 threads = (s-tile of 4) x (t-pair {tp, tp+8}); acc in registers,
// h broadcast from pad-101 LDS (t-pair reads hit 8 disjoint bank spans).
// DS wave-instrs: ~205K total (was ~3.1M ds_bpermute).
// ---------------------------------------------------------------------------
__global__ __launch_bounds__(256) void k_scores(const float* __restrict__ h_all,
                                                const float* __restrict__ enc_out,
                                                const int* __restrict__ lens,
                                                const int* __restrict__ tf_p,
                                                float* __restrict__ scores_all) {
    if (tf_p[0] == 0) return;
    __shared__ float4 hS[Lsz * 101];   // 25.9 KB, padded stride

    int b  = blockIdx.x >> 2;
    int sc = blockIdx.x & 3;
    int tid = threadIdx.x;
    int len = lens[b];
    int s0 = sc * 128;
    if (s0 >= len) return;             // whole chunk masked downstream

    const float4* h4g = (const float4*)(h_all + (size_t)b * (Lsz * Hsz));
    for (int i = tid; i < Lsz * 100; i += 256) {
        int t = i / 100, k4 = i % 100;
        hS[t * 101 + k4] = h4g[i];
    }
    __syncthreads();

    int stile = tid >> 3;              // 0..31
    int tp    = tid & 7;               // 0..7
    int t0 = tp, t1 = tp + 8;
    int sbase = s0 + stile * 4;

    const float4* e0 = (const float4*)(enc_out + ((size_t)b * Ssz + sbase + 0) * Hsz);
    const float4* e1 = (const float4*)(enc_out + ((size_t)b * Ssz + sbase + 1) * Hsz);
    const float4* e2 = (const float4*)(enc_out + ((size_t)b * Ssz + sbase + 2) * Hsz);
    const float4* e3 = (const float4*)(enc_out + ((size_t)b * Ssz + sbase + 3) * Hsz);
    const float4* h0p = hS + t0 * 101;
    const float4* h1p = hS + t1 * 101;

    float4 a0 = make_float4(0.f, 0.f, 0.f, 0.f);   // t0 x {s0..s3}
    float4 a1 = make_float4(0.f, 0.f, 0.f, 0.f);   // t1 x {s0..s3}
    for (int k4 = 0; k4 < 100; ++k4) {
        float4 v0 = e0[k4], v1 = e1[k4], v2 = e2[k4], v3 = e3[k4];
        float4 h0 = h0p[k4], h1 = h1p[k4];
        a0.x = fmaf(v0.x, h0.x, a0.x); a0.x = fmaf(v0.y, h0.y, a0.x);
        a0.x = fmaf(v0.z, h0.z, a0.x); a0.x = fmaf(v0.w, h0.w, a0.x);
        a0.y = fmaf(v1.x, h0.x, a0.y); a0.y = fmaf(v1.y, h0.y, a0.y);
        a0.y = fmaf(v1.z, h0.z, a0.y); a0.y = fmaf(v1.w, h0.w, a0.y);
        a0.z = fmaf(v2.x, h0.x, a0.z); a0.z = fmaf(v2.y, h0.y, a0.z);
        a0.z = fmaf(v2.z, h0.z, a0.z); a0.z = fmaf(v2.w, h0.w, a0.z);
        a0.w = fmaf(v3.x, h0.x, a0.w); a0.w = fmaf(v3.y, h0.y, a0.w);
        a0.w = fmaf(v3.z, h0.z, a0.w); a0.w = fmaf(v3.w, h0.w, a0.w);
        a1.x = fmaf(v0.x, h1.x, a1.x); a1.x = fmaf(v0.y, h1.y, a1.x);
        a1.x = fmaf(v0.z, h1.z, a1.x); a1.x = fmaf(v0.w, h1.w, a1.x);
        a1.y = fmaf(v1.x, h1.x, a1.y); a1.y = fmaf(v1.y, h1.y, a1.y);
        a1.y = fmaf(v1.z, h1.z, a1.y); a1.y = fmaf(v1.w, h1.w, a1.y);
        a1.z = fmaf(v2.x, h1.x, a1.z); a1.z = fmaf(v2.y, h1.y, a1.z);
        a1.z = fmaf(v2.z, h1.z, a1.z); a1.z = fmaf(v2.w, h1.w, a1.z);
        a1.w = fmaf(v3.x, h1.x, a1.w); a1.w = fmaf(v3.y, h1.y, a1.w);
        a1.w = fmaf(v3.z, h1.z, a1.w); a1.w = fmaf(v3.w, h1.w, a1.w);
    }

    *(float4*)(scores_all + (size_t)t0 * (Bsz * Ssz) + (size_t)b * Ssz + sbase) = a0;
    *(float4*)(scores_all + (size_t)t1 * (Bsz * Ssz) + (size_t)b * Ssz + sbase) = a1;
}

// ---------------------------------------------------------------------------
// Batched softmax + LDS-vocab scatter + argmax (tf==1): one block per (t,b).
// Accumulates pointer dist in 128 KB LDS, streams full row out (no zeroing,
// no global atomics).
// ---------------------------------------------------------------------------
__global__ __launch_bounds__(256) void k_softmax_all(const float* __restrict__ scores_all,
                                                     const int* __restrict__ lens,
                                                     const int* __restrict__ uttrs,
                                                     const int* __restrict__ tf_p,
                                                     float* __restrict__ out_probs,
                                                     float* __restrict__ preds_out) {
    if (tf_p[0] == 0) return;
    __shared__ float4 vb4[Vsz / 4];   // 128 KB vocab accumulator
    __shared__ float sL[Ssz];
    __shared__ float redv[4];
    __shared__ int   redi[4];
    __shared__ float bc_max, bc_sum;
    __shared__ int   bc_idx;

    int t = blockIdx.x >> 6;
    int b = blockIdx.x & 63;
    int tid = threadIdx.x;
    int lane = tid & 63, w = tid >> 6;
    int len = lens[b];
    const float* srow = scores_all + (size_t)t * (Bsz * Ssz) + b * Ssz;

    float4 z4 = make_float4(0.f, 0.f, 0.f, 0.f);
    for (int i = tid; i < Vsz / 4; i += 256) vb4[i] = z4;

    for (int s = tid; s < len; s += 256) sL[s] = srow[s];
    __syncthreads();

    float bv = -INFINITY; int bi = 0x7fffffff;
    for (int s = tid; s < len; s += 256) {
        float v = sL[s];
        if (v > bv || (v == bv && s < bi)) { bv = v; bi = s; }
    }
    #pragma unroll
    for (int off = 32; off >= 1; off >>= 1) {
        float ov = __shfl_xor(bv, off, 64);
        int   oi = __shfl_xor(bi, off, 64);
        if (ov > bv || (ov == bv && oi < bi)) { bv = ov; bi = oi; }
    }
    if (lane == 0) { redv[w] = bv; redi[w] = bi; }
    __syncthreads();
    if (tid == 0) {
        float mv = redv[0]; int mi = redi[0];
        for (int i = 1; i < 4; ++i)
            if (redv[i] > mv || (redv[i] == mv && redi[i] < mi)) { mv = redv[i]; mi = redi[i]; }
        bc_max = mv; bc_idx = mi;
    }
    __syncthreads();
    float maxv = bc_max;
    int   amax = bc_idx;

    float ls = 0.f;
    for (int s = tid; s < len; s += 256) {
        float e = expf(sL[s] - maxv);
        sL[s] = e;
        ls += e;
    }
    #pragma unroll
    for (int off = 32; off >= 1; off >>= 1) ls += __shfl_xor(ls, off, 64);
    if (lane == 0) redv[w] = ls;
    __syncthreads();
    if (tid == 0) bc_sum = redv[0] + redv[1] + redv[2] + redv[3];
    __syncthreads();
    float sum = bc_sum;

    float* vbf = (float*)vb4;
    for (int s = tid; s < len; s += 256) {
        atomicAdd(&vbf[uttrs[b * Ssz + s]], sL[s] / sum);
    }
    __syncthreads();

    // stream the full vocab row out nontemporally (native vector type)
    const nf4* vbn = (const nf4*)vb4;
    nf4* orow4 = (nf4*)(out_probs + (size_t)b * (Lsz * Vsz) + (size_t)t * Vsz);
    for (int i = tid; i < Vsz / 4; i += 256)
        __builtin_nontemporal_store(vbn[i], &orow4[i]);

    if (tid == 0) preds_out[(size_t)t * Bsz + b] = (float)uttrs[b * Ssz + amax];
}

// ---------------------------------------------------------------------------
extern "C" void kernel_launch(void* const* d_in, const int* in_sizes, int n_in,
                              void* d_out, int out_size, void* d_ws, size_t ws_size,
                              hipStream_t stream) {
    const float* enc_hidden = (const float*)d_in[0];
    const float* enc_out    = (const float*)d_in[1];
    const int*   enc_lens   = (const int*)d_in[2];
    const int*   uttrs      = (const int*)d_in[3];
    const int*   tgt        = (const int*)d_in[4];
    const int*   slot_p     = (const int*)d_in[5];
    const int*   tf_p       = (const int*)d_in[6];
    const float* embedding  = (const float*)d_in[7];
    const float* slot_emb   = (const float*)d_in[8];
    const float* W_ih       = (const float*)d_in[9];
    const float* W_hh       = (const float*)d_in[10];
    const float* b_ih       = (const float*)d_in[11];
    const float* b_hh       = (const float*)d_in[12];

    float* out = (float*)d_out;
    float* ws  = (float*)d_ws;

    float* gi_all     = ws + GI_OFF;
    float* h_all      = ws + HALL_OFF;
    float* scores_all = ws + SCALL_OFF;
    float* preds_out  = out + (size_t)Bsz * Lsz * Vsz;

    int n4 = out_size >> 2;

    // 1) init: h0 + barrier ctrs (+ full zero / WT transposes only if tf==0)
    k_init<<<2048, 256, 0, stream>>>(W_hh, W_ih, enc_hidden, tf_p,
                                     (float4*)d_out, n4, ws);

    // 2) gi GEMM for all 16 steps (tf==1 only)
    k_gi<<<256, 256, 0, stream>>>(tgt, slot_p, tf_p, embedding, slot_emb,
                                  W_ih, gi_all);

    // 3) chain (tf==1: 16 independent group-barriers; tf==0: per-batch fallback)
    k_chain<<<NBLK_CHAIN, 960, 0, stream>>>(ws, gi_all, W_hh, enc_hidden, enc_out,
                                            enc_lens, uttrs, slot_p, tf_p,
                                            embedding, slot_emb, b_ih, b_hh,
                                            ws, h_all, out, preds_out);

    // 4) batched scores + softmax/scatter (tf==1 only)
    k_scores<<<256, 256, 0, stream>>>(h_all, enc_out, enc_lens, tf_p, scores_all);
    k_softmax_all<<<1024, 256, 0, stream>>>(scores_all, enc_lens, uttrs, tf_p,
                                            out, preds_out);
}

// Round 7
// 466.224 us; speedup vs baseline: 1.1459x; 1.1459x over previous
//
#include <hip/hip_runtime.h>
#include <math.h>

// Problem dims (fixed by reference)
#define Bsz 64
#define Ssz 512
#define Hsz 400
#define Dsz 400
#define Vsz 32000
#define Lsz 16
#define H3  1200   // 3*H

// Workspace layout (float offsets)
#define WT_HH_OFF 0                 // 400*1200 transposed W_hh [k][j]  (fallback only)
#define WT_IH_OFF 480000            // 400*1200 transposed W_ih [k][j]  (fallback only)
#define HQ_OFF    960000            // 16 bg * 2(ping/pong) * 1600 floats  h buffers
#define GI_OFF    1011200           // 16*1200*64   gi[t][j][b]
#define HALL_OFF  2240000           // 64*16*400    h_all[b][t][d]
#define SCALL_OFF 2649600           // 16*64*512    scores[t][b][s]
#define CTR_OFF   3173888           // 16 barrier counters, stride 32 uints (512 uints)
// total 3,174,400 floats = 12.7 MB

#define NBG   16                    // batch groups (4 batches each)
#define DGRP  16                    // d-groups = blocks per batch-group barrier
#define NBLK_CHAIN 256              // NBG * DGRP; 1 block/CU -> co-resident
#define KS    18                    // k-splits in the chain GEMV
#define PROBS4 8192000              // B*L*V/4 float4
#define START4 8192256              // (B*L*V + B*L)/4 : tail after preds region

// part index: [ks][gate][dd][bq]
#define PIDX(ks, g, dd, bq) ((((ks) * 3 + (g)) * 25 + (dd)) * 4 + (bq))

// native vector type for nontemporal builtins (HIP float4 class is rejected)
typedef float nf4 __attribute__((ext_vector_type(4)));

// ---------------------------------------------------------------------------
// k_init: tf==1: h0 + barrier ctrs (+tail zero). tf==0: full zero + WT + h0.
// ---------------------------------------------------------------------------
__global__ __launch_bounds__(256) void k_init(const float* __restrict__ W_hh,
                                              const float* __restrict__ W_ih,
                                              const float* __restrict__ enc_hidden,
                                              const int* __restrict__ tf_p,
                                              float4* __restrict__ out4, int n4,
                                              float* __restrict__ ws) {
    const int tf = tf_p[0];
    const int z0 = tf ? START4 : 0;          // first out4 index to zero
    const int nz = (n4 > z0) ? (n4 - z0) : 0;
    const int nT = tf ? 0 : 480000;          // transpose regions only for fallback
    const int R1 = nz + nT;
    const int R2 = R1 + nT;
    const int R3 = R2 + 25600;
    const int R4 = R3 + 512;
    int stride = gridDim.x * 256;
    for (int i = blockIdx.x * 256 + threadIdx.x; i < R4; i += stride) {
        if (i < nz) {
            out4[z0 + i] = make_float4(0.f, 0.f, 0.f, 0.f);
        } else if (i < R1) {
            int r = i - nz;
            int k = r / 1200, j = r % 1200;
            ws[WT_HH_OFF + r] = W_hh[(size_t)j * Hsz + k];
        } else if (i < R2) {
            int r = i - R1;
            int k = r / 1200, j = r % 1200;
            ws[WT_IH_OFF + r] = W_ih[(size_t)j * Dsz + k];
        } else if (i < R3) {
            int r = i - R2;
            int k = r >> 6, B = r & 63;
            // per-bg ping buffer, layout float4[k4][b] within group
            ws[HQ_OFF + (B >> 2) * 3200 + (((k >> 2) << 2) + (B & 3)) * 4 + (k & 3)]
                = enc_hidden[B * Hsz + k];
        } else {
            ((unsigned*)(ws + CTR_OFF))[i - R3] = 0u;
        }
    }
}

// ---------------------------------------------------------------------------
// k_gi (tf==1 only): gi[t][j][b] = (x_t[b] @ W_ih^T)[j], tiled GEMM.
// ---------------------------------------------------------------------------
__global__ __launch_bounds__(256) void k_gi(const int* __restrict__ tgt,
                                            const int* __restrict__ slot_p,
                                            const int* __restrict__ tf_p,
                                            const float* __restrict__ embedding,
                                            const float* __restrict__ slot_emb,
                                            const float* __restrict__ W_ih,
                                            float* __restrict__ gi) {
    if (tf_p[0] == 0) return;
    __shared__ float4 xs[100 * 64];   // 102.4 KB, [k4][b]

    int t  = blockIdx.x >> 4;
    int jc = blockIdx.x & 15;
    int tid = threadIdx.x;
    int lane = tid & 63, wv = tid >> 6;

    {
        int bb = tid & 63, q = tid >> 6;
        const float* src = (t == 0)
            ? (slot_emb + (size_t)slot_p[0] * Dsz)
            : (embedding + (size_t)tgt[bb * Lsz + (t - 1)] * Dsz);
        const float4* src4 = (const float4*)src;
        for (int k4 = q * 25; k4 < q * 25 + 25; ++k4) xs[k4 * 64 + bb] = src4[k4];
    }
    __syncthreads();

    for (int g = wv; g < 19; g += 4) {
        int j0l = g * 4;
        int nj = (j0l + 4 <= 75) ? 4 : (75 - j0l);
        int j0 = jc * 75 + j0l;
        const float4* w0 = (const float4*)(W_ih + (size_t)(j0 + 0) * Dsz);
        const float4* w1 = (const float4*)(W_ih + (size_t)(j0 + ((nj > 1) ? 1 : 0)) * Dsz);
        const float4* w2 = (const float4*)(W_ih + (size_t)(j0 + ((nj > 2) ? 2 : 0)) * Dsz);
        const float4* w3 = (const float4*)(W_ih + (size_t)(j0 + ((nj > 3) ? 3 : 0)) * Dsz);
        float a0 = 0.f, a1 = 0.f, a2 = 0.f, a3 = 0.f;
        for (int k4 = 0; k4 < 100; ++k4) {
            float4 xv = xs[k4 * 64 + lane];
            float4 r0 = w0[k4], r1 = w1[k4], r2 = w2[k4], r3 = w3[k4];
            a0 = fmaf(r0.x, xv.x, a0); a0 = fmaf(r0.y, xv.y, a0);
            a0 = fmaf(r0.z, xv.z, a0); a0 = fmaf(r0.w, xv.w, a0);
            a1 = fmaf(r1.x, xv.x, a1); a1 = fmaf(r1.y, xv.y, a1);
            a1 = fmaf(r1.z, xv.z, a1); a1 = fmaf(r1.w, xv.w, a1);
            a2 = fmaf(r2.x, xv.x, a2); a2 = fmaf(r2.y, xv.y, a2);
            a2 = fmaf(r2.z, xv.z, a2); a2 = fmaf(r2.w, xv.w, a2);
            a3 = fmaf(r3.x, xv.x, a3); a3 = fmaf(r3.y, xv.y, a3);
            a3 = fmaf(r3.z, xv.z, a3); a3 = fmaf(r3.w, xv.w, a3);
        }
        float* go = gi + ((size_t)t * H3 + j0) * 64 + lane;
        go[0] = a0;
        if (nj > 1) go[64] = a1;
        if (nj > 2) go[128] = a2;
        if (nj > 3) go[192] = a3;
    }
}

// ---------------------------------------------------------------------------
// k_chain: tf==1: 256 blocks = 16 batch-groups (4 b each) x 16 d-groups.
// Per-bg 16-block barrier, R5 protocol (tid0-only poll): widening the IF
// poller set to 13 waves (R6) congested the fabric, +83 us. Keep pollers=1.
// tf==0: blocks 0..63 run independent per-batch full decode (unchanged).
// ---------------------------------------------------------------------------
struct SmemChain {
    float4 W4[75 * 101];    // 121.2 KB  W_hh slice rows (padded to 101 float4)
    float4 h4[400];         //   6.4 KB  h staged [k4][b] for the 4 batches
    float  part[KS * 300];  //  21.6 KB  [ks][gate][dd][bq]
};
struct SmemFallback {
    float part_i[3 * H3];
    float part_h[3 * H3];
    float hx[Hsz];
    float xv[Dsz];
    float sL[Ssz];
    float redv[15];
    int   redi[15];
    float bc_max, bc_sum;
    int   bc_idx;
};
union SmemU { SmemChain c; SmemFallback f; };

__device__ __forceinline__ float sigmoidf_(float x) { return 1.f / (1.f + expf(-x)); }

__global__ __launch_bounds__(960) void k_chain(const float* __restrict__ ws_ro,
                                               const float* __restrict__ gi,
                                               const float* __restrict__ W_hh,
                                               const float* __restrict__ enc_hidden,
                                               const float* __restrict__ enc_out,
                                               const int* __restrict__ lens,
                                               const int* __restrict__ uttrs,
                                               const int* __restrict__ slot_p,
                                               const int* __restrict__ tf_p,
                                               const float* __restrict__ embedding,
                                               const float* __restrict__ slot_emb,
                                               const float* __restrict__ b_ih,
                                               const float* __restrict__ b_hh,
                                               float* __restrict__ ws_rw,
                                               float* __restrict__ h_all,
                                               float* __restrict__ out_probs,
                                               float* __restrict__ preds_out) {
    __shared__ SmemU sm;
    const int tid = threadIdx.x;
    const int tf  = tf_p[0];

    if (tf != 0) {
        // ================= grouped h-chain =================
        const int bg = blockIdx.x & 15;      // batch group (4 batches)
        const int dg = blockIdx.x >> 4;      // d group (25 dims)
        const int D0 = dg * 25;
        unsigned* ctr = (unsigned*)(ws_rw + CTR_OFF) + bg * 32;

        // preload W_hh slice: rows r = g*25+dd (g gate, dd local dim), padded LDS
        for (int i = tid; i < 7500; i += 960) {
            int r = i / 100, k4 = i % 100;
            int g = r / 25, dd = r % 25;
            sm.c.W4[r * 101 + k4] =
                ((const float4*)(W_hh + (size_t)(g * Hsz + D0 + dd) * Hsz))[k4];
        }

        // GEMV thread geometry (tid < 900): (ks, dd, bp)
        const int gks = tid / 50;
        const int gidx = tid % 50;
        const int gbp = gidx & 1;
        const int gdd = gidx >> 1;
        const int gk4b = (gks * 100) / KS;
        const int gk4e = ((gks + 1) * 100) / KS;
        const int gbq0 = gbp << 1;

        // finalize unit: one (dd,bq) per thread, tids 0..99 (waves 0 and 1)
        const bool is_fin = (tid < 100);
        const int  fbq = tid & 3, fdd = tid >> 2;
        const int  fd  = D0 + fdd;
        float g1r = 0.f, g1z = 0.f, g1n = 0.f;   // gi for current step
        float g2r = 0.f, g2z = 0.f, g2n = 0.f;   // gi prefetch for next step
        float bir = 0.f, biz = 0.f, bin = 0.f;
        float bhr = 0.f, bhz = 0.f, bhn = 0.f;
        if (is_fin) {
            bir = b_ih[fd]; biz = b_ih[fd + Hsz]; bin = b_ih[fd + 2 * Hsz];
            bhr = b_hh[fd]; bhz = b_hh[fd + Hsz]; bhn = b_hh[fd + 2 * Hsz];
            const float* gp = gi + (size_t)fd * 64 + (bg * 4 + fbq);
            g1r = gp[0];
            g1z = gp[(size_t)Hsz * 64];
            g1n = gp[(size_t)2 * Hsz * 64];
        }
        __syncthreads();

        for (int t = 0; t < Lsz; ++t) {
            const unsigned long long* hq8 = (const unsigned long long*)
                (ws_ro + HQ_OFF + (size_t)(bg * 2 + (t & 1)) * 1600);
            float* hq_nxt = ws_rw + HQ_OFF + (size_t)(bg * 2 + ((t & 1) ^ 1)) * 1600;

            // stage h via cache-bypassing loads (fresh from IF, no inv needed)
            unsigned long long* h8 = (unsigned long long*)sm.c.h4;
            if (tid < 800)
                h8[tid] = __hip_atomic_load(hq8 + tid, __ATOMIC_RELAXED,
                                            __HIP_MEMORY_SCOPE_AGENT);
            __syncthreads();

            // gi(t+1) prefetch issued early: L2 latency hides under the GEMV
            if (is_fin && t + 1 < Lsz) {
                const float* gp = gi + ((size_t)(t + 1) * H3 + fd) * 64
                                + (bg * 4 + fbq);
                g2r = gp[0];
                g2z = gp[(size_t)Hsz * 64];
                g2n = gp[(size_t)2 * Hsz * 64];
            }

            // GEMV partials: 900 threads (14 waves), 3 gate-rows x 2 batches
            // per thread over a ~5.6-k4 slice. 5 LDS reads per 24 FMA.
            if (tid < 900) {
                const float4* Wr = sm.c.W4 + (0 * 25 + gdd) * 101;
                const float4* Wz = sm.c.W4 + (1 * 25 + gdd) * 101;
                const float4* Wn = sm.c.W4 + (2 * 25 + gdd) * 101;
                float4 ar0 = make_float4(0.f, 0.f, 0.f, 0.f), ar1 = ar0;
                float4 az0 = ar0, az1 = ar0, an0 = ar0, an1 = ar0;
                for (int k4 = gk4b; k4 < gk4e; ++k4) {
                    float4 h0 = sm.c.h4[(k4 << 2) | gbq0];
                    float4 h1 = sm.c.h4[(k4 << 2) | gbq0 | 1];
                    float4 wr = Wr[k4], wz = Wz[k4], wn = Wn[k4];
                    ar0.x = fmaf(wr.x, h0.x, ar0.x); ar0.y = fmaf(wr.y, h0.y, ar0.y);
                    ar0.z = fmaf(wr.z, h0.z, ar0.z); ar0.w = fmaf(wr.w, h0.w, ar0.w);
                    ar1.x = fmaf(wr.x, h1.x, ar1.x); ar1.y = fmaf(wr.y, h1.y, ar1.y);
                    ar1.z = fmaf(wr.z, h1.z, ar1.z); ar1.w = fmaf(wr.w, h1.w, ar1.w);
                    az0.x = fmaf(wz.x, h0.x, az0.x); az0.y = fmaf(wz.y, h0.y, az0.y);
                    az0.z = fmaf(wz.z, h0.z, az0.z); az0.w = fmaf(wz.w, h0.w, az0.w);
                    az1.x = fmaf(wz.x, h1.x, az1.x); az1.y = fmaf(wz.y, h1.y, az1.y);
                    az1.z = fmaf(wz.z, h1.z, az1.z); az1.w = fmaf(wz.w, h1.w, az1.w);
                    an0.x = fmaf(wn.x, h0.x, an0.x); an0.y = fmaf(wn.y, h0.y, an0.y);
                    an0.z = fmaf(wn.z, h0.z, an0.z); an0.w = fmaf(wn.w, h0.w, an0.w);
                    an1.x = fmaf(wn.x, h1.x, an1.x); an1.y = fmaf(wn.y, h1.y, an1.y);
                    an1.z = fmaf(wn.z, h1.z, an1.z); an1.w = fmaf(wn.w, h1.w, an1.w);
                }
                sm.c.part[PIDX(gks, 0, gdd, gbq0)]     = (ar0.x + ar0.y) + (ar0.z + ar0.w);
                sm.c.part[PIDX(gks, 0, gdd, gbq0 | 1)] = (ar1.x + ar1.y) + (ar1.z + ar1.w);
                sm.c.part[PIDX(gks, 1, gdd, gbq0)]     = (az0.x + az0.y) + (az0.z + az0.w);
                sm.c.part[PIDX(gks, 1, gdd, gbq0 | 1)] = (az1.x + az1.y) + (az1.z + az1.w);
                sm.c.part[PIDX(gks, 2, gdd, gbq0)]     = (an0.x + an0.y) + (an0.z + an0.w);
                sm.c.part[PIDX(gks, 2, gdd, gbq0 | 1)] = (an1.x + an1.y) + (an1.z + an1.w);
            }
            __syncthreads();

            // finalize: waves 0+1, one (dd,bq) unit per thread, sum 18 k-splits
            if (is_fin) {
                float ghr = bhr, ghz = bhz, ghn = bhn;
                #pragma unroll
                for (int ks = 0; ks < KS; ++ks) {
                    ghr += sm.c.part[PIDX(ks, 0, fdd, fbq)];
                    ghz += sm.c.part[PIDX(ks, 1, fdd, fbq)];
                    ghn += sm.c.part[PIDX(ks, 2, fdd, fbq)];
                }
                float rr = sigmoidf_(g1r + bir + ghr);
                float zz = sigmoidf_(g1z + biz + ghz);
                float nn = tanhf(g1n + bin + rr * ghn);
                int hidx = (((fd >> 2) << 2) | fbq) * 4 + (fd & 3);
                float hp = ((const float*)sm.c.h4)[hidx];
                float hv = (1.f - zz) * nn + zz * hp;
                // device-visible (IF) store: peers read via bypass loads
                __hip_atomic_store(&hq_nxt[hidx], hv, __ATOMIC_RELAXED,
                                   __HIP_MEMORY_SCOPE_AGENT);
                h_all[(size_t)(bg * 4 + fbq) * (Lsz * Hsz)
                      + (size_t)t * Hsz + fd] = hv;
                g1r = g2r; g1z = g2z; g1n = g2n;
            }

            if (t < Lsz - 1) {
                __syncthreads();
                // one release-add per finalize wave: each wave's release drains
                // its OWN h stores (vmcnt is per-wave) before publishing at IF
                if (tid == 0 || tid == 64) {
                    __hip_atomic_fetch_add(ctr, 1u, __ATOMIC_RELEASE,
                                           __HIP_MEMORY_SCOPE_AGENT);
                }
                if (tid == 0) {
                    unsigned target = 2u * (unsigned)DGRP * (t + 1);
                    while (__hip_atomic_load(ctr, __ATOMIC_RELAXED,
                                             __HIP_MEMORY_SCOPE_AGENT) < target) {
                        __builtin_amdgcn_s_sleep(1);
                    }
                }
                __syncthreads();
            }
        }
        return;
    }

    // ================= tf==0 fallback: per-batch independent decode =========
    if (blockIdx.x >= Bsz) return;
    const int b    = blockIdx.x;
    const int lane = tid & 63;
    const int w    = tid >> 6;          // 0..14
    const int jc   = tid % 300;
    const int ksf  = tid / 300;
    const int kbeg = ksf * 134;
    const int kend = (ksf == 2) ? Hsz : kbeg + 134;
    const int len  = lens[b];

    const float4* WTH4 = (const float4*)(ws_ro + WT_HH_OFF);
    const float4* WTI4 = (const float4*)(ws_ro + WT_IH_OFF);

    if (tid < Hsz) {
        sm.f.hx[tid] = enc_hidden[b * Hsz + tid];
        sm.f.xv[tid] = slot_emb[(size_t)slot_p[0] * Dsz + tid];
    }
    __syncthreads();

    for (int t = 0; t < Lsz; ++t) {
        if (tid < 900) {
            float4 ai = make_float4(0.f, 0.f, 0.f, 0.f);
            float4 ah = make_float4(0.f, 0.f, 0.f, 0.f);
            for (int k = kbeg; k < kend; ++k) {
                float4 wi = WTI4[(size_t)k * 300 + jc];
                float4 wh = WTH4[(size_t)k * 300 + jc];
                float x = sm.f.xv[k], h = sm.f.hx[k];
                ai.x = fmaf(wi.x, x, ai.x); ai.y = fmaf(wi.y, x, ai.y);
                ai.z = fmaf(wi.z, x, ai.z); ai.w = fmaf(wi.w, x, ai.w);
                ah.x = fmaf(wh.x, h, ah.x); ah.y = fmaf(wh.y, h, ah.y);
                ah.z = fmaf(wh.z, h, ah.z); ah.w = fmaf(wh.w, h, ah.w);
            }
            ((float4*)sm.f.part_i)[ksf * 300 + jc] = ai;
            ((float4*)sm.f.part_h)[ksf * 300 + jc] = ah;
        }
        __syncthreads();

        if (tid < Hsz) {
            int d = tid;
            float i_r = sm.f.part_i[d]           + sm.f.part_i[H3 + d]           + sm.f.part_i[2 * H3 + d]           + b_ih[d];
            float i_z = sm.f.part_i[d + Hsz]     + sm.f.part_i[H3 + d + Hsz]     + sm.f.part_i[2 * H3 + d + Hsz]     + b_ih[d + Hsz];
            float i_n = sm.f.part_i[d + 2 * Hsz] + sm.f.part_i[H3 + d + 2 * Hsz] + sm.f.part_i[2 * H3 + d + 2 * Hsz] + b_ih[d + 2 * Hsz];
            float h_r = sm.f.part_h[d]           + sm.f.part_h[H3 + d]           + sm.f.part_h[2 * H3 + d]           + b_hh[d];
            float h_z = sm.f.part_h[d + Hsz]     + sm.f.part_h[H3 + d + Hsz]     + sm.f.part_h[2 * H3 + d + Hsz]     + b_hh[d + Hsz];
            float h_n = sm.f.part_h[d + 2 * Hsz] + sm.f.part_h[H3 + d + 2 * Hsz] + sm.f.part_h[2 * H3 + d + 2 * Hsz] + b_hh[d + 2 * Hsz];
            float r = sigmoidf_(i_r + h_r);
            float z = sigmoidf_(i_z + h_z);
            float n = tanhf(i_n + r * h_n);
            sm.f.hx[d] = (1.f - z) * n + z * sm.f.hx[d];
        }
        __syncthreads();

        const float4* hx4 = (const float4*)sm.f.hx;
        for (int s = w; s < len; s += 15) {
            const float4* e4 = (const float4*)(enc_out + ((size_t)b * Ssz + s) * Hsz);
            float4 ev = e4[lane];
            float4 hv = hx4[lane];
            float acc = ev.x * hv.x + ev.y * hv.y + ev.z * hv.z + ev.w * hv.w;
            if (lane < 36) {
                float4 ev2 = e4[64 + lane];
                float4 hv2 = hx4[64 + lane];
                acc += ev2.x * hv2.x + ev2.y * hv2.y + ev2.z * hv2.z + ev2.w * hv2.w;
            }
            #pragma unroll
            for (int off = 32; off >= 1; off >>= 1) acc += __shfl_xor(acc, off, 64);
            if (lane == 0) sm.f.sL[s] = acc;
        }
        __syncthreads();

        float bv = -INFINITY; int bi = 0x7fffffff;
        for (int s = tid; s < len; s += 960) {
            float v = sm.f.sL[s];
            if (v > bv || (v == bv && s < bi)) { bv = v; bi = s; }
        }
        #pragma unroll
        for (int off = 32; off >= 1; off >>= 1) {
            float ov = __shfl_xor(bv, off, 64);
            int   oi = __shfl_xor(bi, off, 64);
            if (ov > bv || (ov == bv && oi < bi)) { bv = ov; bi = oi; }
        }
        if (lane == 0) { sm.f.redv[w] = bv; sm.f.redi[w] = bi; }
        __syncthreads();
        if (tid == 0) {
            float mv = sm.f.redv[0]; int mi = sm.f.redi[0];
            for (int i = 1; i < 15; ++i)
                if (sm.f.redv[i] > mv || (sm.f.redv[i] == mv && sm.f.redi[i] < mi)) {
                    mv = sm.f.redv[i]; mi = sm.f.redi[i];
                }
            sm.f.bc_max = mv; sm.f.bc_idx = mi;
        }
        __syncthreads();
        float maxv = sm.f.bc_max;
        int   amax = sm.f.bc_idx;

        float ls = 0.f;
        for (int s = tid; s < len; s += 960) {
            float e = expf(sm.f.sL[s] - maxv);
            sm.f.sL[s] = e;
            ls += e;
        }
        #pragma unroll
        for (int off = 32; off >= 1; off >>= 1) ls += __shfl_xor(ls, off, 64);
        if (lane == 0) sm.f.redv[w] = ls;
        __syncthreads();
        if (tid == 0) {
            float sms = 0.f;
            for (int i = 0; i < 15; ++i) sms += sm.f.redv[i];
            sm.f.bc_sum = sms;
        }
        __syncthreads();
        float sum = sm.f.bc_sum;

        float* orow = out_probs + (size_t)b * (Lsz * Vsz) + (size_t)t * Vsz;
        for (int s = tid; s < len; s += 960) {
            atomicAdd(&orow[uttrs[b * Ssz + s]], sm.f.sL[s] / sum);
        }

        int predtok = uttrs[b * Ssz + amax];
        if (tid == 0) preds_out[(size_t)t * Bsz + b] = (float)predtok;
        __syncthreads();
        if (tid < Dsz) sm.f.xv[tid] = embedding[(size_t)predtok * Dsz + tid];
        __syncthreads();
    }
}

// ---------------------------------------------------------------------------
// Batched scores (tf==1), shuffle-free: 256 blocks = (b, s-quarter of 128).
// 256 threads = (s-tile of 4) x (t-pair {tp, tp+8}); acc in registers,
// h broadcast from pad-101 LDS.
// ---------------------------------------------------------------------------
__global__ __launch_bounds__(256) void k_scores(const float* __restrict__ h_all,
                                                const float* __restrict__ enc_out,
                                                const int* __restrict__ lens,
                                                const int* __restrict__ tf_p,
                                                float* __restrict__ scores_all) {
    if (tf_p[0] == 0) return;
    __shared__ float4 hS[Lsz * 101];   // 25.9 KB, padded stride

    int b  = blockIdx.x >> 2;
    int sc = blockIdx.x & 3;
    int tid = threadIdx.x;
    int len = lens[b];
    int s0 = sc * 128;
    if (s0 >= len) return;             // whole chunk masked downstream

    const float4* h4g = (const float4*)(h_all + (size_t)b * (Lsz * Hsz));
    for (int i = tid; i < Lsz * 100; i += 256) {
        int t = i / 100, k4 = i % 100;
        hS[t * 101 + k4] = h4g[i];
    }
    __syncthreads();

    int stile = tid >> 3;              // 0..31
    int tp    = tid & 7;               // 0..7
    int t0 = tp, t1 = tp + 8;
    int sbase = s0 + stile * 4;

    const float4* e0 = (const float4*)(enc_out + ((size_t)b * Ssz + sbase + 0) * Hsz);
    const float4* e1 = (const float4*)(enc_out + ((size_t)b * Ssz + sbase + 1) * Hsz);
    const float4* e2 = (const float4*)(enc_out + ((size_t)b * Ssz + sbase + 2) * Hsz);
    const float4* e3 = (const float4*)(enc_out + ((size_t)b * Ssz + sbase + 3) * Hsz);
    const float4* h0p = hS + t0 * 101;
    const float4* h1p = hS + t1 * 101;

    float4 a0 = make_float4(0.f, 0.f, 0.f, 0.f);   // t0 x {s0..s3}
    float4 a1 = make_float4(0.f, 0.f, 0.f, 0.f);   // t1 x {s0..s3}
    for (int k4 = 0; k4 < 100; ++k4) {
        float4 v0 = e0[k4], v1 = e1[k4], v2 = e2[k4], v3 = e3[k4];
        float4 h0 = h0p[k4], h1 = h1p[k4];
        a0.x = fmaf(v0.x, h0.x, a0.x); a0.x = fmaf(v0.y, h0.y, a0.x);
        a0.x = fmaf(v0.z, h0.z, a0.x); a0.x = fmaf(v0.w, h0.w, a0.x);
        a0.y = fmaf(v1.x, h0.x, a0.y); a0.y = fmaf(v1.y, h0.y, a0.y);
        a0.y = fmaf(v1.z, h0.z, a0.y); a0.y = fmaf(v1.w, h0.w, a0.y);
        a0.z = fmaf(v2.x, h0.x, a0.z); a0.z = fmaf(v2.y, h0.y, a0.z);
        a0.z = fmaf(v2.z, h0.z, a0.z); a0.z = fmaf(v2.w, h0.w, a0.z);
        a0.w = fmaf(v3.x, h0.x, a0.w); a0.w = fmaf(v3.y, h0.y, a0.w);
        a0.w = fmaf(v3.z, h0.z, a0.w); a0.w = fmaf(v3.w, h0.w, a0.w);
        a1.x = fmaf(v0.x, h1.x, a1.x); a1.x = fmaf(v0.y, h1.y, a1.x);
        a1.x = fmaf(v0.z, h1.z, a1.x); a1.x = fmaf(v0.w, h1.w, a1.x);
        a1.y = fmaf(v1.x, h1.x, a1.y); a1.y = fmaf(v1.y, h1.y, a1.y);
        a1.y = fmaf(v1.z, h1.z, a1.y); a1.y = fmaf(v1.w, h1.w, a1.y);
        a1.z = fmaf(v2.x, h1.x, a1.z); a1.z = fmaf(v2.y, h1.y, a1.z);
        a1.z = fmaf(v2.z, h1.z, a1.z); a1.z = fmaf(v2.w, h1.w, a1.z);
        a1.w = fmaf(v3.x, h1.x, a1.w); a1.w = fmaf(v3.y, h1.y, a1.w);
        a1.w = fmaf(v3.z, h1.z, a1.w); a1.w = fmaf(v3.w, h1.w, a1.w);
    }

    *(float4*)(scores_all + (size_t)t0 * (Bsz * Ssz) + (size_t)b * Ssz + sbase) = a0;
    *(float4*)(scores_all + (size_t)t1 * (Bsz * Ssz) + (size_t)b * Ssz + sbase) = a1;
}

// ---------------------------------------------------------------------------
// Batched softmax + LDS-vocab scatter + argmax (tf==1): one block per (t,b).
// Accumulates pointer dist in 128 KB LDS, streams full row out (no zeroing,
// no global atomics).
// ---------------------------------------------------------------------------
__global__ __launch_bounds__(256) void k_softmax_all(const float* __restrict__ scores_all,
                                                     const int* __restrict__ lens,
                                                     const int* __restrict__ uttrs,
                                                     const int* __restrict__ tf_p,
                                                     float* __restrict__ out_probs,
                                                     float* __restrict__ preds_out) {
    if (tf_p[0] == 0) return;
    __shared__ float4 vb4[Vsz / 4];   // 128 KB vocab accumulator
    __shared__ float sL[Ssz];
    __shared__ float redv[4];
    __shared__ int   redi[4];
    __shared__ float bc_max, bc_sum;
    __shared__ int   bc_idx;

    int t = blockIdx.x >> 6;
    int b = blockIdx.x & 63;
    int tid = threadIdx.x;
    int lane = tid & 63, w = tid >> 6;
    int len = lens[b];
    const float* srow = scores_all + (size_t)t * (Bsz * Ssz) + b * Ssz;

    float4 z4 = make_float4(0.f, 0.f, 0.f, 0.f);
    for (int i = tid; i < Vsz / 4; i += 256) vb4[i] = z4;

    for (int s = tid; s < len; s += 256) sL[s] = srow[s];
    __syncthreads();

    float bv = -INFINITY; int bi = 0x7fffffff;
    for (int s = tid; s < len; s += 256) {
        float v = sL[s];
        if (v > bv || (v == bv && s < bi)) { bv = v; bi = s; }
    }
    #pragma unroll
    for (int off = 32; off >= 1; off >>= 1) {
        float ov = __shfl_xor(bv, off, 64);
        int   oi = __shfl_xor(bi, off, 64);
        if (ov > bv || (ov == bv && oi < bi)) { bv = ov; bi = oi; }
    }
    if (lane == 0) { redv[w] = bv; redi[w] = bi; }
    __syncthreads();
    if (tid == 0) {
        float mv = redv[0]; int mi = redi[0];
        for (int i = 1; i < 4; ++i)
            if (redv[i] > mv || (redv[i] == mv && redi[i] < mi)) { mv = redv[i]; mi = redi[i]; }
        bc_max = mv; bc_idx = mi;
    }
    __syncthreads();
    float maxv = bc_max;
    int   amax = bc_idx;

    float ls = 0.f;
    for (int s = tid; s < len; s += 256) {
        float e = expf(sL[s] - maxv);
        sL[s] = e;
        ls += e;
    }
    #pragma unroll
    for (int off = 32; off >= 1; off >>= 1) ls += __shfl_xor(ls, off, 64);
    if (lane == 0) redv[w] = ls;
    __syncthreads();
    if (tid == 0) bc_sum = redv[0] + redv[1] + redv[2] + redv[3];
    __syncthreads();
    float sum = bc_sum;

    float* vbf = (float*)vb4;
    for (int s = tid; s < len; s += 256) {
        atomicAdd(&vbf[uttrs[b * Ssz + s]], sL[s] / sum);
    }
    __syncthreads();

    // stream the full vocab row out nontemporally (native vector type)
    const nf4* vbn = (const nf4*)vb4;
    nf4* orow4 = (nf4*)(out_probs + (size_t)b * (Lsz * Vsz) + (size_t)t * Vsz);
    for (int i = tid; i < Vsz / 4; i += 256)
        __builtin_nontemporal_store(vbn[i], &orow4[i]);

    if (tid == 0) preds_out[(size_t)t * Bsz + b] = (float)uttrs[b * Ssz + amax];
}

// ---------------------------------------------------------------------------
extern "C" void kernel_launch(void* const* d_in, const int* in_sizes, int n_in,
                              void* d_out, int out_size, void* d_ws, size_t ws_size,
                              hipStream_t stream) {
    const float* enc_hidden = (const float*)d_in[0];
    const float* enc_out    = (const float*)d_in[1];
    const int*   enc_lens   = (const int*)d_in[2];
    const int*   uttrs      = (const int*)d_in[3];
    const int*   tgt        = (const int*)d_in[4];
    const int*   slot_p     = (const int*)d_in[5];
    const int*   tf_p       = (const int*)d_in[6];
    const float* embedding  = (const float*)d_in[7];
    const float* slot_emb   = (const float*)d_in[8];
    const float* W_ih       = (const float*)d_in[9];
    const float* W_hh       = (const float*)d_in[10];
    const float* b_ih       = (const float*)d_in[11];
    const float* b_hh       = (const float*)d_in[12];

    float* out = (float*)d_out;
    float* ws  = (float*)d_ws;

    float* gi_all     = ws + GI_OFF;
    float* h_all      = ws + HALL_OFF;
    float* scores_all = ws + SCALL_OFF;
    float* preds_out  = out + (size_t)Bsz * Lsz * Vsz;

    int n4 = out_size >> 2;

    // 1) init: h0 + barrier ctrs (+ full zero / WT transposes only if tf==0)
    k_init<<<2048, 256, 0, stream>>>(W_hh, W_ih, enc_hidden, tf_p,
                                     (float4*)d_out, n4, ws);

    // 2) gi GEMM for all 16 steps (tf==1 only)
    k_gi<<<256, 256, 0, stream>>>(tgt, slot_p, tf_p, embedding, slot_emb,
                                  W_ih, gi_all);

    // 3) chain (tf==1: 16 independent group-barriers; tf==0: per-batch fallback)
    k_chain<<<NBLK_CHAIN, 960, 0, stream>>>(ws, gi_all, W_hh, enc_hidden, enc_out,
                                            enc_lens, uttrs, slot_p, tf_p,
                                            embedding, slot_emb, b_ih, b_hh,
                                            ws, h_all, out, preds_out);

    // 4) batched scores + softmax/scatter (tf==1 only)
    k_scores<<<256, 256, 0, stream>>>(h_all, enc_out, enc_lens, tf_p, scores_all);
    k_softmax_all<<<1024, 256, 0, stream>>>(scores_all, enc_lens, uttrs, tf_p,
                                            out, preds_out);
}

// Round 8
// 457.349 us; speedup vs baseline: 1.1681x; 1.0194x over previous
//
#include <hip/hip_runtime.h>
#include <math.h>

// Problem dims (fixed by reference)
#define Bsz 64
#define Ssz 512
#define Hsz 400
#define Dsz 400
#define Vsz 32000
#define Lsz 16
#define H3  1200   // 3*H

// Workspace layout (float offsets)
#define WT_HH_OFF 0                 // 400*1200 transposed W_hh [k][j]  (fallback only)
#define WT_IH_OFF 480000            // 400*1200 transposed W_ih [k][j]  (fallback only)
#define HQ_OFF    960000            // 16 bg * 2(ping/pong) * 1600 floats  h buffers
#define GI_OFF    1011200           // 16*1200*64   gi[t][j][b]
#define HALL_OFF  2240000           // 64*16*400    h_all[b][t][d]
#define SCALL_OFF 2649600           // 16*64*512    scores[t][b][s]
#define CTR_OFF   3173888           // 16 barrier counters, stride 32 uints (512 uints)
// total 3,174,400 floats = 12.7 MB

#define NBG   16                    // batch groups (4 batches each)
#define DGRP  16                    // d-groups = blocks per batch-group barrier
#define NBLK_CHAIN 256              // NBG * DGRP; 1 block/CU -> co-resident
#define KS    18                    // k-splits in the chain GEMV
#define PROBS4 8192000              // B*L*V/4 float4
#define START4 8192256              // (B*L*V + B*L)/4 : tail after preds region

// part index: [ks][gate][dd][bq]
#define PIDX(ks, g, dd, bq) ((((ks) * 3 + (g)) * 25 + (dd)) * 4 + (bq))

// native vector type for nontemporal builtins (HIP float4 class is rejected)
typedef float nf4 __attribute__((ext_vector_type(4)));

// ---------------------------------------------------------------------------
// k_init: tf==1: h0 + barrier ctrs (+tail zero). tf==0: full zero + WT + h0.
// ---------------------------------------------------------------------------
__global__ __launch_bounds__(256) void k_init(const float* __restrict__ W_hh,
                                              const float* __restrict__ W_ih,
                                              const float* __restrict__ enc_hidden,
                                              const int* __restrict__ tf_p,
                                              float4* __restrict__ out4, int n4,
                                              float* __restrict__ ws) {
    const int tf = tf_p[0];
    const int z0 = tf ? START4 : 0;          // first out4 index to zero
    const int nz = (n4 > z0) ? (n4 - z0) : 0;
    const int nT = tf ? 0 : 480000;          // transpose regions only for fallback
    const int R1 = nz + nT;
    const int R2 = R1 + nT;
    const int R3 = R2 + 25600;
    const int R4 = R3 + 512;
    int stride = gridDim.x * 256;
    for (int i = blockIdx.x * 256 + threadIdx.x; i < R4; i += stride) {
        if (i < nz) {
            out4[z0 + i] = make_float4(0.f, 0.f, 0.f, 0.f);
        } else if (i < R1) {
            int r = i - nz;
            int k = r / 1200, j = r % 1200;
            ws[WT_HH_OFF + r] = W_hh[(size_t)j * Hsz + k];
        } else if (i < R2) {
            int r = i - R1;
            int k = r / 1200, j = r % 1200;
            ws[WT_IH_OFF + r] = W_ih[(size_t)j * Dsz + k];
        } else if (i < R3) {
            int r = i - R2;
            int k = r >> 6, B = r & 63;
            // per-bg ping buffer, layout float4[k4][b] within group
            ws[HQ_OFF + (B >> 2) * 3200 + (((k >> 2) << 2) + (B & 3)) * 4 + (k & 3)]
                = enc_hidden[B * Hsz + k];
        } else {
            ((unsigned*)(ws + CTR_OFF))[i - R3] = 0u;
        }
    }
}

// ---------------------------------------------------------------------------
// k_gi (tf==1 only): gi[t][j][b] = (x_t[b] @ W_ih^T)[j], tiled GEMM.
// 512 threads (8 waves -> 2/SIMD for latency hiding) + unroll-4 k-loop (MLP).
// ---------------------------------------------------------------------------
__global__ __launch_bounds__(512) void k_gi(const int* __restrict__ tgt,
                                            const int* __restrict__ slot_p,
                                            const int* __restrict__ tf_p,
                                            const float* __restrict__ embedding,
                                            const float* __restrict__ slot_emb,
                                            const float* __restrict__ W_ih,
                                            float* __restrict__ gi) {
    if (tf_p[0] == 0) return;
    __shared__ float4 xs[100 * 64];   // 102.4 KB, [k4][b]

    int t  = blockIdx.x >> 4;
    int jc = blockIdx.x & 15;
    int tid = threadIdx.x;
    int lane = tid & 63, wv = tid >> 6;   // wv 0..7

    {
        int bb = tid & 63, q = tid >> 6;
        const float* src = (t == 0)
            ? (slot_emb + (size_t)slot_p[0] * Dsz)
            : (embedding + (size_t)tgt[bb * Lsz + (t - 1)] * Dsz);
        const float4* src4 = (const float4*)src;
        for (int k4 = q; k4 < 100; k4 += 8) xs[k4 * 64 + bb] = src4[k4];
    }
    __syncthreads();

    for (int g = wv; g < 19; g += 8) {
        int j0l = g * 4;
        int nj = (j0l + 4 <= 75) ? 4 : (75 - j0l);
        int j0 = jc * 75 + j0l;
        const float4* w0 = (const float4*)(W_ih + (size_t)(j0 + 0) * Dsz);
        const float4* w1 = (const float4*)(W_ih + (size_t)(j0 + ((nj > 1) ? 1 : 0)) * Dsz);
        const float4* w2 = (const float4*)(W_ih + (size_t)(j0 + ((nj > 2) ? 2 : 0)) * Dsz);
        const float4* w3 = (const float4*)(W_ih + (size_t)(j0 + ((nj > 3) ? 3 : 0)) * Dsz);
        float a0 = 0.f, a1 = 0.f, a2 = 0.f, a3 = 0.f;
        #pragma unroll 4
        for (int k4 = 0; k4 < 100; ++k4) {
            float4 xv = xs[k4 * 64 + lane];
            float4 r0 = w0[k4], r1 = w1[k4], r2 = w2[k4], r3 = w3[k4];
            a0 = fmaf(r0.x, xv.x, a0); a0 = fmaf(r0.y, xv.y, a0);
            a0 = fmaf(r0.z, xv.z, a0); a0 = fmaf(r0.w, xv.w, a0);
            a1 = fmaf(r1.x, xv.x, a1); a1 = fmaf(r1.y, xv.y, a1);
            a1 = fmaf(r1.z, xv.z, a1); a1 = fmaf(r1.w, xv.w, a1);
            a2 = fmaf(r2.x, xv.x, a2); a2 = fmaf(r2.y, xv.y, a2);
            a2 = fmaf(r2.z, xv.z, a2); a2 = fmaf(r2.w, xv.w, a2);
            a3 = fmaf(r3.x, xv.x, a3); a3 = fmaf(r3.y, xv.y, a3);
            a3 = fmaf(r3.z, xv.z, a3); a3 = fmaf(r3.w, xv.w, a3);
        }
        float* go = gi + ((size_t)t * H3 + j0) * 64 + lane;
        go[0] = a0;
        if (nj > 1) go[64] = a1;
        if (nj > 2) go[128] = a2;
        if (nj > 3) go[192] = a3;
    }
}

// ---------------------------------------------------------------------------
// k_chain: tf==1: 256 blocks = 16 batch-groups (4 b each) x 16 d-groups.
// Per-bg 16-block barrier, R5 protocol (tid0-only poll): widening the IF
// poller set to 13 waves (R6) congested the fabric, +83 us. Keep pollers=1.
// tf==0: blocks 0..63 run independent per-batch full decode (unchanged).
// ---------------------------------------------------------------------------
struct SmemChain {
    float4 W4[75 * 101];    // 121.2 KB  W_hh slice rows (padded to 101 float4)
    float4 h4[400];         //   6.4 KB  h staged [k4][b] for the 4 batches
    float  part[KS * 300];  //  21.6 KB  [ks][gate][dd][bq]
};
struct SmemFallback {
    float part_i[3 * H3];
    float part_h[3 * H3];
    float hx[Hsz];
    float xv[Dsz];
    float sL[Ssz];
    float redv[15];
    int   redi[15];
    float bc_max, bc_sum;
    int   bc_idx;
};
union SmemU { SmemChain c; SmemFallback f; };

__device__ __forceinline__ float sigmoidf_(float x) { return 1.f / (1.f + expf(-x)); }

__global__ __launch_bounds__(960) void k_chain(const float* __restrict__ ws_ro,
                                               const float* __restrict__ gi,
                                               const float* __restrict__ W_hh,
                                               const float* __restrict__ enc_hidden,
                                               const float* __restrict__ enc_out,
                                               const int* __restrict__ lens,
                                               const int* __restrict__ uttrs,
                                               const int* __restrict__ slot_p,
                                               const int* __restrict__ tf_p,
                                               const float* __restrict__ embedding,
                                               const float* __restrict__ slot_emb,
                                               const float* __restrict__ b_ih,
                                               const float* __restrict__ b_hh,
                                               float* __restrict__ ws_rw,
                                               float* __restrict__ h_all,
                                               float* __restrict__ out_probs,
                                               float* __restrict__ preds_out) {
    __shared__ SmemU sm;
    const int tid = threadIdx.x;
    const int tf  = tf_p[0];

    if (tf != 0) {
        // ================= grouped h-chain =================
        const int bg = blockIdx.x & 15;      // batch group (4 batches)
        const int dg = blockIdx.x >> 4;      // d group (25 dims)
        const int D0 = dg * 25;
        unsigned* ctr = (unsigned*)(ws_rw + CTR_OFF) + bg * 32;

        // preload W_hh slice: rows r = g*25+dd (g gate, dd local dim), padded LDS
        for (int i = tid; i < 7500; i += 960) {
            int r = i / 100, k4 = i % 100;
            int g = r / 25, dd = r % 25;
            sm.c.W4[r * 101 + k4] =
                ((const float4*)(W_hh + (size_t)(g * Hsz + D0 + dd) * Hsz))[k4];
        }

        // GEMV thread geometry (tid < 900): (ks, dd, bp)
        const int gks = tid / 50;
        const int gidx = tid % 50;
        const int gbp = gidx & 1;
        const int gdd = gidx >> 1;
        const int gk4b = (gks * 100) / KS;
        const int gk4e = ((gks + 1) * 100) / KS;
        const int gbq0 = gbp << 1;

        // finalize unit: one (dd,bq) per thread, tids 0..99 (waves 0 and 1)
        const bool is_fin = (tid < 100);
        const int  fbq = tid & 3, fdd = tid >> 2;
        const int  fd  = D0 + fdd;
        float g1r = 0.f, g1z = 0.f, g1n = 0.f;   // gi for current step
        float g2r = 0.f, g2z = 0.f, g2n = 0.f;   // gi prefetch for next step
        float bir = 0.f, biz = 0.f, bin = 0.f;
        float bhr = 0.f, bhz = 0.f, bhn = 0.f;
        if (is_fin) {
            bir = b_ih[fd]; biz = b_ih[fd + Hsz]; bin = b_ih[fd + 2 * Hsz];
            bhr = b_hh[fd]; bhz = b_hh[fd + Hsz]; bhn = b_hh[fd + 2 * Hsz];
            const float* gp = gi + (size_t)fd * 64 + (bg * 4 + fbq);
            g1r = gp[0];
            g1z = gp[(size_t)Hsz * 64];
            g1n = gp[(size_t)2 * Hsz * 64];
        }
        __syncthreads();

        for (int t = 0; t < Lsz; ++t) {
            const unsigned long long* hq8 = (const unsigned long long*)
                (ws_ro + HQ_OFF + (size_t)(bg * 2 + (t & 1)) * 1600);
            float* hq_nxt = ws_rw + HQ_OFF + (size_t)(bg * 2 + ((t & 1) ^ 1)) * 1600;

            // stage h via cache-bypassing loads (fresh from IF, no inv needed)
            unsigned long long* h8 = (unsigned long long*)sm.c.h4;
            if (tid < 800)
                h8[tid] = __hip_atomic_load(hq8 + tid, __ATOMIC_RELAXED,
                                            __HIP_MEMORY_SCOPE_AGENT);
            __syncthreads();

            // gi(t+1) prefetch issued early: L2 latency hides under the GEMV
            if (is_fin && t + 1 < Lsz) {
                const float* gp = gi + ((size_t)(t + 1) * H3 + fd) * 64
                                + (bg * 4 + fbq);
                g2r = gp[0];
                g2z = gp[(size_t)Hsz * 64];
                g2n = gp[(size_t)2 * Hsz * 64];
            }

            // GEMV partials: 900 threads (14 waves), 3 gate-rows x 2 batches
            // per thread over a ~5.6-k4 slice. 5 LDS reads per 24 FMA.
            if (tid < 900) {
                const float4* Wr = sm.c.W4 + (0 * 25 + gdd) * 101;
                const float4* Wz = sm.c.W4 + (1 * 25 + gdd) * 101;
                const float4* Wn = sm.c.W4 + (2 * 25 + gdd) * 101;
                float4 ar0 = make_float4(0.f, 0.f, 0.f, 0.f), ar1 = ar0;
                float4 az0 = ar0, az1 = ar0, an0 = ar0, an1 = ar0;
                for (int k4 = gk4b; k4 < gk4e; ++k4) {
                    float4 h0 = sm.c.h4[(k4 << 2) | gbq0];
                    float4 h1 = sm.c.h4[(k4 << 2) | gbq0 | 1];
                    float4 wr = Wr[k4], wz = Wz[k4], wn = Wn[k4];
                    ar0.x = fmaf(wr.x, h0.x, ar0.x); ar0.y = fmaf(wr.y, h0.y, ar0.y);
                    ar0.z = fmaf(wr.z, h0.z, ar0.z); ar0.w = fmaf(wr.w, h0.w, ar0.w);
                    ar1.x = fmaf(wr.x, h1.x, ar1.x); ar1.y = fmaf(wr.y, h1.y, ar1.y);
                    ar1.z = fmaf(wr.z, h1.z, ar1.z); ar1.w = fmaf(wr.w, h1.w, ar1.w);
                    az0.x = fmaf(wz.x, h0.x, az0.x); az0.y = fmaf(wz.y, h0.y, az0.y);
                    az0.z = fmaf(wz.z, h0.z, az0.z); az0.w = fmaf(wz.w, h0.w, az0.w);
                    az1.x = fmaf(wz.x, h1.x, az1.x); az1.y = fmaf(wz.y, h1.y, az1.y);
                    az1.z = fmaf(wz.z, h1.z, az1.z); az1.w = fmaf(wz.w, h1.w, az1.w);
                    an0.x = fmaf(wn.x, h0.x, an0.x); an0.y = fmaf(wn.y, h0.y, an0.y);
                    an0.z = fmaf(wn.z, h0.z, an0.z); an0.w = fmaf(wn.w, h0.w, an0.w);
                    an1.x = fmaf(wn.x, h1.x, an1.x); an1.y = fmaf(wn.y, h1.y, an1.y);
                    an1.z = fmaf(wn.z, h1.z, an1.z); an1.w = fmaf(wn.w, h1.w, an1.w);
                }
                sm.c.part[PIDX(gks, 0, gdd, gbq0)]     = (ar0.x + ar0.y) + (ar0.z + ar0.w);
                sm.c.part[PIDX(gks, 0, gdd, gbq0 | 1)] = (ar1.x + ar1.y) + (ar1.z + ar1.w);
                sm.c.part[PIDX(gks, 1, gdd, gbq0)]     = (az0.x + az0.y) + (az0.z + az0.w);
                sm.c.part[PIDX(gks, 1, gdd, gbq0 | 1)] = (az1.x + az1.y) + (az1.z + az1.w);
                sm.c.part[PIDX(gks, 2, gdd, gbq0)]     = (an0.x + an0.y) + (an0.z + an0.w);
                sm.c.part[PIDX(gks, 2, gdd, gbq0 | 1)] = (an1.x + an1.y) + (an1.z + an1.w);
            }
            __syncthreads();

            // finalize: waves 0+1, one (dd,bq) unit per thread, sum 18 k-splits
            if (is_fin) {
                float ghr = bhr, ghz = bhz, ghn = bhn;
                #pragma unroll
                for (int ks = 0; ks < KS; ++ks) {
                    ghr += sm.c.part[PIDX(ks, 0, fdd, fbq)];
                    ghz += sm.c.part[PIDX(ks, 1, fdd, fbq)];
                    ghn += sm.c.part[PIDX(ks, 2, fdd, fbq)];
                }
                float rr = sigmoidf_(g1r + bir + ghr);
                float zz = sigmoidf_(g1z + biz + ghz);
                float nn = tanhf(g1n + bin + rr * ghn);
                int hidx = (((fd >> 2) << 2) | fbq) * 4 + (fd & 3);
                float hp = ((const float*)sm.c.h4)[hidx];
                float hv = (1.f - zz) * nn + zz * hp;
                // device-visible (IF) store: peers read via bypass loads
                __hip_atomic_store(&hq_nxt[hidx], hv, __ATOMIC_RELAXED,
                                   __HIP_MEMORY_SCOPE_AGENT);
                h_all[(size_t)(bg * 4 + fbq) * (Lsz * Hsz)
                      + (size_t)t * Hsz + fd] = hv;
                g1r = g2r; g1z = g2z; g1n = g2n;
            }

            if (t < Lsz - 1) {
                __syncthreads();
                // one release-add per finalize wave: each wave's release drains
                // its OWN h stores (vmcnt is per-wave) before publishing at IF
                if (tid == 0 || tid == 64) {
                    __hip_atomic_fetch_add(ctr, 1u, __ATOMIC_RELEASE,
                                           __HIP_MEMORY_SCOPE_AGENT);
                }
                if (tid == 0) {
                    unsigned target = 2u * (unsigned)DGRP * (t + 1);
                    while (__hip_atomic_load(ctr, __ATOMIC_RELAXED,
                                             __HIP_MEMORY_SCOPE_AGENT) < target) {
                        __builtin_amdgcn_s_sleep(1);
                    }
                }
                __syncthreads();
            }
        }
        return;
    }

    // ================= tf==0 fallback: per-batch independent decode =========
    if (blockIdx.x >= Bsz) return;
    const int b    = blockIdx.x;
    const int lane = tid & 63;
    const int w    = tid >> 6;          // 0..14
    const int jc   = tid % 300;
    const int ksf  = tid / 300;
    const int kbeg = ksf * 134;
    const int kend = (ksf == 2) ? Hsz : kbeg + 134;
    const int len  = lens[b];

    const float4* WTH4 = (const float4*)(ws_ro + WT_HH_OFF);
    const float4* WTI4 = (const float4*)(ws_ro + WT_IH_OFF);

    if (tid < Hsz) {
        sm.f.hx[tid] = enc_hidden[b * Hsz + tid];
        sm.f.xv[tid] = slot_emb[(size_t)slot_p[0] * Dsz + tid];
    }
    __syncthreads();

    for (int t = 0; t < Lsz; ++t) {
        if (tid < 900) {
            float4 ai = make_float4(0.f, 0.f, 0.f, 0.f);
            float4 ah = make_float4(0.f, 0.f, 0.f, 0.f);
            for (int k = kbeg; k < kend; ++k) {
                float4 wi = WTI4[(size_t)k * 300 + jc];
                float4 wh = WTH4[(size_t)k * 300 + jc];
                float x = sm.f.xv[k], h = sm.f.hx[k];
                ai.x = fmaf(wi.x, x, ai.x); ai.y = fmaf(wi.y, x, ai.y);
                ai.z = fmaf(wi.z, x, ai.z); ai.w = fmaf(wi.w, x, ai.w);
                ah.x = fmaf(wh.x, h, ah.x); ah.y = fmaf(wh.y, h, ah.y);
                ah.z = fmaf(wh.z, h, ah.z); ah.w = fmaf(wh.w, h, ah.w);
            }
            ((float4*)sm.f.part_i)[ksf * 300 + jc] = ai;
            ((float4*)sm.f.part_h)[ksf * 300 + jc] = ah;
        }
        __syncthreads();

        if (tid < Hsz) {
            int d = tid;
            float i_r = sm.f.part_i[d]           + sm.f.part_i[H3 + d]           + sm.f.part_i[2 * H3 + d]           + b_ih[d];
            float i_z = sm.f.part_i[d + Hsz]     + sm.f.part_i[H3 + d + Hsz]     + sm.f.part_i[2 * H3 + d + Hsz]     + b_ih[d + Hsz];
            float i_n = sm.f.part_i[d + 2 * Hsz] + sm.f.part_i[H3 + d + 2 * Hsz] + sm.f.part_i[2 * H3 + d + 2 * Hsz] + b_ih[d + 2 * Hsz];
            float h_r = sm.f.part_h[d]           + sm.f.part_h[H3 + d]           + sm.f.part_h[2 * H3 + d]           + b_hh[d];
            float h_z = sm.f.part_h[d + Hsz]     + sm.f.part_h[H3 + d + Hsz]     + sm.f.part_h[2 * H3 + d + Hsz]     + b_hh[d + Hsz];
            float h_n = sm.f.part_h[d + 2 * Hsz] + sm.f.part_h[H3 + d + 2 * Hsz] + sm.f.part_h[2 * H3 + d + 2 * Hsz] + b_hh[d + 2 * Hsz];
            float r = sigmoidf_(i_r + h_r);
            float z = sigmoidf_(i_z + h_z);
            float n = tanhf(i_n + r * h_n);
            sm.f.hx[d] = (1.f - z) * n + z * sm.f.hx[d];
        }
        __syncthreads();

        const float4* hx4 = (const float4*)sm.f.hx;
        for (int s = w; s < len; s += 15) {
            const float4* e4 = (const float4*)(enc_out + ((size_t)b * Ssz + s) * Hsz);
            float4 ev = e4[lane];
            float4 hv = hx4[lane];
            float acc = ev.x * hv.x + ev.y * hv.y + ev.z * hv.z + ev.w * hv.w;
            if (lane < 36) {
                float4 ev2 = e4[64 + lane];
                float4 hv2 = hx4[64 + lane];
                acc += ev2.x * hv2.x + ev2.y * hv2.y + ev2.z * hv2.z + ev2.w * hv2.w;
            }
            #pragma unroll
            for (int off = 32; off >= 1; off >>= 1) acc += __shfl_xor(acc, off, 64);
            if (lane == 0) sm.f.sL[s] = acc;
        }
        __syncthreads();

        float bv = -INFINITY; int bi = 0x7fffffff;
        for (int s = tid; s < len; s += 960) {
            float v = sm.f.sL[s];
            if (v > bv || (v == bv && s < bi)) { bv = v; bi = s; }
        }
        #pragma unroll
        for (int off = 32; off >= 1; off >>= 1) {
            float ov = __shfl_xor(bv, off, 64);
            int   oi = __shfl_xor(bi, off, 64);
            if (ov > bv || (ov == bv && oi < bi)) { bv = ov; bi = oi; }
        }
        if (lane == 0) { sm.f.redv[w] = bv; sm.f.redi[w] = bi; }
        __syncthreads();
        if (tid == 0) {
            float mv = sm.f.redv[0]; int mi = sm.f.redi[0];
            for (int i = 1; i < 15; ++i)
                if (sm.f.redv[i] > mv || (sm.f.redv[i] == mv && sm.f.redi[i] < mi)) {
                    mv = sm.f.redv[i]; mi = sm.f.redi[i];
                }
            sm.f.bc_max = mv; sm.f.bc_idx = mi;
        }
        __syncthreads();
        float maxv = sm.f.bc_max;
        int   amax = sm.f.bc_idx;

        float ls = 0.f;
        for (int s = tid; s < len; s += 960) {
            float e = expf(sm.f.sL[s] - maxv);
            sm.f.sL[s] = e;
            ls += e;
        }
        #pragma unroll
        for (int off = 32; off >= 1; off >>= 1) ls += __shfl_xor(ls, off, 64);
        if (lane == 0) sm.f.redv[w] = ls;
        __syncthreads();
        if (tid == 0) {
            float sms = 0.f;
            for (int i = 0; i < 15; ++i) sms += sm.f.redv[i];
            sm.f.bc_sum = sms;
        }
        __syncthreads();
        float sum = sm.f.bc_sum;

        float* orow = out_probs + (size_t)b * (Lsz * Vsz) + (size_t)t * Vsz;
        for (int s = tid; s < len; s += 960) {
            atomicAdd(&orow[uttrs[b * Ssz + s]], sm.f.sL[s] / sum);
        }

        int predtok = uttrs[b * Ssz + amax];
        if (tid == 0) preds_out[(size_t)t * Bsz + b] = (float)predtok;
        __syncthreads();
        if (tid < Dsz) sm.f.xv[tid] = embedding[(size_t)predtok * Dsz + tid];
        __syncthreads();
    }
}

// ---------------------------------------------------------------------------
// Batched scores (tf==1), shuffle-free: 256 blocks = (b, s-quarter of 128).
// 512 threads = (s-tile of 2) x (t-pair {tp, tp+8}); acc in registers,
// h broadcast from pad-101 LDS. 8 waves/CU -> 2/SIMD latency hiding.
// ---------------------------------------------------------------------------
__global__ __launch_bounds__(512) void k_scores(const float* __restrict__ h_all,
                                                const float* __restrict__ enc_out,
                                                const int* __restrict__ lens,
                                                const int* __restrict__ tf_p,
                                                float* __restrict__ scores_all) {
    if (tf_p[0] == 0) return;
    __shared__ float4 hS[Lsz * 101];   // 25.9 KB, padded stride

    int b  = blockIdx.x >> 2;
    int sc = blockIdx.x & 3;
    int tid = threadIdx.x;
    int len = lens[b];
    int s0 = sc * 128;
    if (s0 >= len) return;             // whole chunk masked downstream

    const float4* h4g = (const float4*)(h_all + (size_t)b * (Lsz * Hsz));
    for (int i = tid; i < Lsz * 100; i += 512) {
        int t = i / 100, k4 = i % 100;
        hS[t * 101 + k4] = h4g[i];
    }
    __syncthreads();

    int stile = tid >> 3;              // 0..63
    int tp    = tid & 7;               // 0..7
    int t0 = tp, t1 = tp + 8;
    int sbase = s0 + stile * 2;

    const float4* e0 = (const float4*)(enc_out + ((size_t)b * Ssz + sbase + 0) * Hsz);
    const float4* e1 = (const float4*)(enc_out + ((size_t)b * Ssz + sbase + 1) * Hsz);
    const float4* h0p = hS + t0 * 101;
    const float4* h1p = hS + t1 * 101;

    float a00 = 0.f, a01 = 0.f;        // t0 x {s0, s1}
    float a10 = 0.f, a11 = 0.f;        // t1 x {s0, s1}
    #pragma unroll 4
    for (int k4 = 0; k4 < 100; ++k4) {
        float4 v0 = e0[k4], v1 = e1[k4];
        float4 h0 = h0p[k4], h1 = h1p[k4];
        a00 = fmaf(v0.x, h0.x, a00); a00 = fmaf(v0.y, h0.y, a00);
        a00 = fmaf(v0.z, h0.z, a00); a00 = fmaf(v0.w, h0.w, a00);
        a01 = fmaf(v1.x, h0.x, a01); a01 = fmaf(v1.y, h0.y, a01);
        a01 = fmaf(v1.z, h0.z, a01); a01 = fmaf(v1.w, h0.w, a01);
        a10 = fmaf(v0.x, h1.x, a10); a10 = fmaf(v0.y, h1.y, a10);
        a10 = fmaf(v0.z, h1.z, a10); a10 = fmaf(v0.w, h1.w, a10);
        a11 = fmaf(v1.x, h1.x, a11); a11 = fmaf(v1.y, h1.y, a11);
        a11 = fmaf(v1.z, h1.z, a11); a11 = fmaf(v1.w, h1.w, a11);
    }

    float2 r0 = make_float2(a00, a01);
    float2 r1 = make_float2(a10, a11);
    *(float2*)(scores_all + (size_t)t0 * (Bsz * Ssz) + (size_t)b * Ssz + sbase) = r0;
    *(float2*)(scores_all + (size_t)t1 * (Bsz * Ssz) + (size_t)b * Ssz + sbase) = r1;
}

// ---------------------------------------------------------------------------
// Batched softmax + LDS-vocab scatter + argmax (tf==1): one block per (t,b).
// Accumulates pointer dist in 128 KB LDS, streams full row out (no zeroing,
// no global atomics).
// ---------------------------------------------------------------------------
__global__ __launch_bounds__(256) void k_softmax_all(const float* __restrict__ scores_all,
                                                     const int* __restrict__ lens,
                                                     const int* __restrict__ uttrs,
                                                     const int* __restrict__ tf_p,
                                                     float* __restrict__ out_probs,
                                                     float* __restrict__ preds_out) {
    if (tf_p[0] == 0) return;
    __shared__ float4 vb4[Vsz / 4];   // 128 KB vocab accumulator
    __shared__ float sL[Ssz];
    __shared__ float redv[4];
    __shared__ int   redi[4];
    __shared__ float bc_max, bc_sum;
    __shared__ int   bc_idx;

    int t = blockIdx.x >> 6;
    int b = blockIdx.x & 63;
    int tid = threadIdx.x;
    int lane = tid & 63, w = tid >> 6;
    int len = lens[b];
    const float* srow = scores_all + (size_t)t * (Bsz * Ssz) + b * Ssz;

    float4 z4 = make_float4(0.f, 0.f, 0.f, 0.f);
    for (int i = tid; i < Vsz / 4; i += 256) vb4[i] = z4;

    for (int s = tid; s < len; s += 256) sL[s] = srow[s];
    __syncthreads();

    float bv = -INFINITY; int bi = 0x7fffffff;
    for (int s = tid; s < len; s += 256) {
        float v = sL[s];
        if (v > bv || (v == bv && s < bi)) { bv = v; bi = s; }
    }
    #pragma unroll
    for (int off = 32; off >= 1; off >>= 1) {
        float ov = __shfl_xor(bv, off, 64);
        int   oi = __shfl_xor(bi, off, 64);
        if (ov > bv || (ov == bv && oi < bi)) { bv = ov; bi = oi; }
    }
    if (lane == 0) { redv[w] = bv; redi[w] = bi; }
    __syncthreads();
    if (tid == 0) {
        float mv = redv[0]; int mi = redi[0];
        for (int i = 1; i < 4; ++i)
            if (redv[i] > mv || (redv[i] == mv && redi[i] < mi)) { mv = redv[i]; mi = redi[i]; }
        bc_max = mv; bc_idx = mi;
    }
    __syncthreads();
    float maxv = bc_max;
    int   amax = bc_idx;

    float ls = 0.f;
    for (int s = tid; s < len; s += 256) {
        float e = expf(sL[s] - maxv);
        sL[s] = e;
        ls += e;
    }
    #pragma unroll
    for (int off = 32; off >= 1; off >>= 1) ls += __shfl_xor(ls, off, 64);
    if (lane == 0) redv[w] = ls;
    __syncthreads();
    if (tid == 0) bc_sum = redv[0] + redv[1] + redv[2] + redv[3];
    __syncthreads();
    float sum = bc_sum;

    float* vbf = (float*)vb4;
    for (int s = tid; s < len; s += 256) {
        atomicAdd(&vbf[uttrs[b * Ssz + s]], sL[s] / sum);
    }
    __syncthreads();

    // stream the full vocab row out nontemporally (native vector type)
    const nf4* vbn = (const nf4*)vb4;
    nf4* orow4 = (nf4*)(out_probs + (size_t)b * (Lsz * Vsz) + (size_t)t * Vsz);
    for (int i = tid; i < Vsz / 4; i += 256)
        __builtin_nontemporal_store(vbn[i], &orow4[i]);

    if (tid == 0) preds_out[(size_t)t * Bsz + b] = (float)uttrs[b * Ssz + amax];
}

// ---------------------------------------------------------------------------
extern "C" void kernel_launch(void* const* d_in, const int* in_sizes, int n_in,
                              void* d_out, int out_size, void* d_ws, size_t ws_size,
                              hipStream_t stream) {
    const float* enc_hidden = (const float*)d_in[0];
    const float* enc_out    = (const float*)d_in[1];
    const int*   enc_lens   = (const int*)d_in[2];
    const int*   uttrs      = (const int*)d_in[3];
    const int*   tgt        = (const int*)d_in[4];
    const int*   slot_p     = (const int*)d_in[5];
    const int*   tf_p       = (const int*)d_in[6];
    const float* embedding  = (const float*)d_in[7];
    const float* slot_emb   = (const float*)d_in[8];
    const float* W_ih       = (const float*)d_in[9];
    const float* W_hh       = (const float*)d_in[10];
    const float* b_ih       = (const float*)d_in[11];
    const float* b_hh       = (const float*)d_in[12];

    float* out = (float*)d_out;
    float* ws  = (float*)d_ws;

    float* gi_all     = ws + GI_OFF;
    float* h_all      = ws + HALL_OFF;
    float* scores_all = ws + SCALL_OFF;
    float* preds_out  = out + (size_t)Bsz * Lsz * Vsz;

    int n4 = out_size >> 2;

    // 1) init: h0 + barrier ctrs (+ full zero / WT transposes only if tf==0)
    k_init<<<2048, 256, 0, stream>>>(W_hh, W_ih, enc_hidden, tf_p,
                                     (float4*)d_out, n4, ws);

    // 2) gi GEMM for all 16 steps (tf==1 only), 512 threads for TLP
    k_gi<<<256, 512, 0, stream>>>(tgt, slot_p, tf_p, embedding, slot_emb,
                                  W_ih, gi_all);

    // 3) chain (tf==1: 16 independent group-barriers; tf==0: per-batch fallback)
    k_chain<<<NBLK_CHAIN, 960, 0, stream>>>(ws, gi_all, W_hh, enc_hidden, enc_out,
                                            enc_lens, uttrs, slot_p, tf_p,
                                            embedding, slot_emb, b_ih, b_hh,
                                            ws, h_all, out, preds_out);

    // 4) batched scores + softmax/scatter (tf==1 only)
    k_scores<<<256, 512, 0, stream>>>(h_all, enc_out, enc_lens, tf_p, scores_all);
    k_softmax_all<<<1024, 256, 0, stream>>>(scores_all, enc_lens, uttrs, tf_p,
                                            out, preds_out);
}

// Round 9
// 375.562 us; speedup vs baseline: 1.4225x; 1.2178x over previous
//
#include <hip/hip_runtime.h>
#include <math.h>

// Problem dims (fixed by reference)
#define Bsz 64
#define Ssz 512
#define Hsz 400
#define Dsz 400
#define Vsz 32000
#define Lsz 16
#define H3  1200   // 3*H

// Workspace layout (float offsets)
#define WT_HH_OFF 0                 // 400*1200 transposed W_hh [k][j]  (fallback only)
#define WT_IH_OFF 480000            // 400*1200 transposed W_ih [k][j]  (fallback only)
#define HQ_OFF    0                 // tf==1 only: 16bg x 16t x 1600 floats sentinel
                                    // h-buffers (aliases WT region; disjoint paths)
#define GI_OFF    1011200           // 16*1200*64   gi[t][j][b]
#define HALL_OFF  2240000           // 64*16*400    h_all[b][t][d]
#define SCALL_OFF 2649600           // 16*64*512    scores[t][b][s]
// total 3,173,888 floats = 12.7 MB (counter removed)

#define NBG   16                    // batch groups (4 batches each)
#define DGRP  16                    // d-groups per batch-group
#define NBLK_CHAIN 256              // NBG * DGRP; 1 block/CU -> co-resident
#define KS    18                    // k-splits in the chain GEMV
#define SENT  0xFFFFFFFFu           // sentinel bit pattern (-NaN, unreachable)
#define START4 8192256              // (B*L*V + B*L)/4 : tail after preds region

// part index: [ks][gate][dd][bq]
#define PIDX(ks, g, dd, bq) ((((ks) * 3 + (g)) * 25 + (dd)) * 4 + (bq))

// native vector type for nontemporal builtins (HIP float4 class is rejected)
typedef float nf4 __attribute__((ext_vector_type(4)));

// ---------------------------------------------------------------------------
// k_init: tf==1: h0 into hbuf[0] + sentinels into hbuf[1..15].
//         tf==0: full output zero + WT transposes.
// ---------------------------------------------------------------------------
__global__ __launch_bounds__(256) void k_init(const float* __restrict__ W_hh,
                                              const float* __restrict__ W_ih,
                                              const float* __restrict__ enc_hidden,
                                              const int* __restrict__ tf_p,
                                              float4* __restrict__ out4, int n4,
                                              float* __restrict__ ws) {
    const int tf = tf_p[0];
    const int nz = tf ? 0 : n4;
    const int nT = tf ? 0 : 480000;
    const int nH = tf ? (NBG * Lsz * 1600) : 0;   // 409,600
    const int R1 = nz + nT;
    const int R2 = R1 + nT;
    const int R3 = R2 + nH;
    int stride = gridDim.x * 256;
    for (int i = blockIdx.x * 256 + threadIdx.x; i < R3; i += stride) {
        if (i < nz) {
            out4[i] = make_float4(0.f, 0.f, 0.f, 0.f);
        } else if (i < R1) {
            int r = i - nz;
            int k = r / 1200, j = r % 1200;
            ws[WT_HH_OFF + r] = W_hh[(size_t)j * Hsz + k];
        } else if (i < R2) {
            int r = i - R1;
            int k = r / 1200, j = r % 1200;
            ws[WT_IH_OFF + r] = W_ih[(size_t)j * Dsz + k];
        } else {
            // hbuf layout: [bg][t][1600]; linear index r = (bg*16+t)*1600+off
            int r = i - R2;
            int t = (r / 1600) & 15;
            if (t > 0) {
                ((unsigned*)(ws + HQ_OFF))[r] = SENT;
            } else {
                int bg  = r / 25600;          // 16*1600
                int off = r % 1600;
                int k  = ((off >> 4) << 2) | (off & 3);
                int bq = (off >> 2) & 3;
                ws[HQ_OFF + r] = enc_hidden[(bg * 4 + bq) * Hsz + k];
            }
        }
    }
}

// ---------------------------------------------------------------------------
// k_gi (tf==1 only): gi[t][j][b] = (x_t[b] @ W_ih^T)[j], tiled GEMM.
// 512 threads (8 waves -> 2/SIMD for latency hiding) + unroll-4 k-loop (MLP).
// ---------------------------------------------------------------------------
__global__ __launch_bounds__(512) void k_gi(const int* __restrict__ tgt,
                                            const int* __restrict__ slot_p,
                                            const int* __restrict__ tf_p,
                                            const float* __restrict__ embedding,
                                            const float* __restrict__ slot_emb,
                                            const float* __restrict__ W_ih,
                                            float* __restrict__ gi) {
    if (tf_p[0] == 0) return;
    __shared__ float4 xs[100 * 64];   // 102.4 KB, [k4][b]

    int t  = blockIdx.x >> 4;
    int jc = blockIdx.x & 15;
    int tid = threadIdx.x;
    int lane = tid & 63, wv = tid >> 6;   // wv 0..7

    {
        int bb = tid & 63, q = tid >> 6;
        const float* src = (t == 0)
            ? (slot_emb + (size_t)slot_p[0] * Dsz)
            : (embedding + (size_t)tgt[bb * Lsz + (t - 1)] * Dsz);
        const float4* src4 = (const float4*)src;
        for (int k4 = q; k4 < 100; k4 += 8) xs[k4 * 64 + bb] = src4[k4];
    }
    __syncthreads();

    for (int g = wv; g < 19; g += 8) {
        int j0l = g * 4;
        int nj = (j0l + 4 <= 75) ? 4 : (75 - j0l);
        int j0 = jc * 75 + j0l;
        const float4* w0 = (const float4*)(W_ih + (size_t)(j0 + 0) * Dsz);
        const float4* w1 = (const float4*)(W_ih + (size_t)(j0 + ((nj > 1) ? 1 : 0)) * Dsz);
        const float4* w2 = (const float4*)(W_ih + (size_t)(j0 + ((nj > 2) ? 2 : 0)) * Dsz);
        const float4* w3 = (const float4*)(W_ih + (size_t)(j0 + ((nj > 3) ? 3 : 0)) * Dsz);
        float a0 = 0.f, a1 = 0.f, a2 = 0.f, a3 = 0.f;
        #pragma unroll 4
        for (int k4 = 0; k4 < 100; ++k4) {
            float4 xv = xs[k4 * 64 + lane];
            float4 r0 = w0[k4], r1 = w1[k4], r2 = w2[k4], r3 = w3[k4];
            a0 = fmaf(r0.x, xv.x, a0); a0 = fmaf(r0.y, xv.y, a0);
            a0 = fmaf(r0.z, xv.z, a0); a0 = fmaf(r0.w, xv.w, a0);
            a1 = fmaf(r1.x, xv.x, a1); a1 = fmaf(r1.y, xv.y, a1);
            a1 = fmaf(r1.z, xv.z, a1); a1 = fmaf(r1.w, xv.w, a1);
            a2 = fmaf(r2.x, xv.x, a2); a2 = fmaf(r2.y, xv.y, a2);
            a2 = fmaf(r2.z, xv.z, a2); a2 = fmaf(r2.w, xv.w, a2);
            a3 = fmaf(r3.x, xv.x, a3); a3 = fmaf(r3.y, xv.y, a3);
            a3 = fmaf(r3.z, xv.z, a3); a3 = fmaf(r3.w, xv.w, a3);
        }
        float* go = gi + ((size_t)t * H3 + j0) * 64 + lane;
        go[0] = a0;
        if (nj > 1) go[64] = a1;
        if (nj > 2) go[128] = a2;
        if (nj > 3) go[192] = a3;
    }
}

// ---------------------------------------------------------------------------
// k_chain: tf==1: 256 blocks = 16 bg x 16 dg. NO counter barrier: per-(bg,t)
// single-writer sentinel h-buffers; consumers poll their OWN 8B word (distinct
// addresses -> no R6-style same-line congestion; polls self-terminate).
// 2 syncthreads/step (was 4) and zero counter RTTs.
// tf==0: blocks 0..63 run independent per-batch full decode (unchanged).
// ---------------------------------------------------------------------------
struct SmemChain {
    float4 W4[75 * 101];    // 121.2 KB  W_hh slice rows (padded to 101 float4)
    float4 h4[400];         //   6.4 KB  h staged [k4][b] for the 4 batches
    float  part[KS * 300];  //  21.6 KB  [ks][gate][dd][bq]
};
struct SmemFallback {
    float part_i[3 * H3];
    float part_h[3 * H3];
    float hx[Hsz];
    float xv[Dsz];
    float sL[Ssz];
    float redv[15];
    int   redi[15];
    float bc_max, bc_sum;
    int   bc_idx;
};
union SmemU { SmemChain c; SmemFallback f; };

__device__ __forceinline__ float sigmoidf_(float x) { return 1.f / (1.f + expf(-x)); }

__device__ __forceinline__ unsigned long long poll8(const unsigned long long* p) {
    unsigned long long v;
    for (;;) {
        v = __hip_atomic_load(p, __ATOMIC_RELAXED, __HIP_MEMORY_SCOPE_AGENT);
        if ((unsigned)v != SENT && (unsigned)(v >> 32) != SENT) return v;
        __builtin_amdgcn_s_sleep(1);
    }
}

__global__ __launch_bounds__(960) void k_chain(const float* __restrict__ ws_ro,
                                               const float* __restrict__ gi,
                                               const float* __restrict__ W_hh,
                                               const float* __restrict__ enc_hidden,
                                               const float* __restrict__ enc_out,
                                               const int* __restrict__ lens,
                                               const int* __restrict__ uttrs,
                                               const int* __restrict__ slot_p,
                                               const int* __restrict__ tf_p,
                                               const float* __restrict__ embedding,
                                               const float* __restrict__ slot_emb,
                                               const float* __restrict__ b_ih,
                                               const float* __restrict__ b_hh,
                                               float* __restrict__ ws_rw,
                                               float* __restrict__ h_all,
                                               float* __restrict__ out_probs,
                                               float* __restrict__ preds_out) {
    __shared__ SmemU sm;
    const int tid = threadIdx.x;
    const int tf  = tf_p[0];

    if (tf != 0) {
        // ================= grouped h-chain (sentinel dataflow) ==============
        const int bg = blockIdx.x & 15;      // batch group (4 batches)
        const int dg = blockIdx.x >> 4;      // d group (25 dims)
        const int D0 = dg * 25;
        const float* hq_ro = ws_ro + HQ_OFF + (size_t)bg * (Lsz * 1600);
        float*       hq_rw = ws_rw + HQ_OFF + (size_t)bg * (Lsz * 1600);

        // preload W_hh slice: rows r = g*25+dd (g gate, dd local dim), padded LDS
        for (int i = tid; i < 7500; i += 960) {
            int r = i / 100, k4 = i % 100;
            int g = r / 25, dd = r % 25;
            sm.c.W4[r * 101 + k4] =
                ((const float4*)(W_hh + (size_t)(g * Hsz + D0 + dd) * Hsz))[k4];
        }

        // GEMV thread geometry (tid < 900): (ks, dd, bp)
        const int gks = tid / 50;
        const int gidx = tid % 50;
        const int gbp = gidx & 1;
        const int gdd = gidx >> 1;
        const int gk4b = (gks * 100) / KS;
        const int gk4e = ((gks + 1) * 100) / KS;
        const int gbq0 = gbp << 1;

        // finalize unit: one (dd,bq) per thread, tids 0..99 (waves 0 and 1)
        const bool is_fin = (tid < 100);
        const int  fbq = tid & 3, fdd = tid >> 2;
        const int  fd  = D0 + fdd;
        const int  fhidx = (((fd >> 2) << 2) | fbq) * 4 + (fd & 3);
        float g1r = 0.f, g1z = 0.f, g1n = 0.f;   // gi for current step
        float g2r = 0.f, g2z = 0.f, g2n = 0.f;   // gi prefetch for next step
        float bir = 0.f, biz = 0.f, bin = 0.f;
        float bhr = 0.f, bhz = 0.f, bhn = 0.f;
        if (is_fin) {
            bir = b_ih[fd]; biz = b_ih[fd + Hsz]; bin = b_ih[fd + 2 * Hsz];
            bhr = b_hh[fd]; bhz = b_hh[fd + Hsz]; bhn = b_hh[fd + 2 * Hsz];
            const float* gp = gi + (size_t)fd * 64 + (bg * 4 + fbq);
            g1r = gp[0];
            g1z = gp[(size_t)Hsz * 64];
            g1n = gp[(size_t)2 * Hsz * 64];
        }

        // pre-stage hbuf[0] (h0, pre-written by k_init: polls succeed at once)
        if (tid < 800) {
            ((unsigned long long*)sm.c.h4)[tid] =
                poll8((const unsigned long long*)hq_ro + tid);
        }
        __syncthreads();

        for (int t = 0; t < Lsz; ++t) {
            float hpreg = 0.f;
            // own hp read BEFORE mid-sync (polls overwrite h4 after it);
            // gi(t+1) prefetch: L2 latency hides under the GEMV
            if (is_fin) {
                hpreg = ((const float*)sm.c.h4)[fhidx];
                if (t + 1 < Lsz) {
                    const float* gp = gi + ((size_t)(t + 1) * H3 + fd) * 64
                                    + (bg * 4 + fbq);
                    g2r = gp[0];
                    g2z = gp[(size_t)Hsz * 64];
                    g2n = gp[(size_t)2 * Hsz * 64];
                }
            }

            // GEMV partials: 900 threads (14 waves), 3 gate-rows x 2 batches
            // per thread over a ~5.6-k4 slice. 5 LDS reads per 24 FMA.
            if (tid < 900) {
                const float4* Wr = sm.c.W4 + (0 * 25 + gdd) * 101;
                const float4* Wz = sm.c.W4 + (1 * 25 + gdd) * 101;
                const float4* Wn = sm.c.W4 + (2 * 25 + gdd) * 101;
                float4 ar0 = make_float4(0.f, 0.f, 0.f, 0.f), ar1 = ar0;
                float4 az0 = ar0, az1 = ar0, an0 = ar0, an1 = ar0;
                for (int k4 = gk4b; k4 < gk4e; ++k4) {
                    float4 h0 = sm.c.h4[(k4 << 2) | gbq0];
                    float4 h1 = sm.c.h4[(k4 << 2) | gbq0 | 1];
                    float4 wr = Wr[k4], wz = Wz[k4], wn = Wn[k4];
                    ar0.x = fmaf(wr.x, h0.x, ar0.x); ar0.y = fmaf(wr.y, h0.y, ar0.y);
                    ar0.z = fmaf(wr.z, h0.z, ar0.z); ar0.w = fmaf(wr.w, h0.w, ar0.w);
                    ar1.x = fmaf(wr.x, h1.x, ar1.x); ar1.y = fmaf(wr.y, h1.y, ar1.y);
                    ar1.z = fmaf(wr.z, h1.z, ar1.z); ar1.w = fmaf(wr.w, h1.w, ar1.w);
                    az0.x = fmaf(wz.x, h0.x, az0.x); az0.y = fmaf(wz.y, h0.y, az0.y);
                    az0.z = fmaf(wz.z, h0.z, az0.z); az0.w = fmaf(wz.w, h0.w, az0.w);
                    az1.x = fmaf(wz.x, h1.x, az1.x); az1.y = fmaf(wz.y, h1.y, az1.y);
                    az1.z = fmaf(wz.z, h1.z, az1.z); az1.w = fmaf(wz.w, h1.w, az1.w);
                    an0.x = fmaf(wn.x, h0.x, an0.x); an0.y = fmaf(wn.y, h0.y, an0.y);
                    an0.z = fmaf(wn.z, h0.z, an0.z); an0.w = fmaf(wn.w, h0.w, an0.w);
                    an1.x = fmaf(wn.x, h1.x, an1.x); an1.y = fmaf(wn.y, h1.y, an1.y);
                    an1.z = fmaf(wn.z, h1.z, an1.z); an1.w = fmaf(wn.w, h1.w, an1.w);
                }
                sm.c.part[PIDX(gks, 0, gdd, gbq0)]     = (ar0.x + ar0.y) + (ar0.z + ar0.w);
                sm.c.part[PIDX(gks, 0, gdd, gbq0 | 1)] = (ar1.x + ar1.y) + (ar1.z + ar1.w);
                sm.c.part[PIDX(gks, 1, gdd, gbq0)]     = (az0.x + az0.y) + (az0.z + az0.w);
                sm.c.part[PIDX(gks, 1, gdd, gbq0 | 1)] = (az1.x + az1.y) + (az1.z + az1.w);
                sm.c.part[PIDX(gks, 2, gdd, gbq0)]     = (an0.x + an0.y) + (an0.z + an0.w);
                sm.c.part[PIDX(gks, 2, gdd, gbq0 | 1)] = (an1.x + an1.y) + (an1.z + an1.w);
            }
            __syncthreads();    // part ready; all h4 reads done

            // finalize: waves 0+1, one (dd,bq) unit per thread, sum 18 k-splits
            if (is_fin) {
                float ghr = bhr, ghz = bhz, ghn = bhn;
                #pragma unroll
                for (int ks = 0; ks < KS; ++ks) {
                    ghr += sm.c.part[PIDX(ks, 0, fdd, fbq)];
                    ghz += sm.c.part[PIDX(ks, 1, fdd, fbq)];
                    ghn += sm.c.part[PIDX(ks, 2, fdd, fbq)];
                }
                float rr = sigmoidf_(g1r + bir + ghr);
                float zz = sigmoidf_(g1z + biz + ghz);
                float nn = tanhf(g1n + bin + rr * ghn);
                float hv = (1.f - zz) * nn + zz * hpreg;
                if (t + 1 < Lsz) {
                    // device-visible store into the (t+1) sentinel buffer:
                    // arrival of the VALUE is the synchronization signal
                    __hip_atomic_store(&hq_rw[(size_t)(t + 1) * 1600 + fhidx], hv,
                                       __ATOMIC_RELAXED, __HIP_MEMORY_SCOPE_AGENT);
                }
                h_all[(size_t)(bg * 4 + fbq) * (Lsz * Hsz)
                      + (size_t)t * Hsz + fd] = hv;
                g1r = g2r; g1z = g2z; g1n = g2n;
            }

            if (t + 1 < Lsz) {
                // fused stage: poll own 8B word of hbuf[t+1] (distinct addrs,
                // self-terminating -> no counter hot-line congestion)
                if (tid < 800) {
                    ((unsigned long long*)sm.c.h4)[tid] =
                        poll8((const unsigned long long*)
                              (hq_ro + (size_t)(t + 1) * 1600) + tid);
                }
                __syncthreads();    // h4 ready for next step
            }
        }
        return;
    }

    // ================= tf==0 fallback: per-batch independent decode =========
    if (blockIdx.x >= Bsz) return;
    const int b    = blockIdx.x;
    const int lane = tid & 63;
    const int w    = tid >> 6;          // 0..14
    const int jc   = tid % 300;
    const int ksf  = tid / 300;
    const int kbeg = ksf * 134;
    const int kend = (ksf == 2) ? Hsz : kbeg + 134;
    const int len  = lens[b];

    const float4* WTH4 = (const float4*)(ws_ro + WT_HH_OFF);
    const float4* WTI4 = (const float4*)(ws_ro + WT_IH_OFF);

    if (tid < Hsz) {
        sm.f.hx[tid] = enc_hidden[b * Hsz + tid];
        sm.f.xv[tid] = slot_emb[(size_t)slot_p[0] * Dsz + tid];
    }
    __syncthreads();

    for (int t = 0; t < Lsz; ++t) {
        if (tid < 900) {
            float4 ai = make_float4(0.f, 0.f, 0.f, 0.f);
            float4 ah = make_float4(0.f, 0.f, 0.f, 0.f);
            for (int k = kbeg; k < kend; ++k) {
                float4 wi = WTI4[(size_t)k * 300 + jc];
                float4 wh = WTH4[(size_t)k * 300 + jc];
                float x = sm.f.xv[k], h = sm.f.hx[k];
                ai.x = fmaf(wi.x, x, ai.x); ai.y = fmaf(wi.y, x, ai.y);
                ai.z = fmaf(wi.z, x, ai.z); ai.w = fmaf(wi.w, x, ai.w);
                ah.x = fmaf(wh.x, h, ah.x); ah.y = fmaf(wh.y, h, ah.y);
                ah.z = fmaf(wh.z, h, ah.z); ah.w = fmaf(wh.w, h, ah.w);
            }
            ((float4*)sm.f.part_i)[ksf * 300 + jc] = ai;
            ((float4*)sm.f.part_h)[ksf * 300 + jc] = ah;
        }
        __syncthreads();

        if (tid < Hsz) {
            int d = tid;
            float i_r = sm.f.part_i[d]           + sm.f.part_i[H3 + d]           + sm.f.part_i[2 * H3 + d]           + b_ih[d];
            float i_z = sm.f.part_i[d + Hsz]     + sm.f.part_i[H3 + d + Hsz]     + sm.f.part_i[2 * H3 + d + Hsz]     + b_ih[d + Hsz];
            float i_n = sm.f.part_i[d + 2 * Hsz] + sm.f.part_i[H3 + d + 2 * Hsz] + sm.f.part_i[2 * H3 + d + 2 * Hsz] + b_ih[d + 2 * Hsz];
            float h_r = sm.f.part_h[d]           + sm.f.part_h[H3 + d]           + sm.f.part_h[2 * H3 + d]           + b_hh[d];
            float h_z = sm.f.part_h[d + Hsz]     + sm.f.part_h[H3 + d + Hsz]     + sm.f.part_h[2 * H3 + d + Hsz]     + b_hh[d + Hsz];
            float h_n = sm.f.part_h[d + 2 * Hsz] + sm.f.part_h[H3 + d + 2 * Hsz] + sm.f.part_h[2 * H3 + d + 2 * Hsz] + b_hh[d + 2 * Hsz];
            float r = sigmoidf_(i_r + h_r);
            float z = sigmoidf_(i_z + h_z);
            float n = tanhf(i_n + r * h_n);
            sm.f.hx[d] = (1.f - z) * n + z * sm.f.hx[d];
        }
        __syncthreads();

        const float4* hx4 = (const float4*)sm.f.hx;
        for (int s = w; s < len; s += 15) {
            const float4* e4 = (const float4*)(enc_out + ((size_t)b * Ssz + s) * Hsz);
            float4 ev = e4[lane];
            float4 hv = hx4[lane];
            float acc = ev.x * hv.x + ev.y * hv.y + ev.z * hv.z + ev.w * hv.w;
            if (lane < 36) {
                float4 ev2 = e4[64 + lane];
                float4 hv2 = hx4[64 + lane];
                acc += ev2.x * hv2.x + ev2.y * hv2.y + ev2.z * hv2.z + ev2.w * hv2.w;
            }
            #pragma unroll
            for (int off = 32; off >= 1; off >>= 1) acc += __shfl_xor(acc, off, 64);
            if (lane == 0) sm.f.sL[s] = acc;
        }
        __syncthreads();

        float bv = -INFINITY; int bi = 0x7fffffff;
        for (int s = tid; s < len; s += 960) {
            float v = sm.f.sL[s];
            if (v > bv || (v == bv && s < bi)) { bv = v; bi = s; }
        }
        #pragma unroll
        for (int off = 32; off >= 1; off >>= 1) {
            float ov = __shfl_xor(bv, off, 64);
            int   oi = __shfl_xor(bi, off, 64);
            if (ov > bv || (ov == bv && oi < bi)) { bv = ov; bi = oi; }
        }
        if (lane == 0) { sm.f.redv[w] = bv; sm.f.redi[w] = bi; }
        __syncthreads();
        if (tid == 0) {
            float mv = sm.f.redv[0]; int mi = sm.f.redi[0];
            for (int i = 1; i < 15; ++i)
                if (sm.f.redv[i] > mv || (sm.f.redv[i] == mv && sm.f.redi[i] < mi)) {
                    mv = sm.f.redv[i]; mi = sm.f.redi[i];
                }
            sm.f.bc_max = mv; sm.f.bc_idx = mi;
        }
        __syncthreads();
        float maxv = sm.f.bc_max;
        int   amax = sm.f.bc_idx;

        float ls = 0.f;
        for (int s = tid; s < len; s += 960) {
            float e = expf(sm.f.sL[s] - maxv);
            sm.f.sL[s] = e;
            ls += e;
        }
        #pragma unroll
        for (int off = 32; off >= 1; off >>= 1) ls += __shfl_xor(ls, off, 64);
        if (lane == 0) sm.f.redv[w] = ls;
        __syncthreads();
        if (tid == 0) {
            float sms = 0.f;
            for (int i = 0; i < 15; ++i) sms += sm.f.redv[i];
            sm.f.bc_sum = sms;
        }
        __syncthreads();
        float sum = sm.f.bc_sum;

        float* orow = out_probs + (size_t)b * (Lsz * Vsz) + (size_t)t * Vsz;
        for (int s = tid; s < len; s += 960) {
            atomicAdd(&orow[uttrs[b * Ssz + s]], sm.f.sL[s] / sum);
        }

        int predtok = uttrs[b * Ssz + amax];
        if (tid == 0) preds_out[(size_t)t * Bsz + b] = (float)predtok;
        __syncthreads();
        if (tid < Dsz) sm.f.xv[tid] = embedding[(size_t)predtok * Dsz + tid];
        __syncthreads();
    }
}

// ---------------------------------------------------------------------------
// Batched scores (tf==1), shuffle-free: 256 blocks = (b, s-quarter of 128).
// 512 threads = (s-tile of 2) x (t-pair {tp, tp+8}); acc in registers,
// h broadcast from pad-101 LDS. 8 waves/CU -> 2/SIMD latency hiding.
// ---------------------------------------------------------------------------
__global__ __launch_bounds__(512) void k_scores(const float* __restrict__ h_all,
                                                const float* __restrict__ enc_out,
                                                const int* __restrict__ lens,
                                                const int* __restrict__ tf_p,
                                                float* __restrict__ scores_all) {
    if (tf_p[0] == 0) return;
    __shared__ float4 hS[Lsz * 101];   // 25.9 KB, padded stride

    int b  = blockIdx.x >> 2;
    int sc = blockIdx.x & 3;
    int tid = threadIdx.x;
    int len = lens[b];
    int s0 = sc * 128;
    if (s0 >= len) return;             // whole chunk masked downstream

    const float4* h4g = (const float4*)(h_all + (size_t)b * (Lsz * Hsz));
    for (int i = tid; i < Lsz * 100; i += 512) {
        int t = i / 100, k4 = i % 100;
        hS[t * 101 + k4] = h4g[i];
    }
    __syncthreads();

    int stile = tid >> 3;              // 0..63
    int tp    = tid & 7;               // 0..7
    int t0 = tp, t1 = tp + 8;
    int sbase = s0 + stile * 2;

    const float4* e0 = (const float4*)(enc_out + ((size_t)b * Ssz + sbase + 0) * Hsz);
    const float4* e1 = (const float4*)(enc_out + ((size_t)b * Ssz + sbase + 1) * Hsz);
    const float4* h0p = hS + t0 * 101;
    const float4* h1p = hS + t1 * 101;

    float a00 = 0.f, a01 = 0.f;        // t0 x {s0, s1}
    float a10 = 0.f, a11 = 0.f;        // t1 x {s0, s1}
    #pragma unroll 4
    for (int k4 = 0; k4 < 100; ++k4) {
        float4 v0 = e0[k4], v1 = e1[k4];
        float4 h0 = h0p[k4], h1 = h1p[k4];
        a00 = fmaf(v0.x, h0.x, a00); a00 = fmaf(v0.y, h0.y, a00);
        a00 = fmaf(v0.z, h0.z, a00); a00 = fmaf(v0.w, h0.w, a00);
        a01 = fmaf(v1.x, h0.x, a01); a01 = fmaf(v1.y, h0.y, a01);
        a01 = fmaf(v1.z, h0.z, a01); a01 = fmaf(v1.w, h0.w, a01);
        a10 = fmaf(v0.x, h1.x, a10); a10 = fmaf(v0.y, h1.y, a10);
        a10 = fmaf(v0.z, h1.z, a10); a10 = fmaf(v0.w, h1.w, a10);
        a11 = fmaf(v1.x, h1.x, a11); a11 = fmaf(v1.y, h1.y, a11);
        a11 = fmaf(v1.z, h1.z, a11); a11 = fmaf(v1.w, h1.w, a11);
    }

    float2 r0 = make_float2(a00, a01);
    float2 r1 = make_float2(a10, a11);
    *(float2*)(scores_all + (size_t)t0 * (Bsz * Ssz) + (size_t)b * Ssz + sbase) = r0;
    *(float2*)(scores_all + (size_t)t1 * (Bsz * Ssz) + (size_t)b * Ssz + sbase) = r1;
}

// ---------------------------------------------------------------------------
// Batched softmax + LDS-vocab scatter + argmax (tf==1): one block per (t,b).
// Accumulates pointer dist in 128 KB LDS, streams full row out (no zeroing,
// no global atomics).
// ---------------------------------------------------------------------------
__global__ __launch_bounds__(256) void k_softmax_all(const float* __restrict__ scores_all,
                                                     const int* __restrict__ lens,
                                                     const int* __restrict__ uttrs,
                                                     const int* __restrict__ tf_p,
                                                     float* __restrict__ out_probs,
                                                     float* __restrict__ preds_out) {
    if (tf_p[0] == 0) return;
    __shared__ float4 vb4[Vsz / 4];   // 128 KB vocab accumulator
    __shared__ float sL[Ssz];
    __shared__ float redv[4];
    __shared__ int   redi[4];
    __shared__ float bc_max, bc_sum;
    __shared__ int   bc_idx;

    int t = blockIdx.x >> 6;
    int b = blockIdx.x & 63;
    int tid = threadIdx.x;
    int lane = tid & 63, w = tid >> 6;
    int len = lens[b];
    const float* srow = scores_all + (size_t)t * (Bsz * Ssz) + b * Ssz;

    float4 z4 = make_float4(0.f, 0.f, 0.f, 0.f);
    for (int i = tid; i < Vsz / 4; i += 256) vb4[i] = z4;

    for (int s = tid; s < len; s += 256) sL[s] = srow[s];
    __syncthreads();

    float bv = -INFINITY; int bi = 0x7fffffff;
    for (int s = tid; s < len; s += 256) {
        float v = sL[s];
        if (v > bv || (v == bv && s < bi)) { bv = v; bi = s; }
    }
    #pragma unroll
    for (int off = 32; off >= 1; off >>= 1) {
        float ov = __shfl_xor(bv, off, 64);
        int   oi = __shfl_xor(bi, off, 64);
        if (ov > bv || (ov == bv && oi < bi)) { bv = ov; bi = oi; }
    }
    if (lane == 0) { redv[w] = bv; redi[w] = bi; }
    __syncthreads();
    if (tid == 0) {
        float mv = redv[0]; int mi = redi[0];
        for (int i = 1; i < 4; ++i)
            if (redv[i] > mv || (redv[i] == mv && redi[i] < mi)) { mv = redv[i]; mi = redi[i]; }
        bc_max = mv; bc_idx = mi;
    }
    __syncthreads();
    float maxv = bc_max;
    int   amax = bc_idx;

    float ls = 0.f;
    for (int s = tid; s < len; s += 256) {
        float e = expf(sL[s] - maxv);
        sL[s] = e;
        ls += e;
    }
    #pragma unroll
    for (int off = 32; off >= 1; off >>= 1) ls += __shfl_xor(ls, off, 64);
    if (lane == 0) redv[w] = ls;
    __syncthreads();
    if (tid == 0) bc_sum = redv[0] + redv[1] + redv[2] + redv[3];
    __syncthreads();
    float sum = bc_sum;

    float* vbf = (float*)vb4;
    for (int s = tid; s < len; s += 256) {
        atomicAdd(&vbf[uttrs[b * Ssz + s]], sL[s] / sum);
    }
    __syncthreads();

    // stream the full vocab row out nontemporally (native vector type)
    const nf4* vbn = (const nf4*)vb4;
    nf4* orow4 = (nf4*)(out_probs + (size_t)b * (Lsz * Vsz) + (size_t)t * Vsz);
    for (int i = tid; i < Vsz / 4; i += 256)
        __builtin_nontemporal_store(vbn[i], &orow4[i]);

    if (tid == 0) preds_out[(size_t)t * Bsz + b] = (float)uttrs[b * Ssz + amax];
}

// ---------------------------------------------------------------------------
extern "C" void kernel_launch(void* const* d_in, const int* in_sizes, int n_in,
                              void* d_out, int out_size, void* d_ws, size_t ws_size,
                              hipStream_t stream) {
    const float* enc_hidden = (const float*)d_in[0];
    const float* enc_out    = (const float*)d_in[1];
    const int*   enc_lens   = (const int*)d_in[2];
    const int*   uttrs      = (const int*)d_in[3];
    const int*   tgt        = (const int*)d_in[4];
    const int*   slot_p     = (const int*)d_in[5];
    const int*   tf_p       = (const int*)d_in[6];
    const float* embedding  = (const float*)d_in[7];
    const float* slot_emb   = (const float*)d_in[8];
    const float* W_ih       = (const float*)d_in[9];
    const float* W_hh       = (const float*)d_in[10];
    const float* b_ih       = (const float*)d_in[11];
    const float* b_hh       = (const float*)d_in[12];

    float* out = (float*)d_out;
    float* ws  = (float*)d_ws;

    float* gi_all     = ws + GI_OFF;
    float* h_all      = ws + HALL_OFF;
    float* scores_all = ws + SCALL_OFF;
    float* preds_out  = out + (size_t)Bsz * Lsz * Vsz;

    int n4 = out_size >> 2;

    // 1) init: tf==1: h0 + sentinel h-buffers; tf==0: full zero + WT
    k_init<<<2048, 256, 0, stream>>>(W_hh, W_ih, enc_hidden, tf_p,
                                     (float4*)d_out, n4, ws);

    // 2) gi GEMM for all 16 steps (tf==1 only), 512 threads for TLP
    k_gi<<<256, 512, 0, stream>>>(tgt, slot_p, tf_p, embedding, slot_emb,
                                  W_ih, gi_all);

    // 3) chain (tf==1: sentinel dataflow, no counter; tf==0: per-batch fallback)
    k_chain<<<NBLK_CHAIN, 960, 0, stream>>>(ws, gi_all, W_hh, enc_hidden, enc_out,
                                            enc_lens, uttrs, slot_p, tf_p,
                                            embedding, slot_emb, b_ih, b_hh,
                                            ws, h_all, out, preds_out);

    // 4) batched scores + softmax/scatter (tf==1 only)
    k_scores<<<256, 512, 0, stream>>>(h_all, enc_out, enc_lens, tf_p, scores_all);
    k_softmax_all<<<1024, 256, 0, stream>>>(scores_all, enc_lens, uttrs, tf_p,
                                            out, preds_out);
}

// Round 10
// 366.223 us; speedup vs baseline: 1.4587x; 1.0255x over previous
//
#include <hip/hip_runtime.h>
#include <math.h>

// Problem dims (fixed by reference)
#define Bsz 64
#define Ssz 512
#define Hsz 400
#define Dsz 400
#define Vsz 32000
#define Lsz 16
#define H3  1200   // 3*H

// Workspace layout (float offsets)
#define WT_HH_OFF 0                 // 400*1200 transposed W_hh [k][j]  (fallback only)
#define WT_IH_OFF 480000            // 400*1200 transposed W_ih [k][j]  (fallback only)
#define HQ_OFF    0                 // tf==1 only: 16bg x 16t x 1600 floats sentinel
                                    // h-buffers (aliases WT region; disjoint paths)
#define GI_OFF    1011200           // 2 x 16*1200*64 gi k-half partials
#define GIP_STRIDE 1228800          // floats per k-half partial
#define HALL_OFF  3468800           // 64*16*400    h_all[b][t][d]
#define SCALL_OFF 3878400           // 16*64*512    scores[t][b][s]
// total 4,402,688 floats = 17.6 MB

#define NBG   16                    // batch groups (4 batches each)
#define DGRP  16                    // d-groups per batch-group
#define NBLK_CHAIN 256              // NBG * DGRP; 1 block/CU -> co-resident
#define KS    18                    // k-splits in the chain GEMV
#define SENT  0xFFFFFFFFu           // sentinel bit pattern (-NaN, unreachable)

// part index: [ks][gate][dd][bq]
#define PIDX(ks, g, dd, bq) ((((ks) * 3 + (g)) * 25 + (dd)) * 4 + (bq))

// native vector type for nontemporal builtins (HIP float4 class is rejected)
typedef float nf4 __attribute__((ext_vector_type(4)));

// ---------------------------------------------------------------------------
// k_init: tf==1: h0 into hbuf[0] + sentinels into hbuf[1..15].
//         tf==0: full output zero + WT transposes.
// ---------------------------------------------------------------------------
__global__ __launch_bounds__(256) void k_init(const float* __restrict__ W_hh,
                                              const float* __restrict__ W_ih,
                                              const float* __restrict__ enc_hidden,
                                              const int* __restrict__ tf_p,
                                              float4* __restrict__ out4, int n4,
                                              float* __restrict__ ws) {
    const int tf = tf_p[0];
    const int nz = tf ? 0 : n4;
    const int nT = tf ? 0 : 480000;
    const int nH = tf ? (NBG * Lsz * 1600) : 0;   // 409,600
    const int R1 = nz + nT;
    const int R2 = R1 + nT;
    const int R3 = R2 + nH;
    int stride = gridDim.x * 256;
    for (int i = blockIdx.x * 256 + threadIdx.x; i < R3; i += stride) {
        if (i < nz) {
            out4[i] = make_float4(0.f, 0.f, 0.f, 0.f);
        } else if (i < R1) {
            int r = i - nz;
            int k = r / 1200, j = r % 1200;
            ws[WT_HH_OFF + r] = W_hh[(size_t)j * Hsz + k];
        } else if (i < R2) {
            int r = i - R1;
            int k = r / 1200, j = r % 1200;
            ws[WT_IH_OFF + r] = W_ih[(size_t)j * Dsz + k];
        } else {
            // hbuf layout: [bg][t][1600]; linear index r = (bg*16+t)*1600+off
            int r = i - R2;
            int t = (r / 1600) & 15;
            if (t > 0) {
                ((unsigned*)(ws + HQ_OFF))[r] = SENT;
            } else {
                int bg  = r / 25600;          // 16*1600
                int off = r % 1600;
                int k  = ((off >> 4) << 2) | (off & 3);
                int bq = (off >> 2) & 3;
                ws[HQ_OFF + r] = enc_hidden[(bg * 4 + bq) * Hsz + k];
            }
        }
    }
}

// ---------------------------------------------------------------------------
// k_gi (tf==1 only): gi partials [kq][t][j][b] = half-K products.
// 512 blocks = (t, jc, k-half); xs 51.2 KB -> 2 blocks/CU, 16 waves/CU
// (R9 lesson: grid 256 capped residency at 1 block/CU -> latency-exposed).
// k_chain sums the two partials during its gi prefetch.
// ---------------------------------------------------------------------------
__global__ __launch_bounds__(512) void k_gi(const int* __restrict__ tgt,
                                            const int* __restrict__ slot_p,
                                            const int* __restrict__ tf_p,
                                            const float* __restrict__ embedding,
                                            const float* __restrict__ slot_emb,
                                            const float* __restrict__ W_ih,
                                            float* __restrict__ gi) {
    if (tf_p[0] == 0) return;
    __shared__ float4 xs[50 * 64];   // 51.2 KB, [k4][b] (half K)

    int kq = blockIdx.x & 1;
    int jc = (blockIdx.x >> 1) & 15;
    int t  = blockIdx.x >> 5;
    int tid = threadIdx.x;
    int lane = tid & 63, wv = tid >> 6;   // wv 0..7

    {
        int bb = tid & 63, q = tid >> 6;
        const float* src = (t == 0)
            ? (slot_emb + (size_t)slot_p[0] * Dsz)
            : (embedding + (size_t)tgt[bb * Lsz + (t - 1)] * Dsz);
        const float4* src4 = (const float4*)src + kq * 50;
        for (int k4 = q; k4 < 50; k4 += 8) xs[k4 * 64 + bb] = src4[k4];
    }
    __syncthreads();

    for (int g = wv; g < 19; g += 8) {
        int j0l = g * 4;
        int nj = (j0l + 4 <= 75) ? 4 : (75 - j0l);
        int j0 = jc * 75 + j0l;
        const float4* w0 = (const float4*)(W_ih + (size_t)(j0 + 0) * Dsz) + kq * 50;
        const float4* w1 = (const float4*)(W_ih + (size_t)(j0 + ((nj > 1) ? 1 : 0)) * Dsz) + kq * 50;
        const float4* w2 = (const float4*)(W_ih + (size_t)(j0 + ((nj > 2) ? 2 : 0)) * Dsz) + kq * 50;
        const float4* w3 = (const float4*)(W_ih + (size_t)(j0 + ((nj > 3) ? 3 : 0)) * Dsz) + kq * 50;
        float a0 = 0.f, a1 = 0.f, a2 = 0.f, a3 = 0.f;
        #pragma unroll 5
        for (int k4 = 0; k4 < 50; ++k4) {
            float4 xv = xs[k4 * 64 + lane];
            float4 r0 = w0[k4], r1 = w1[k4], r2 = w2[k4], r3 = w3[k4];
            a0 = fmaf(r0.x, xv.x, a0); a0 = fmaf(r0.y, xv.y, a0);
            a0 = fmaf(r0.z, xv.z, a0); a0 = fmaf(r0.w, xv.w, a0);
            a1 = fmaf(r1.x, xv.x, a1); a1 = fmaf(r1.y, xv.y, a1);
            a1 = fmaf(r1.z, xv.z, a1); a1 = fmaf(r1.w, xv.w, a1);
            a2 = fmaf(r2.x, xv.x, a2); a2 = fmaf(r2.y, xv.y, a2);
            a2 = fmaf(r2.z, xv.z, a2); a2 = fmaf(r2.w, xv.w, a2);
            a3 = fmaf(r3.x, xv.x, a3); a3 = fmaf(r3.y, xv.y, a3);
            a3 = fmaf(r3.z, xv.z, a3); a3 = fmaf(r3.w, xv.w, a3);
        }
        float* go = gi + (size_t)kq * GIP_STRIDE + ((size_t)t * H3 + j0) * 64 + lane;
        go[0] = a0;
        if (nj > 1) go[64] = a1;
        if (nj > 2) go[128] = a2;
        if (nj > 3) go[192] = a3;
    }
}

// ---------------------------------------------------------------------------
// k_chain: tf==1: 256 blocks = 16 bg x 16 dg. Sentinel dataflow (R9):
// per-(bg,t) single-writer h-buffers, consumers poll their OWN 8B word.
// gi is read as the sum of two k-half partials.
// tf==0: blocks 0..63 run independent per-batch full decode (unchanged).
// ---------------------------------------------------------------------------
struct SmemChain {
    float4 W4[75 * 101];    // 121.2 KB  W_hh slice rows (padded to 101 float4)
    float4 h4[400];         //   6.4 KB  h staged [k4][b] for the 4 batches
    float  part[KS * 300];  //  21.6 KB  [ks][gate][dd][bq]
};
struct SmemFallback {
    float part_i[3 * H3];
    float part_h[3 * H3];
    float hx[Hsz];
    float xv[Dsz];
    float sL[Ssz];
    float redv[15];
    int   redi[15];
    float bc_max, bc_sum;
    int   bc_idx;
};
union SmemU { SmemChain c; SmemFallback f; };

__device__ __forceinline__ float sigmoidf_(float x) { return 1.f / (1.f + expf(-x)); }

__device__ __forceinline__ unsigned long long poll8(const unsigned long long* p) {
    unsigned long long v;
    for (;;) {
        v = __hip_atomic_load(p, __ATOMIC_RELAXED, __HIP_MEMORY_SCOPE_AGENT);
        if ((unsigned)v != SENT && (unsigned)(v >> 32) != SENT) return v;
        __builtin_amdgcn_s_sleep(1);
    }
}

__global__ __launch_bounds__(960) void k_chain(const float* __restrict__ ws_ro,
                                               const float* __restrict__ gi,
                                               const float* __restrict__ W_hh,
                                               const float* __restrict__ enc_hidden,
                                               const float* __restrict__ enc_out,
                                               const int* __restrict__ lens,
                                               const int* __restrict__ uttrs,
                                               const int* __restrict__ slot_p,
                                               const int* __restrict__ tf_p,
                                               const float* __restrict__ embedding,
                                               const float* __restrict__ slot_emb,
                                               const float* __restrict__ b_ih,
                                               const float* __restrict__ b_hh,
                                               float* __restrict__ ws_rw,
                                               float* __restrict__ h_all,
                                               float* __restrict__ out_probs,
                                               float* __restrict__ preds_out) {
    __shared__ SmemU sm;
    const int tid = threadIdx.x;
    const int tf  = tf_p[0];

    if (tf != 0) {
        // ================= grouped h-chain (sentinel dataflow) ==============
        const int bg = blockIdx.x & 15;      // batch group (4 batches)
        const int dg = blockIdx.x >> 4;      // d group (25 dims)
        const int D0 = dg * 25;
        const float* hq_ro = ws_ro + HQ_OFF + (size_t)bg * (Lsz * 1600);
        float*       hq_rw = ws_rw + HQ_OFF + (size_t)bg * (Lsz * 1600);

        // preload W_hh slice: rows r = g*25+dd (g gate, dd local dim), padded LDS
        for (int i = tid; i < 7500; i += 960) {
            int r = i / 100, k4 = i % 100;
            int g = r / 25, dd = r % 25;
            sm.c.W4[r * 101 + k4] =
                ((const float4*)(W_hh + (size_t)(g * Hsz + D0 + dd) * Hsz))[k4];
        }

        // GEMV thread geometry (tid < 900): (ks, dd, bp)
        const int gks = tid / 50;
        const int gidx = tid % 50;
        const int gbp = gidx & 1;
        const int gdd = gidx >> 1;
        const int gk4b = (gks * 100) / KS;
        const int gk4e = ((gks + 1) * 100) / KS;
        const int gbq0 = gbp << 1;

        // finalize unit: one (dd,bq) per thread, tids 0..99 (waves 0 and 1)
        const bool is_fin = (tid < 100);
        const int  fbq = tid & 3, fdd = tid >> 2;
        const int  fd  = D0 + fdd;
        const int  fhidx = (((fd >> 2) << 2) | fbq) * 4 + (fd & 3);
        float g1r = 0.f, g1z = 0.f, g1n = 0.f;   // gi for current step
        float g2r = 0.f, g2z = 0.f, g2n = 0.f;   // gi prefetch for next step
        float bir = 0.f, biz = 0.f, bin = 0.f;
        float bhr = 0.f, bhz = 0.f, bhn = 0.f;
        if (is_fin) {
            bir = b_ih[fd]; biz = b_ih[fd + Hsz]; bin = b_ih[fd + 2 * Hsz];
            bhr = b_hh[fd]; bhz = b_hh[fd + Hsz]; bhn = b_hh[fd + 2 * Hsz];
            const float* gp = gi + (size_t)fd * 64 + (bg * 4 + fbq);
            g1r = gp[0]                     + gp[GIP_STRIDE];
            g1z = gp[(size_t)Hsz * 64]      + gp[GIP_STRIDE + (size_t)Hsz * 64];
            g1n = gp[(size_t)2 * Hsz * 64]  + gp[GIP_STRIDE + (size_t)2 * Hsz * 64];
        }

        // pre-stage hbuf[0] (h0, pre-written by k_init: polls succeed at once)
        if (tid < 800) {
            ((unsigned long long*)sm.c.h4)[tid] =
                poll8((const unsigned long long*)hq_ro + tid);
        }
        __syncthreads();

        for (int t = 0; t < Lsz; ++t) {
            float hpreg = 0.f;
            // own hp read BEFORE mid-sync (polls overwrite h4 after it);
            // gi(t+1) prefetch: L2 latency hides under the GEMV
            if (is_fin) {
                hpreg = ((const float*)sm.c.h4)[fhidx];
                if (t + 1 < Lsz) {
                    const float* gp = gi + ((size_t)(t + 1) * H3 + fd) * 64
                                    + (bg * 4 + fbq);
                    g2r = gp[0]                    + gp[GIP_STRIDE];
                    g2z = gp[(size_t)Hsz * 64]     + gp[GIP_STRIDE + (size_t)Hsz * 64];
                    g2n = gp[(size_t)2 * Hsz * 64] + gp[GIP_STRIDE + (size_t)2 * Hsz * 64];
                }
            }

            // GEMV partials: 900 threads (14 waves), 3 gate-rows x 2 batches
            // per thread over a ~5.6-k4 slice. 5 LDS reads per 24 FMA.
            if (tid < 900) {
                const float4* Wr = sm.c.W4 + (0 * 25 + gdd) * 101;
                const float4* Wz = sm.c.W4 + (1 * 25 + gdd) * 101;
                const float4* Wn = sm.c.W4 + (2 * 25 + gdd) * 101;
                float4 ar0 = make_float4(0.f, 0.f, 0.f, 0.f), ar1 = ar0;
                float4 az0 = ar0, az1 = ar0, an0 = ar0, an1 = ar0;
                for (int k4 = gk4b; k4 < gk4e; ++k4) {
                    float4 h0 = sm.c.h4[(k4 << 2) | gbq0];
                    float4 h1 = sm.c.h4[(k4 << 2) | gbq0 | 1];
                    float4 wr = Wr[k4], wz = Wz[k4], wn = Wn[k4];
                    ar0.x = fmaf(wr.x, h0.x, ar0.x); ar0.y = fmaf(wr.y, h0.y, ar0.y);
                    ar0.z = fmaf(wr.z, h0.z, ar0.z); ar0.w = fmaf(wr.w, h0.w, ar0.w);
                    ar1.x = fmaf(wr.x, h1.x, ar1.x); ar1.y = fmaf(wr.y, h1.y, ar1.y);
                    ar1.z = fmaf(wr.z, h1.z, ar1.z); ar1.w = fmaf(wr.w, h1.w, ar1.w);
                    az0.x = fmaf(wz.x, h0.x, az0.x); az0.y = fmaf(wz.y, h0.y, az0.y);
                    az0.z = fmaf(wz.z, h0.z, az0.z); az0.w = fmaf(wz.w, h0.w, az0.w);
                    az1.x = fmaf(wz.x, h1.x, az1.x); az1.y = fmaf(wz.y, h1.y, az1.y);
                    az1.z = fmaf(wz.z, h1.z, az1.z); az1.w = fmaf(wz.w, h1.w, az1.w);
                    an0.x = fmaf(wn.x, h0.x, an0.x); an0.y = fmaf(wn.y, h0.y, an0.y);
                    an0.z = fmaf(wn.z, h0.z, an0.z); an0.w = fmaf(wn.w, h0.w, an0.w);
                    an1.x = fmaf(wn.x, h1.x, an1.x); an1.y = fmaf(wn.y, h1.y, an1.y);
                    an1.z = fmaf(wn.z, h1.z, an1.z); an1.w = fmaf(wn.w, h1.w, an1.w);
                }
                sm.c.part[PIDX(gks, 0, gdd, gbq0)]     = (ar0.x + ar0.y) + (ar0.z + ar0.w);
                sm.c.part[PIDX(gks, 0, gdd, gbq0 | 1)] = (ar1.x + ar1.y) + (ar1.z + ar1.w);
                sm.c.part[PIDX(gks, 1, gdd, gbq0)]     = (az0.x + az0.y) + (az0.z + az0.w);
                sm.c.part[PIDX(gks, 1, gdd, gbq0 | 1)] = (az1.x + az1.y) + (az1.z + az1.w);
                sm.c.part[PIDX(gks, 2, gdd, gbq0)]     = (an0.x + an0.y) + (an0.z + an0.w);
                sm.c.part[PIDX(gks, 2, gdd, gbq0 | 1)] = (an1.x + an1.y) + (an1.z + an1.w);
            }
            __syncthreads();    // part ready; all h4 reads done

            // finalize: waves 0+1, one (dd,bq) unit per thread, sum 18 k-splits
            if (is_fin) {
                float ghr = bhr, ghz = bhz, ghn = bhn;
                #pragma unroll
                for (int ks = 0; ks < KS; ++ks) {
                    ghr += sm.c.part[PIDX(ks, 0, fdd, fbq)];
                    ghz += sm.c.part[PIDX(ks, 1, fdd, fbq)];
                    ghn += sm.c.part[PIDX(ks, 2, fdd, fbq)];
                }
                float rr = sigmoidf_(g1r + bir + ghr);
                float zz = sigmoidf_(g1z + biz + ghz);
                float nn = tanhf(g1n + bin + rr * ghn);
                float hv = (1.f - zz) * nn + zz * hpreg;
                if (t + 1 < Lsz) {
                    // device-visible store into the (t+1) sentinel buffer:
                    // arrival of the VALUE is the synchronization signal
                    __hip_atomic_store(&hq_rw[(size_t)(t + 1) * 1600 + fhidx], hv,
                                       __ATOMIC_RELAXED, __HIP_MEMORY_SCOPE_AGENT);
                }
                h_all[(size_t)(bg * 4 + fbq) * (Lsz * Hsz)
                      + (size_t)t * Hsz + fd] = hv;
                g1r = g2r; g1z = g2z; g1n = g2n;
            }

            if (t + 1 < Lsz) {
                // fused stage: poll own 8B word of hbuf[t+1] (distinct addrs,
                // self-terminating -> no counter hot-line congestion)
                if (tid < 800) {
                    ((unsigned long long*)sm.c.h4)[tid] =
                        poll8((const unsigned long long*)
                              (hq_ro + (size_t)(t + 1) * 1600) + tid);
                }
                __syncthreads();    // h4 ready for next step
            }
        }
        return;
    }

    // ================= tf==0 fallback: per-batch independent decode =========
    if (blockIdx.x >= Bsz) return;
    const int b    = blockIdx.x;
    const int lane = tid & 63;
    const int w    = tid >> 6;          // 0..14
    const int jc   = tid % 300;
    const int ksf  = tid / 300;
    const int kbeg = ksf * 134;
    const int kend = (ksf == 2) ? Hsz : kbeg + 134;
    const int len  = lens[b];

    const float4* WTH4 = (const float4*)(ws_ro + WT_HH_OFF);
    const float4* WTI4 = (const float4*)(ws_ro + WT_IH_OFF);

    if (tid < Hsz) {
        sm.f.hx[tid] = enc_hidden[b * Hsz + tid];
        sm.f.xv[tid] = slot_emb[(size_t)slot_p[0] * Dsz + tid];
    }
    __syncthreads();

    for (int t = 0; t < Lsz; ++t) {
        if (tid < 900) {
            float4 ai = make_float4(0.f, 0.f, 0.f, 0.f);
            float4 ah = make_float4(0.f, 0.f, 0.f, 0.f);
            for (int k = kbeg; k < kend; ++k) {
                float4 wi = WTI4[(size_t)k * 300 + jc];
                float4 wh = WTH4[(size_t)k * 300 + jc];
                float x = sm.f.xv[k], h = sm.f.hx[k];
                ai.x = fmaf(wi.x, x, ai.x); ai.y = fmaf(wi.y, x, ai.y);
                ai.z = fmaf(wi.z, x, ai.z); ai.w = fmaf(wi.w, x, ai.w);
                ah.x = fmaf(wh.x, h, ah.x); ah.y = fmaf(wh.y, h, ah.y);
                ah.z = fmaf(wh.z, h, ah.z); ah.w = fmaf(wh.w, h, ah.w);
            }
            ((float4*)sm.f.part_i)[ksf * 300 + jc] = ai;
            ((float4*)sm.f.part_h)[ksf * 300 + jc] = ah;
        }
        __syncthreads();

        if (tid < Hsz) {
            int d = tid;
            float i_r = sm.f.part_i[d]           + sm.f.part_i[H3 + d]           + sm.f.part_i[2 * H3 + d]           + b_ih[d];
            float i_z = sm.f.part_i[d + Hsz]     + sm.f.part_i[H3 + d + Hsz]     + sm.f.part_i[2 * H3 + d + Hsz]     + b_ih[d + Hsz];
            float i_n = sm.f.part_i[d + 2 * Hsz] + sm.f.part_i[H3 + d + 2 * Hsz] + sm.f.part_i[2 * H3 + d + 2 * Hsz] + b_ih[d + 2 * Hsz];
            float h_r = sm.f.part_h[d]           + sm.f.part_h[H3 + d]           + sm.f.part_h[2 * H3 + d]           + b_hh[d];
            float h_z = sm.f.part_h[d + Hsz]     + sm.f.part_h[H3 + d + Hsz]     + sm.f.part_h[2 * H3 + d + Hsz]     + b_hh[d + Hsz];
            float h_n = sm.f.part_h[d + 2 * Hsz] + sm.f.part_h[H3 + d + 2 * Hsz] + sm.f.part_h[2 * H3 + d + 2 * Hsz] + b_hh[d + 2 * Hsz];
            float r = sigmoidf_(i_r + h_r);
            float z = sigmoidf_(i_z + h_z);
            float n = tanhf(i_n + r * h_n);
            sm.f.hx[d] = (1.f - z) * n + z * sm.f.hx[d];
        }
        __syncthreads();

        const float4* hx4 = (const float4*)sm.f.hx;
        for (int s = w; s < len; s += 15) {
            const float4* e4 = (const float4*)(enc_out + ((size_t)b * Ssz + s) * Hsz);
            float4 ev = e4[lane];
            float4 hv = hx4[lane];
            float acc = ev.x * hv.x + ev.y * hv.y + ev.z * hv.z + ev.w * hv.w;
            if (lane < 36) {
                float4 ev2 = e4[64 + lane];
                float4 hv2 = hx4[64 + lane];
                acc += ev2.x * hv2.x + ev2.y * hv2.y + ev2.z * hv2.z + ev2.w * hv2.w;
            }
            #pragma unroll
            for (int off = 32; off >= 1; off >>= 1) acc += __shfl_xor(acc, off, 64);
            if (lane == 0) sm.f.sL[s] = acc;
        }
        __syncthreads();

        float bv = -INFINITY; int bi = 0x7fffffff;
        for (int s = tid; s < len; s += 960) {
            float v = sm.f.sL[s];
            if (v > bv || (v == bv && s < bi)) { bv = v; bi = s; }
        }
        #pragma unroll
        for (int off = 32; off >= 1; off >>= 1) {
            float ov = __shfl_xor(bv, off, 64);
            int   oi = __shfl_xor(bi, off, 64);
            if (ov > bv || (ov == bv && oi < bi)) { bv = ov; bi = oi; }
        }
        if (lane == 0) { sm.f.redv[w] = bv; sm.f.redi[w] = bi; }
        __syncthreads();
        if (tid == 0) {
            float mv = sm.f.redv[0]; int mi = sm.f.redi[0];
            for (int i = 1; i < 15; ++i)
                if (sm.f.redv[i] > mv || (sm.f.redv[i] == mv && sm.f.redi[i] < mi)) {
                    mv = sm.f.redv[i]; mi = sm.f.redi[i];
                }
            sm.f.bc_max = mv; sm.f.bc_idx = mi;
        }
        __syncthreads();
        float maxv = sm.f.bc_max;
        int   amax = sm.f.bc_idx;

        float ls = 0.f;
        for (int s = tid; s < len; s += 960) {
            float e = expf(sm.f.sL[s] - maxv);
            sm.f.sL[s] = e;
            ls += e;
        }
        #pragma unroll
        for (int off = 32; off >= 1; off >>= 1) ls += __shfl_xor(ls, off, 64);
        if (lane == 0) sm.f.redv[w] = ls;
        __syncthreads();
        if (tid == 0) {
            float sms = 0.f;
            for (int i = 0; i < 15; ++i) sms += sm.f.redv[i];
            sm.f.bc_sum = sms;
        }
        __syncthreads();
        float sum = sm.f.bc_sum;

        float* orow = out_probs + (size_t)b * (Lsz * Vsz) + (size_t)t * Vsz;
        for (int s = tid; s < len; s += 960) {
            atomicAdd(&orow[uttrs[b * Ssz + s]], sm.f.sL[s] / sum);
        }

        int predtok = uttrs[b * Ssz + amax];
        if (tid == 0) preds_out[(size_t)t * Bsz + b] = (float)predtok;
        __syncthreads();
        if (tid < Dsz) sm.f.xv[tid] = embedding[(size_t)predtok * Dsz + tid];
        __syncthreads();
    }
}

// ---------------------------------------------------------------------------
// Batched scores (tf==1), shuffle-free: 256 blocks = (b, s-quarter of 128).
// 512 threads = (s-tile of 2) x (t-pair {tp, tp+8}); acc in registers,
// h broadcast from pad-101 LDS. 8 waves/CU -> 2/SIMD latency hiding.
// ---------------------------------------------------------------------------
__global__ __launch_bounds__(512) void k_scores(const float* __restrict__ h_all,
                                                const float* __restrict__ enc_out,
                                                const int* __restrict__ lens,
                                                const int* __restrict__ tf_p,
                                                float* __restrict__ scores_all) {
    if (tf_p[0] == 0) return;
    __shared__ float4 hS[Lsz * 101];   // 25.9 KB, padded stride

    int b  = blockIdx.x >> 2;
    int sc = blockIdx.x & 3;
    int tid = threadIdx.x;
    int len = lens[b];
    int s0 = sc * 128;
    if (s0 >= len) return;             // whole chunk masked downstream

    const float4* h4g = (const float4*)(h_all + (size_t)b * (Lsz * Hsz));
    for (int i = tid; i < Lsz * 100; i += 512) {
        int t = i / 100, k4 = i % 100;
        hS[t * 101 + k4] = h4g[i];
    }
    __syncthreads();

    int stile = tid >> 3;              // 0..63
    int tp    = tid & 7;               // 0..7
    int t0 = tp, t1 = tp + 8;
    int sbase = s0 + stile * 2;

    const float4* e0 = (const float4*)(enc_out + ((size_t)b * Ssz + sbase + 0) * Hsz);
    const float4* e1 = (const float4*)(enc_out + ((size_t)b * Ssz + sbase + 1) * Hsz);
    const float4* h0p = hS + t0 * 101;
    const float4* h1p = hS + t1 * 101;

    float a00 = 0.f, a01 = 0.f;        // t0 x {s0, s1}
    float a10 = 0.f, a11 = 0.f;        // t1 x {s0, s1}
    #pragma unroll 4
    for (int k4 = 0; k4 < 100; ++k4) {
        float4 v0 = e0[k4], v1 = e1[k4];
        float4 h0 = h0p[k4], h1 = h1p[k4];
        a00 = fmaf(v0.x, h0.x, a00); a00 = fmaf(v0.y, h0.y, a00);
        a00 = fmaf(v0.z, h0.z, a00); a00 = fmaf(v0.w, h0.w, a00);
        a01 = fmaf(v1.x, h0.x, a01); a01 = fmaf(v1.y, h0.y, a01);
        a01 = fmaf(v1.z, h0.z, a01); a01 = fmaf(v1.w, h0.w, a01);
        a10 = fmaf(v0.x, h1.x, a10); a10 = fmaf(v0.y, h1.y, a10);
        a10 = fmaf(v0.z, h1.z, a10); a10 = fmaf(v0.w, h1.w, a10);
        a11 = fmaf(v1.x, h1.x, a11); a11 = fmaf(v1.y, h1.y, a11);
        a11 = fmaf(v1.z, h1.z, a11); a11 = fmaf(v1.w, h1.w, a11);
    }

    float2 r0 = make_float2(a00, a01);
    float2 r1 = make_float2(a10, a11);
    *(float2*)(scores_all + (size_t)t0 * (Bsz * Ssz) + (size_t)b * Ssz + sbase) = r0;
    *(float2*)(scores_all + (size_t)t1 * (Bsz * Ssz) + (size_t)b * Ssz + sbase) = r1;
}

// ---------------------------------------------------------------------------
// Batched softmax + LDS-vocab scatter + argmax (tf==1): 2048 blocks =
// (t, b, vocab-half). 64 KB LDS half-vocab -> 2 blocks/CU so the output
// stream pipelines across phases. Reductions duplicated per half (cheap);
// scatter range-filtered; preds written by half 0.
// ---------------------------------------------------------------------------
__global__ __launch_bounds__(256) void k_softmax_all(const float* __restrict__ scores_all,
                                                     const int* __restrict__ lens,
                                                     const int* __restrict__ uttrs,
                                                     const int* __restrict__ tf_p,
                                                     float* __restrict__ out_probs,
                                                     float* __restrict__ preds_out) {
    if (tf_p[0] == 0) return;
    __shared__ float4 vb4[Vsz / 8];   // 64 KB half-vocab accumulator
    __shared__ float sL[Ssz];
    __shared__ float redv[4];
    __shared__ int   redi[4];
    __shared__ float bc_max, bc_sum;
    __shared__ int   bc_idx;

    int vh = blockIdx.x & 1;
    int b  = (blockIdx.x >> 1) & 63;
    int t  = blockIdx.x >> 7;
    int tid = threadIdx.x;
    int lane = tid & 63, w = tid >> 6;
    int len = lens[b];
    const int vbase = vh * (Vsz / 2);
    const float* srow = scores_all + (size_t)t * (Bsz * Ssz) + b * Ssz;

    float4 z4 = make_float4(0.f, 0.f, 0.f, 0.f);
    for (int i = tid; i < Vsz / 8; i += 256) vb4[i] = z4;

    for (int s = tid; s < len; s += 256) sL[s] = srow[s];
    __syncthreads();

    float bv = -INFINITY; int bi = 0x7fffffff;
    for (int s = tid; s < len; s += 256) {
        float v = sL[s];
        if (v > bv || (v == bv && s < bi)) { bv = v; bi = s; }
    }
    #pragma unroll
    for (int off = 32; off >= 1; off >>= 1) {
        float ov = __shfl_xor(bv, off, 64);
        int   oi = __shfl_xor(bi, off, 64);
        if (ov > bv || (ov == bv && oi < bi)) { bv = ov; bi = oi; }
    }
    if (lane == 0) { redv[w] = bv; redi[w] = bi; }
    __syncthreads();
    if (tid == 0) {
        float mv = redv[0]; int mi = redi[0];
        for (int i = 1; i < 4; ++i)
            if (redv[i] > mv || (redv[i] == mv && redi[i] < mi)) { mv = redv[i]; mi = redi[i]; }
        bc_max = mv; bc_idx = mi;
    }
    __syncthreads();
    float maxv = bc_max;
    int   amax = bc_idx;

    float ls = 0.f;
    for (int s = tid; s < len; s += 256) {
        float e = expf(sL[s] - maxv);
        sL[s] = e;
        ls += e;
    }
    #pragma unroll
    for (int off = 32; off >= 1; off >>= 1) ls += __shfl_xor(ls, off, 64);
    if (lane == 0) redv[w] = ls;
    __syncthreads();
    if (tid == 0) bc_sum = redv[0] + redv[1] + redv[2] + redv[3];
    __syncthreads();
    float sum = bc_sum;

    float* vbf = (float*)vb4;
    for (int s = tid; s < len; s += 256) {
        int rel = uttrs[b * Ssz + s] - vbase;
        if ((unsigned)rel < (unsigned)(Vsz / 2))
            atomicAdd(&vbf[rel], sL[s] / sum);
    }
    __syncthreads();

    // stream the half vocab row out nontemporally (native vector type)
    const nf4* vbn = (const nf4*)vb4;
    nf4* orow4 = (nf4*)(out_probs + (size_t)b * (Lsz * Vsz) + (size_t)t * Vsz + vbase);
    for (int i = tid; i < Vsz / 8; i += 256)
        __builtin_nontemporal_store(vbn[i], &orow4[i]);

    if (vh == 0 && tid == 0)
        preds_out[(size_t)t * Bsz + b] = (float)uttrs[b * Ssz + amax];
}

// ---------------------------------------------------------------------------
extern "C" void kernel_launch(void* const* d_in, const int* in_sizes, int n_in,
                              void* d_out, int out_size, void* d_ws, size_t ws_size,
                              hipStream_t stream) {
    const float* enc_hidden = (const float*)d_in[0];
    const float* enc_out    = (const float*)d_in[1];
    const int*   enc_lens   = (const int*)d_in[2];
    const int*   uttrs      = (const int*)d_in[3];
    const int*   tgt        = (const int*)d_in[4];
    const int*   slot_p     = (const int*)d_in[5];
    const int*   tf_p       = (const int*)d_in[6];
    const float* embedding  = (const float*)d_in[7];
    const float* slot_emb   = (const float*)d_in[8];
    const float* W_ih       = (const float*)d_in[9];
    const float* W_hh       = (const float*)d_in[10];
    const float* b_ih       = (const float*)d_in[11];
    const float* b_hh       = (const float*)d_in[12];

    float* out = (float*)d_out;
    float* ws  = (float*)d_ws;

    float* gi_all     = ws + GI_OFF;
    float* h_all      = ws + HALL_OFF;
    float* scores_all = ws + SCALL_OFF;
    float* preds_out  = out + (size_t)Bsz * Lsz * Vsz;

    int n4 = out_size >> 2;

    // 1) init: tf==1: h0 + sentinel h-buffers; tf==0: full zero + WT
    k_init<<<2048, 256, 0, stream>>>(W_hh, W_ih, enc_hidden, tf_p,
                                     (float4*)d_out, n4, ws);

    // 2) gi GEMM k-half partials (tf==1 only), 512 blocks -> 2/CU
    k_gi<<<512, 512, 0, stream>>>(tgt, slot_p, tf_p, embedding, slot_emb,
                                  W_ih, gi_all);

    // 3) chain (tf==1: sentinel dataflow; tf==0: per-batch fallback)
    k_chain<<<NBLK_CHAIN, 960, 0, stream>>>(ws, gi_all, W_hh, enc_hidden, enc_out,
                                            enc_lens, uttrs, slot_p, tf_p,
                                            embedding, slot_emb, b_ih, b_hh,
                                            ws, h_all, out, preds_out);

    // 4) batched scores + vocab-split softmax/scatter (tf==1 only)
    k_scores<<<256, 512, 0, stream>>>(h_all, enc_out, enc_lens, tf_p, scores_all);
    k_softmax_all<<<2048, 256, 0, stream>>>(scores_all, enc_lens, uttrs, tf_p,
                                            out, preds_out);
}

// Round 11
// 363.677 us; speedup vs baseline: 1.4690x; 1.0070x over previous
//
#include <hip/hip_runtime.h>
#include <math.h>

// Problem dims (fixed by reference)
#define Bsz 64
#define Ssz 512
#define Hsz 400
#define Dsz 400
#define Vsz 32000
#define Lsz 16
#define H3  1200   // 3*H

// Workspace layout (float offsets)
#define WT_HH_OFF 0                 // 400*1200 transposed W_hh [k][j]  (fallback only)
#define WT_IH_OFF 480000            // 400*1200 transposed W_ih [k][j]  (fallback only)
#define HQ_OFF    0                 // tf==1 only: 16bg x 16t x 1600 floats sentinel
                                    // h-buffers (aliases WT region; disjoint paths)
#define GI_OFF    1011200           // 2 x 16*1200*64 gi k-half partials
#define GIP_STRIDE 1228800          // floats per k-half partial
#define HALL_OFF  3468800           // 64*16*400    h_all[b][t][d]
#define SCALL_OFF 3878400           // 16*64*512    scores[t][b][s]
// total 4,402,688 floats = 17.6 MB

#define NBG   16                    // batch groups (4 batches each)
#define DGRP  16                    // d-groups per batch-group
#define NBLK_CHAIN 256              // NBG * DGRP; 1 block/CU -> co-resident
#define KS    18                    // k-splits in the chain GEMV
#define SENT  0xFFFFFFFFu           // sentinel bit pattern (-NaN, unreachable)

// part index: [ks][gate][dd][bq]
#define PIDX(ks, g, dd, bq) ((((ks) * 3 + (g)) * 25 + (dd)) * 4 + (bq))

// native vector type for nontemporal builtins (HIP float4 class is rejected)
typedef float nf4 __attribute__((ext_vector_type(4)));

// ---------------------------------------------------------------------------
// k_init: tf==1: no-op (h0+sentinel init folded into k_gi, which precedes
// k_chain in stream order). tf==0: full output zero + WT transposes.
// ---------------------------------------------------------------------------
__global__ __launch_bounds__(256) void k_init(const float* __restrict__ W_hh,
                                              const float* __restrict__ W_ih,
                                              const int* __restrict__ tf_p,
                                              float4* __restrict__ out4, int n4,
                                              float* __restrict__ ws) {
    const int tf = tf_p[0];
    if (tf != 0) return;
    const int nz = n4;
    const int nT = 480000;
    const int R1 = nz + nT;
    const int R2 = R1 + nT;
    int stride = gridDim.x * 256;
    for (int i = blockIdx.x * 256 + threadIdx.x; i < R2; i += stride) {
        if (i < nz) {
            out4[i] = make_float4(0.f, 0.f, 0.f, 0.f);
        } else if (i < R1) {
            int r = i - nz;
            int k = r / 1200, j = r % 1200;
            ws[WT_HH_OFF + r] = W_hh[(size_t)j * Hsz + k];
        } else {
            int r = i - R1;
            int k = r / 1200, j = r % 1200;
            ws[WT_IH_OFF + r] = W_ih[(size_t)j * Dsz + k];
        }
    }
}

// ---------------------------------------------------------------------------
// k_gi (tf==1 only): gi partials [kq][t][j][b] = half-K products.
// 512 blocks = (t, jc, k-half); xs 51.2 KB -> 2 blocks/CU, 16 waves/CU.
// Also performs the tf==1 init (h0 + sentinels) -- stream-ordered before
// k_chain's polls, overlapped with this kernel's own GEMM.
// ---------------------------------------------------------------------------
__global__ __launch_bounds__(512) void k_gi(const int* __restrict__ tgt,
                                            const int* __restrict__ slot_p,
                                            const int* __restrict__ tf_p,
                                            const float* __restrict__ embedding,
                                            const float* __restrict__ slot_emb,
                                            const float* __restrict__ W_ih,
                                            const float* __restrict__ enc_hidden,
                                            float* __restrict__ ws,
                                            float* __restrict__ gi) {
    if (tf_p[0] == 0) return;
    __shared__ float4 xs[50 * 64];   // 51.2 KB, [k4][b] (half K)

    int kq = blockIdx.x & 1;
    int jc = (blockIdx.x >> 1) & 15;
    int t  = blockIdx.x >> 5;
    int tid = threadIdx.x;
    int lane = tid & 63, wv = tid >> 6;   // wv 0..7

    // folded init: h0 into hbuf[0], sentinels into hbuf[1..15]
    {
        int gstride = gridDim.x * 512;
        for (int i = blockIdx.x * 512 + tid; i < NBG * Lsz * 1600; i += gstride) {
            int t_ = (i / 1600) & 15;
            if (t_ > 0) {
                ((unsigned*)(ws + HQ_OFF))[i] = SENT;
            } else {
                int bg  = i / 25600;          // 16*1600
                int off = i % 1600;
                int k  = ((off >> 4) << 2) | (off & 3);
                int bq = (off >> 2) & 3;
                ws[HQ_OFF + i] = enc_hidden[(bg * 4 + bq) * Hsz + k];
            }
        }
    }

    {
        int bb = tid & 63, q = tid >> 6;
        const float* src = (t == 0)
            ? (slot_emb + (size_t)slot_p[0] * Dsz)
            : (embedding + (size_t)tgt[bb * Lsz + (t - 1)] * Dsz);
        const float4* src4 = (const float4*)src + kq * 50;
        for (int k4 = q; k4 < 50; k4 += 8) xs[k4 * 64 + bb] = src4[k4];
    }
    __syncthreads();

    for (int g = wv; g < 19; g += 8) {
        int j0l = g * 4;
        int nj = (j0l + 4 <= 75) ? 4 : (75 - j0l);
        int j0 = jc * 75 + j0l;
        const float4* w0 = (const float4*)(W_ih + (size_t)(j0 + 0) * Dsz) + kq * 50;
        const float4* w1 = (const float4*)(W_ih + (size_t)(j0 + ((nj > 1) ? 1 : 0)) * Dsz) + kq * 50;
        const float4* w2 = (const float4*)(W_ih + (size_t)(j0 + ((nj > 2) ? 2 : 0)) * Dsz) + kq * 50;
        const float4* w3 = (const float4*)(W_ih + (size_t)(j0 + ((nj > 3) ? 3 : 0)) * Dsz) + kq * 50;
        float a0 = 0.f, a1 = 0.f, a2 = 0.f, a3 = 0.f;
        #pragma unroll 5
        for (int k4 = 0; k4 < 50; ++k4) {
            float4 xv = xs[k4 * 64 + lane];
            float4 r0 = w0[k4], r1 = w1[k4], r2 = w2[k4], r3 = w3[k4];
            a0 = fmaf(r0.x, xv.x, a0); a0 = fmaf(r0.y, xv.y, a0);
            a0 = fmaf(r0.z, xv.z, a0); a0 = fmaf(r0.w, xv.w, a0);
            a1 = fmaf(r1.x, xv.x, a1); a1 = fmaf(r1.y, xv.y, a1);
            a1 = fmaf(r1.z, xv.z, a1); a1 = fmaf(r1.w, xv.w, a1);
            a2 = fmaf(r2.x, xv.x, a2); a2 = fmaf(r2.y, xv.y, a2);
            a2 = fmaf(r2.z, xv.z, a2); a2 = fmaf(r2.w, xv.w, a2);
            a3 = fmaf(r3.x, xv.x, a3); a3 = fmaf(r3.y, xv.y, a3);
            a3 = fmaf(r3.z, xv.z, a3); a3 = fmaf(r3.w, xv.w, a3);
        }
        float* go = gi + (size_t)kq * GIP_STRIDE + ((size_t)t * H3 + j0) * 64 + lane;
        go[0] = a0;
        if (nj > 1) go[64] = a1;
        if (nj > 2) go[128] = a2;
        if (nj > 3) go[192] = a3;
    }
}

// ---------------------------------------------------------------------------
// k_chain: tf==1: 256 blocks = 16 bg x 16 dg. Sentinel dataflow (R9):
// per-(bg,t) single-writer h-buffers, consumers poll their OWN 8B word.
// gi is read as the sum of two k-half partials.
// tf==0: blocks 0..63 run independent per-batch full decode (unchanged).
// ---------------------------------------------------------------------------
struct SmemChain {
    float4 W4[75 * 101];    // 121.2 KB  W_hh slice rows (padded to 101 float4)
    float4 h4[400];         //   6.4 KB  h staged [k4][b] for the 4 batches
    float  part[KS * 300];  //  21.6 KB  [ks][gate][dd][bq]
};
struct SmemFallback {
    float part_i[3 * H3];
    float part_h[3 * H3];
    float hx[Hsz];
    float xv[Dsz];
    float sL[Ssz];
    float redv[15];
    int   redi[15];
    float bc_max, bc_sum;
    int   bc_idx;
};
union SmemU { SmemChain c; SmemFallback f; };

__device__ __forceinline__ float sigmoidf_(float x) { return 1.f / (1.f + expf(-x)); }

__device__ __forceinline__ unsigned long long poll8(const unsigned long long* p) {
    unsigned long long v;
    for (;;) {
        v = __hip_atomic_load(p, __ATOMIC_RELAXED, __HIP_MEMORY_SCOPE_AGENT);
        if ((unsigned)v != SENT && (unsigned)(v >> 32) != SENT) return v;
        __builtin_amdgcn_s_sleep(1);
    }
}

__global__ __launch_bounds__(960) void k_chain(const float* __restrict__ ws_ro,
                                               const float* __restrict__ gi,
                                               const float* __restrict__ W_hh,
                                               const float* __restrict__ enc_hidden,
                                               const float* __restrict__ enc_out,
                                               const int* __restrict__ lens,
                                               const int* __restrict__ uttrs,
                                               const int* __restrict__ slot_p,
                                               const int* __restrict__ tf_p,
                                               const float* __restrict__ embedding,
                                               const float* __restrict__ slot_emb,
                                               const float* __restrict__ b_ih,
                                               const float* __restrict__ b_hh,
                                               float* __restrict__ ws_rw,
                                               float* __restrict__ h_all,
                                               float* __restrict__ out_probs,
                                               float* __restrict__ preds_out) {
    __shared__ SmemU sm;
    const int tid = threadIdx.x;
    const int tf  = tf_p[0];

    if (tf != 0) {
        // ================= grouped h-chain (sentinel dataflow) ==============
        const int bg = blockIdx.x & 15;      // batch group (4 batches)
        const int dg = blockIdx.x >> 4;      // d group (25 dims)
        const int D0 = dg * 25;
        const float* hq_ro = ws_ro + HQ_OFF + (size_t)bg * (Lsz * 1600);
        float*       hq_rw = ws_rw + HQ_OFF + (size_t)bg * (Lsz * 1600);

        // preload W_hh slice: rows r = g*25+dd (g gate, dd local dim), padded LDS
        for (int i = tid; i < 7500; i += 960) {
            int r = i / 100, k4 = i % 100;
            int g = r / 25, dd = r % 25;
            sm.c.W4[r * 101 + k4] =
                ((const float4*)(W_hh + (size_t)(g * Hsz + D0 + dd) * Hsz))[k4];
        }

        // GEMV thread geometry (tid < 900): (ks, dd, bp)
        const int gks = tid / 50;
        const int gidx = tid % 50;
        const int gbp = gidx & 1;
        const int gdd = gidx >> 1;
        const int gk4b = (gks * 100) / KS;
        const int gk4e = ((gks + 1) * 100) / KS;
        const int gbq0 = gbp << 1;

        // finalize unit: one (dd,bq) per thread, tids 0..99 (waves 0 and 1)
        const bool is_fin = (tid < 100);
        const int  fbq = tid & 3, fdd = tid >> 2;
        const int  fd  = D0 + fdd;
        const int  fhidx = (((fd >> 2) << 2) | fbq) * 4 + (fd & 3);
        float g1r = 0.f, g1z = 0.f, g1n = 0.f;   // gi for current step
        float g2r = 0.f, g2z = 0.f, g2n = 0.f;   // gi prefetch for next step
        float bir = 0.f, biz = 0.f, bin = 0.f;
        float bhr = 0.f, bhz = 0.f, bhn = 0.f;
        if (is_fin) {
            bir = b_ih[fd]; biz = b_ih[fd + Hsz]; bin = b_ih[fd + 2 * Hsz];
            bhr = b_hh[fd]; bhz = b_hh[fd + Hsz]; bhn = b_hh[fd + 2 * Hsz];
            const float* gp = gi + (size_t)fd * 64 + (bg * 4 + fbq);
            g1r = gp[0]                     + gp[GIP_STRIDE];
            g1z = gp[(size_t)Hsz * 64]      + gp[GIP_STRIDE + (size_t)Hsz * 64];
            g1n = gp[(size_t)2 * Hsz * 64]  + gp[GIP_STRIDE + (size_t)2 * Hsz * 64];
        }

        // pre-stage hbuf[0] (h0, pre-written by k_gi: polls succeed at once)
        if (tid < 800) {
            ((unsigned long long*)sm.c.h4)[tid] =
                poll8((const unsigned long long*)hq_ro + tid);
        }
        __syncthreads();

        for (int t = 0; t < Lsz; ++t) {
            float hpreg = 0.f;
            // own hp read BEFORE mid-sync (polls overwrite h4 after it);
            // gi(t+1) prefetch: L2 latency hides under the GEMV
            if (is_fin) {
                hpreg = ((const float*)sm.c.h4)[fhidx];
                if (t + 1 < Lsz) {
                    const float* gp = gi + ((size_t)(t + 1) * H3 + fd) * 64
                                    + (bg * 4 + fbq);
                    g2r = gp[0]                    + gp[GIP_STRIDE];
                    g2z = gp[(size_t)Hsz * 64]     + gp[GIP_STRIDE + (size_t)Hsz * 64];
                    g2n = gp[(size_t)2 * Hsz * 64] + gp[GIP_STRIDE + (size_t)2 * Hsz * 64];
                }
            }

            // GEMV partials: 900 threads (14 waves), 3 gate-rows x 2 batches
            // per thread over a ~5.6-k4 slice. 5 LDS reads per 24 FMA.
            if (tid < 900) {
                const float4* Wr = sm.c.W4 + (0 * 25 + gdd) * 101;
                const float4* Wz = sm.c.W4 + (1 * 25 + gdd) * 101;
                const float4* Wn = sm.c.W4 + (2 * 25 + gdd) * 101;
                float4 ar0 = make_float4(0.f, 0.f, 0.f, 0.f), ar1 = ar0;
                float4 az0 = ar0, az1 = ar0, an0 = ar0, an1 = ar0;
                for (int k4 = gk4b; k4 < gk4e; ++k4) {
                    float4 h0 = sm.c.h4[(k4 << 2) | gbq0];
                    float4 h1 = sm.c.h4[(k4 << 2) | gbq0 | 1];
                    float4 wr = Wr[k4], wz = Wz[k4], wn = Wn[k4];
                    ar0.x = fmaf(wr.x, h0.x, ar0.x); ar0.y = fmaf(wr.y, h0.y, ar0.y);
                    ar0.z = fmaf(wr.z, h0.z, ar0.z); ar0.w = fmaf(wr.w, h0.w, ar0.w);
                    ar1.x = fmaf(wr.x, h1.x, ar1.x); ar1.y = fmaf(wr.y, h1.y, ar1.y);
                    ar1.z = fmaf(wr.z, h1.z, ar1.z); ar1.w = fmaf(wr.w, h1.w, ar1.w);
                    az0.x = fmaf(wz.x, h0.x, az0.x); az0.y = fmaf(wz.y, h0.y, az0.y);
                    az0.z = fmaf(wz.z, h0.z, az0.z); az0.w = fmaf(wz.w, h0.w, az0.w);
                    az1.x = fmaf(wz.x, h1.x, az1.x); az1.y = fmaf(wz.y, h1.y, az1.y);
                    az1.z = fmaf(wz.z, h1.z, az1.z); az1.w = fmaf(wz.w, h1.w, az1.w);
                    an0.x = fmaf(wn.x, h0.x, an0.x); an0.y = fmaf(wn.y, h0.y, an0.y);
                    an0.z = fmaf(wn.z, h0.z, an0.z); an0.w = fmaf(wn.w, h0.w, an0.w);
                    an1.x = fmaf(wn.x, h1.x, an1.x); an1.y = fmaf(wn.y, h1.y, an1.y);
                    an1.z = fmaf(wn.z, h1.z, an1.z); an1.w = fmaf(wn.w, h1.w, an1.w);
                }
                sm.c.part[PIDX(gks, 0, gdd, gbq0)]     = (ar0.x + ar0.y) + (ar0.z + ar0.w);
                sm.c.part[PIDX(gks, 0, gdd, gbq0 | 1)] = (ar1.x + ar1.y) + (ar1.z + ar1.w);
                sm.c.part[PIDX(gks, 1, gdd, gbq0)]     = (az0.x + az0.y) + (az0.z + az0.w);
                sm.c.part[PIDX(gks, 1, gdd, gbq0 | 1)] = (az1.x + az1.y) + (az1.z + az1.w);
                sm.c.part[PIDX(gks, 2, gdd, gbq0)]     = (an0.x + an0.y) + (an0.z + an0.w);
                sm.c.part[PIDX(gks, 2, gdd, gbq0 | 1)] = (an1.x + an1.y) + (an1.z + an1.w);
            }
            __syncthreads();    // part ready; all h4 reads done

            // finalize: waves 0+1, one (dd,bq) unit per thread, sum 18 k-splits
            if (is_fin) {
                float ghr = bhr, ghz = bhz, ghn = bhn;
                #pragma unroll
                for (int ks = 0; ks < KS; ++ks) {
                    ghr += sm.c.part[PIDX(ks, 0, fdd, fbq)];
                    ghz += sm.c.part[PIDX(ks, 1, fdd, fbq)];
                    ghn += sm.c.part[PIDX(ks, 2, fdd, fbq)];
                }
                float rr = sigmoidf_(g1r + bir + ghr);
                float zz = sigmoidf_(g1z + biz + ghz);
                float nn = tanhf(g1n + bin + rr * ghn);
                float hv = (1.f - zz) * nn + zz * hpreg;
                if (t + 1 < Lsz) {
                    // device-visible store into the (t+1) sentinel buffer:
                    // arrival of the VALUE is the synchronization signal
                    __hip_atomic_store(&hq_rw[(size_t)(t + 1) * 1600 + fhidx], hv,
                                       __ATOMIC_RELAXED, __HIP_MEMORY_SCOPE_AGENT);
                }
                h_all[(size_t)(bg * 4 + fbq) * (Lsz * Hsz)
                      + (size_t)t * Hsz + fd] = hv;
                g1r = g2r; g1z = g2z; g1n = g2n;
            }

            if (t + 1 < Lsz) {
                // fused stage: poll own 8B word of hbuf[t+1] (distinct addrs,
                // self-terminating -> no counter hot-line congestion)
                if (tid < 800) {
                    ((unsigned long long*)sm.c.h4)[tid] =
                        poll8((const unsigned long long*)
                              (hq_ro + (size_t)(t + 1) * 1600) + tid);
                }
                __syncthreads();    // h4 ready for next step
            }
        }
        return;
    }

    // ================= tf==0 fallback: per-batch independent decode =========
    if (blockIdx.x >= Bsz) return;
    const int b    = blockIdx.x;
    const int lane = tid & 63;
    const int w    = tid >> 6;          // 0..14
    const int jc   = tid % 300;
    const int ksf  = tid / 300;
    const int kbeg = ksf * 134;
    const int kend = (ksf == 2) ? Hsz : kbeg + 134;
    const int len  = lens[b];

    const float4* WTH4 = (const float4*)(ws_ro + WT_HH_OFF);
    const float4* WTI4 = (const float4*)(ws_ro + WT_IH_OFF);

    if (tid < Hsz) {
        sm.f.hx[tid] = enc_hidden[b * Hsz + tid];
        sm.f.xv[tid] = slot_emb[(size_t)slot_p[0] * Dsz + tid];
    }
    __syncthreads();

    for (int t = 0; t < Lsz; ++t) {
        if (tid < 900) {
            float4 ai = make_float4(0.f, 0.f, 0.f, 0.f);
            float4 ah = make_float4(0.f, 0.f, 0.f, 0.f);
            for (int k = kbeg; k < kend; ++k) {
                float4 wi = WTI4[(size_t)k * 300 + jc];
                float4 wh = WTH4[(size_t)k * 300 + jc];
                float x = sm.f.xv[k], h = sm.f.hx[k];
                ai.x = fmaf(wi.x, x, ai.x); ai.y = fmaf(wi.y, x, ai.y);
                ai.z = fmaf(wi.z, x, ai.z); ai.w = fmaf(wi.w, x, ai.w);
                ah.x = fmaf(wh.x, h, ah.x); ah.y = fmaf(wh.y, h, ah.y);
                ah.z = fmaf(wh.z, h, ah.z); ah.w = fmaf(wh.w, h, ah.w);
            }
            ((float4*)sm.f.part_i)[ksf * 300 + jc] = ai;
            ((float4*)sm.f.part_h)[ksf * 300 + jc] = ah;
        }
        __syncthreads();

        if (tid < Hsz) {
            int d = tid;
            float i_r = sm.f.part_i[d]           + sm.f.part_i[H3 + d]           + sm.f.part_i[2 * H3 + d]           + b_ih[d];
            float i_z = sm.f.part_i[d + Hsz]     + sm.f.part_i[H3 + d + Hsz]     + sm.f.part_i[2 * H3 + d + Hsz]     + b_ih[d + Hsz];
            float i_n = sm.f.part_i[d + 2 * Hsz] + sm.f.part_i[H3 + d + 2 * Hsz] + sm.f.part_i[2 * H3 + d + 2 * Hsz] + b_ih[d + 2 * Hsz];
            float h_r = sm.f.part_h[d]           + sm.f.part_h[H3 + d]           + sm.f.part_h[2 * H3 + d]           + b_hh[d];
            float h_z = sm.f.part_h[d + Hsz]     + sm.f.part_h[H3 + d + Hsz]     + sm.f.part_h[2 * H3 + d + Hsz]     + b_hh[d + Hsz];
            float h_n = sm.f.part_h[d + 2 * Hsz] + sm.f.part_h[H3 + d + 2 * Hsz] + sm.f.part_h[2 * H3 + d + 2 * Hsz] + b_hh[d + 2 * Hsz];
            float r = sigmoidf_(i_r + h_r);
            float z = sigmoidf_(i_z + h_z);
            float n = tanhf(i_n + r * h_n);
            sm.f.hx[d] = (1.f - z) * n + z * sm.f.hx[d];
        }
        __syncthreads();

        const float4* hx4 = (const float4*)sm.f.hx;
        for (int s = w; s < len; s += 15) {
            const float4* e4 = (const float4*)(enc_out + ((size_t)b * Ssz + s) * Hsz);
            float4 ev = e4[lane];
            float4 hv = hx4[lane];
            float acc = ev.x * hv.x + ev.y * hv.y + ev.z * hv.z + ev.w * hv.w;
            if (lane < 36) {
                float4 ev2 = e4[64 + lane];
                float4 hv2 = hx4[64 + lane];
                acc += ev2.x * hv2.x + ev2.y * hv2.y + ev2.z * hv2.z + ev2.w * hv2.w;
            }
            #pragma unroll
            for (int off = 32; off >= 1; off >>= 1) acc += __shfl_xor(acc, off, 64);
            if (lane == 0) sm.f.sL[s] = acc;
        }
        __syncthreads();

        float bv = -INFINITY; int bi = 0x7fffffff;
        for (int s = tid; s < len; s += 960) {
            float v = sm.f.sL[s];
            if (v > bv || (v == bv && s < bi)) { bv = v; bi = s; }
        }
        #pragma unroll
        for (int off = 32; off >= 1; off >>= 1) {
            float ov = __shfl_xor(bv, off, 64);
            int   oi = __shfl_xor(bi, off, 64);
            if (ov > bv || (ov == bv && oi < bi)) { bv = ov; bi = oi; }
        }
        if (lane == 0) { sm.f.redv[w] = bv; sm.f.redi[w] = bi; }
        __syncthreads();
        if (tid == 0) {
            float mv = sm.f.redv[0]; int mi = sm.f.redi[0];
            for (int i = 1; i < 15; ++i)
                if (sm.f.redv[i] > mv || (sm.f.redv[i] == mv && sm.f.redi[i] < mi)) {
                    mv = sm.f.redv[i]; mi = sm.f.redi[i];
                }
            sm.f.bc_max = mv; sm.f.bc_idx = mi;
        }
        __syncthreads();
        float maxv = sm.f.bc_max;
        int   amax = sm.f.bc_idx;

        float ls = 0.f;
        for (int s = tid; s < len; s += 960) {
            float e = expf(sm.f.sL[s] - maxv);
            sm.f.sL[s] = e;
            ls += e;
        }
        #pragma unroll
        for (int off = 32; off >= 1; off >>= 1) ls += __shfl_xor(ls, off, 64);
        if (lane == 0) sm.f.redv[w] = ls;
        __syncthreads();
        if (tid == 0) {
            float sms = 0.f;
            for (int i = 0; i < 15; ++i) sms += sm.f.redv[i];
            sm.f.bc_sum = sms;
        }
        __syncthreads();
        float sum = sm.f.bc_sum;

        float* orow = out_probs + (size_t)b * (Lsz * Vsz) + (size_t)t * Vsz;
        for (int s = tid; s < len; s += 960) {
            atomicAdd(&orow[uttrs[b * Ssz + s]], sm.f.sL[s] / sum);
        }

        int predtok = uttrs[b * Ssz + amax];
        if (tid == 0) preds_out[(size_t)t * Bsz + b] = (float)predtok;
        __syncthreads();
        if (tid < Dsz) sm.f.xv[tid] = embedding[(size_t)predtok * Dsz + tid];
        __syncthreads();
    }
}

// ---------------------------------------------------------------------------
// Batched scores (tf==1), shuffle-free: 256 blocks = (b, s-quarter of 128).
// 512 threads = (s-tile of 2) x (t-pair {tp, tp+8}); acc in registers,
// h broadcast from pad-101 LDS. 8 waves/CU -> 2/SIMD latency hiding.
// ---------------------------------------------------------------------------
__global__ __launch_bounds__(512) void k_scores(const float* __restrict__ h_all,
                                                const float* __restrict__ enc_out,
                                                const int* __restrict__ lens,
                                                const int* __restrict__ tf_p,
                                                float* __restrict__ scores_all) {
    if (tf_p[0] == 0) return;
    __shared__ float4 hS[Lsz * 101];   // 25.9 KB, padded stride

    int b  = blockIdx.x >> 2;
    int sc = blockIdx.x & 3;
    int tid = threadIdx.x;
    int len = lens[b];
    int s0 = sc * 128;
    if (s0 >= len) return;             // whole chunk masked downstream

    const float4* h4g = (const float4*)(h_all + (size_t)b * (Lsz * Hsz));
    for (int i = tid; i < Lsz * 100; i += 512) {
        int t = i / 100, k4 = i % 100;
        hS[t * 101 + k4] = h4g[i];
    }
    __syncthreads();

    int stile = tid >> 3;              // 0..63
    int tp    = tid & 7;               // 0..7
    int t0 = tp, t1 = tp + 8;
    int sbase = s0 + stile * 2;

    const float4* e0 = (const float4*)(enc_out + ((size_t)b * Ssz + sbase + 0) * Hsz);
    const float4* e1 = (const float4*)(enc_out + ((size_t)b * Ssz + sbase + 1) * Hsz);
    const float4* h0p = hS + t0 * 101;
    const float4* h1p = hS + t1 * 101;

    float a00 = 0.f, a01 = 0.f;        // t0 x {s0, s1}
    float a10 = 0.f, a11 = 0.f;        // t1 x {s0, s1}
    #pragma unroll 4
    for (int k4 = 0; k4 < 100; ++k4) {
        float4 v0 = e0[k4], v1 = e1[k4];
        float4 h0 = h0p[k4], h1 = h1p[k4];
        a00 = fmaf(v0.x, h0.x, a00); a00 = fmaf(v0.y, h0.y, a00);
        a00 = fmaf(v0.z, h0.z, a00); a00 = fmaf(v0.w, h0.w, a00);
        a01 = fmaf(v1.x, h0.x, a01); a01 = fmaf(v1.y, h0.y, a01);
        a01 = fmaf(v1.z, h0.z, a01); a01 = fmaf(v1.w, h0.w, a01);
        a10 = fmaf(v0.x, h1.x, a10); a10 = fmaf(v0.y, h1.y, a10);
        a10 = fmaf(v0.z, h1.z, a10); a10 = fmaf(v0.w, h1.w, a10);
        a11 = fmaf(v1.x, h1.x, a11); a11 = fmaf(v1.y, h1.y, a11);
        a11 = fmaf(v1.z, h1.z, a11); a11 = fmaf(v1.w, h1.w, a11);
    }

    float2 r0 = make_float2(a00, a01);
    float2 r1 = make_float2(a10, a11);
    *(float2*)(scores_all + (size_t)t0 * (Bsz * Ssz) + (size_t)b * Ssz + sbase) = r0;
    *(float2*)(scores_all + (size_t)t1 * (Bsz * Ssz) + (size_t)b * Ssz + sbase) = r1;
}

// ---------------------------------------------------------------------------
// Batched softmax + LDS-vocab scatter + argmax (tf==1): 4096 blocks =
// (t, b, vocab-quarter). 32 KB LDS quarter-vocab -> 4 blocks/CU so the
// output stream pipelines across phases. Reductions duplicated per quarter
// (cheap); scatter range-filtered; preds written by quarter 0.
// ---------------------------------------------------------------------------
__global__ __launch_bounds__(256) void k_softmax_all(const float* __restrict__ scores_all,
                                                     const int* __restrict__ lens,
                                                     const int* __restrict__ uttrs,
                                                     const int* __restrict__ tf_p,
                                                     float* __restrict__ out_probs,
                                                     float* __restrict__ preds_out) {
    if (tf_p[0] == 0) return;
    __shared__ float4 vb4[Vsz / 16];  // 32 KB quarter-vocab accumulator
    __shared__ float sL[Ssz];
    __shared__ float redv[4];
    __shared__ int   redi[4];
    __shared__ float bc_max, bc_sum;
    __shared__ int   bc_idx;

    int vq = blockIdx.x & 3;
    int b  = (blockIdx.x >> 2) & 63;
    int t  = blockIdx.x >> 8;
    int tid = threadIdx.x;
    int lane = tid & 63, w = tid >> 6;
    int len = lens[b];
    const int vbase = vq * (Vsz / 4);
    const float* srow = scores_all + (size_t)t * (Bsz * Ssz) + b * Ssz;

    float4 z4 = make_float4(0.f, 0.f, 0.f, 0.f);
    for (int i = tid; i < Vsz / 16; i += 256) vb4[i] = z4;

    for (int s = tid; s < len; s += 256) sL[s] = srow[s];
    __syncthreads();

    float bv = -INFINITY; int bi = 0x7fffffff;
    for (int s = tid; s < len; s += 256) {
        float v = sL[s];
        if (v > bv || (v == bv && s < bi)) { bv = v; bi = s; }
    }
    #pragma unroll
    for (int off = 32; off >= 1; off >>= 1) {
        float ov = __shfl_xor(bv, off, 64);
        int   oi = __shfl_xor(bi, off, 64);
        if (ov > bv || (ov == bv && oi < bi)) { bv = ov; bi = oi; }
    }
    if (lane == 0) { redv[w] = bv; redi[w] = bi; }
    __syncthreads();
    if (tid == 0) {
        float mv = redv[0]; int mi = redi[0];
        for (int i = 1; i < 4; ++i)
            if (redv[i] > mv || (redv[i] == mv && redi[i] < mi)) { mv = redv[i]; mi = redi[i]; }
        bc_max = mv; bc_idx = mi;
    }
    __syncthreads();
    float maxv = bc_max;
    int   amax = bc_idx;

    float ls = 0.f;
    for (int s = tid; s < len; s += 256) {
        float e = expf(sL[s] - maxv);
        sL[s] = e;
        ls += e;
    }
    #pragma unroll
    for (int off = 32; off >= 1; off >>= 1) ls += __shfl_xor(ls, off, 64);
    if (lane == 0) redv[w] = ls;
    __syncthreads();
    if (tid == 0) bc_sum = redv[0] + redv[1] + redv[2] + redv[3];
    __syncthreads();
    float sum = bc_sum;

    float* vbf = (float*)vb4;
    for (int s = tid; s < len; s += 256) {
        int rel = uttrs[b * Ssz + s] - vbase;
        if ((unsigned)rel < (unsigned)(Vsz / 4))
            atomicAdd(&vbf[rel], sL[s] / sum);
    }
    __syncthreads();

    // stream the quarter vocab row out nontemporally (native vector type)
    const nf4* vbn = (const nf4*)vb4;
    nf4* orow4 = (nf4*)(out_probs + (size_t)b * (Lsz * Vsz) + (size_t)t * Vsz + vbase);
    for (int i = tid; i < Vsz / 16; i += 256)
        __builtin_nontemporal_store(vbn[i], &orow4[i]);

    if (vq == 0 && tid == 0)
        preds_out[(size_t)t * Bsz + b] = (float)uttrs[b * Ssz + amax];
}

// ---------------------------------------------------------------------------
extern "C" void kernel_launch(void* const* d_in, const int* in_sizes, int n_in,
                              void* d_out, int out_size, void* d_ws, size_t ws_size,
                              hipStream_t stream) {
    const float* enc_hidden = (const float*)d_in[0];
    const float* enc_out    = (const float*)d_in[1];
    const int*   enc_lens   = (const int*)d_in[2];
    const int*   uttrs      = (const int*)d_in[3];
    const int*   tgt        = (const int*)d_in[4];
    const int*   slot_p     = (const int*)d_in[5];
    const int*   tf_p       = (const int*)d_in[6];
    const float* embedding  = (const float*)d_in[7];
    const float* slot_emb   = (const float*)d_in[8];
    const float* W_ih       = (const float*)d_in[9];
    const float* W_hh       = (const float*)d_in[10];
    const float* b_ih       = (const float*)d_in[11];
    const float* b_hh       = (const float*)d_in[12];

    float* out = (float*)d_out;
    float* ws  = (float*)d_ws;

    float* gi_all     = ws + GI_OFF;
    float* h_all      = ws + HALL_OFF;
    float* scores_all = ws + SCALL_OFF;
    float* preds_out  = out + (size_t)Bsz * Lsz * Vsz;

    int n4 = out_size >> 2;

    // 1) init: tf==0 only (full zero + WT); tf==1 init folded into k_gi
    k_init<<<2048, 256, 0, stream>>>(W_hh, W_ih, tf_p, (float4*)d_out, n4, ws);

    // 2) gi GEMM k-half partials + folded h0/sentinel init (tf==1 only)
    k_gi<<<512, 512, 0, stream>>>(tgt, slot_p, tf_p, embedding, slot_emb,
                                  W_ih, enc_hidden, ws, gi_all);

    // 3) chain (tf==1: sentinel dataflow; tf==0: per-batch fallback)
    k_chain<<<NBLK_CHAIN, 960, 0, stream>>>(ws, gi_all, W_hh, enc_hidden, enc_out,
                                            enc_lens, uttrs, slot_p, tf_p,
                                            embedding, slot_emb, b_ih, b_hh,
                                            ws, h_all, out, preds_out);

    // 4) batched scores + vocab-quarter softmax/scatter (tf==1 only)
    k_scores<<<256, 512, 0, stream>>>(h_all, enc_out, enc_lens, tf_p, scores_all);
    k_softmax_all<<<4096, 256, 0, stream>>>(scores_all, enc_lens, uttrs, tf_p,
                                            out, preds_out);
}